// Round 2
// baseline (8633.340 us; speedup 1.0000x reference)
//
#include <hip/hip_runtime.h>
#include <hip/hip_bf16.h>

// Problem dims (fixed by reference)
#define NN 49152
#define EHN 8192
#define MM (NN + EHN)       // 57344
#define FD 256
#define DD 256
#define NHEADS 8
#define DHEAD 32
#define CHK 1024
#define NEN (10 * NN)       // 491520
#define NEM (10 * MM)       // 573440

// ---------------- GEMM: C = A @ B(^T) [+bias] [relu] ----------------
// 64x64 tile, 256 threads, 4x4 microtile, fp32.
template<int TRANSB>
__global__ __launch_bounds__(256) void gemm_kernel(
    const float* __restrict__ A, const float* __restrict__ B,
    const float* __restrict__ bias, float* __restrict__ C,
    int M, int Ncols, int K, int relu)
{
  __shared__ float sA[16][68];   // row stride 272B (16B-aligned)
  __shared__ float sB[16][68];
  const int bm = blockIdx.y * 64;
  const int bn = blockIdx.x * 64;
  const int tid = threadIdx.x;
  const int tx = tid & 15, ty = tid >> 4;
  float acc[4][4] = {};
  for (int k0 = 0; k0 < K; k0 += 16) {
    for (int i = tid; i < 64 * 16; i += 256) {
      int r = i >> 4, kk = i & 15;
      sA[kk][r] = A[(size_t)(bm + r) * K + (k0 + kk)];
    }
    if (TRANSB) {
      for (int i = tid; i < 64 * 16; i += 256) {
        int cc = i >> 4, kk = i & 15;
        sB[kk][cc] = B[(size_t)(bn + cc) * K + (k0 + kk)];
      }
    } else {
      for (int i = tid; i < 64 * 16; i += 256) {
        int kk = i >> 6, cc = i & 63;
        sB[kk][cc] = B[(size_t)(k0 + kk) * Ncols + (bn + cc)];
      }
    }
    __syncthreads();
    #pragma unroll
    for (int kk = 0; kk < 16; ++kk) {
      float4 a4 = *(const float4*)&sA[kk][ty * 4];
      float4 b4 = *(const float4*)&sB[kk][tx * 4];
      float a[4] = {a4.x, a4.y, a4.z, a4.w};
      float b[4] = {b4.x, b4.y, b4.z, b4.w};
      #pragma unroll
      for (int i2 = 0; i2 < 4; ++i2)
        #pragma unroll
        for (int j2 = 0; j2 < 4; ++j2)
          acc[i2][j2] += a[i2] * b[j2];
    }
    __syncthreads();
  }
  for (int i2 = 0; i2 < 4; ++i2) {
    int r = bm + ty * 4 + i2;
    for (int j2 = 0; j2 < 4; ++j2) {
      int c = bn + tx * 4 + j2;
      float v = acc[i2][j2];
      if (bias) v += bias[c];
      if (relu) v = fmaxf(v, 0.0f);
      C[(size_t)r * Ncols + c] = v;
    }
  }
}

// ---------------- SpMM: Y[row] += val * X[col], D=256 features ----------------
__global__ __launch_bounds__(256) void spmm_kernel(
    const int* __restrict__ rw, const int* __restrict__ cl,
    const float* __restrict__ vl, const float* __restrict__ X,
    float* __restrict__ Y, int nnz, int src_rows, int dst_rows)
{
  int e0 = blockIdx.x * 4;
  int d = threadIdx.x;
  #pragma unroll
  for (int k = 0; k < 4; ++k) {
    int e = e0 + k;
    if (e >= nnz) return;
    int r = rw[e], c = cl[e];
    if (r < dst_rows && c < src_rows) {
      float v = vl[e];
      atomicAdd(&Y[(size_t)r * DD + d], v * X[(size_t)c * DD + d]);
    }
  }
}

// ---------------- bias (+optional relu), row-major rows x 256 ----------------
__global__ __launch_bounds__(256) void bias_act_kernel(
    float* __restrict__ Y, const float* __restrict__ b, int relu)
{
  size_t idx = (size_t)blockIdx.x * 256 + threadIdx.x;
  float v = Y[idx] + b[threadIdx.x];
  Y[idx] = relu ? fmaxf(v, 0.0f) : v;
}

// ---------------- flash attention, thread-per-query-row ----------------
__global__ __launch_bounds__(256) void attn_kernel(
    const float* __restrict__ Q, const float* __restrict__ K,
    const float* __restrict__ V, float* __restrict__ O)
{
  const int c = blockIdx.z;
  const int h = blockIdx.y;
  const int qrow = blockIdx.x * 256 + threadIdx.x;
  const size_t base = (size_t)c * CHK * DD + (size_t)h * DHEAD;
  const float* qr = Q + base + (size_t)qrow * DD;
  float q[DHEAD], o[DHEAD];
  #pragma unroll
  for (int d = 0; d < DHEAD; ++d) { q[d] = qr[d]; o[d] = 0.0f; }
  float m = -1e30f, l = 0.0f;
  __shared__ float sK[64][DHEAD];
  __shared__ float sV[64][DHEAD];
  const float scale = 0.17677669529663687f;  // 1/sqrt(32)
  for (int kt = 0; kt < CHK; kt += 64) {
    __syncthreads();
    for (int i = threadIdx.x; i < 64 * DHEAD; i += 256) {
      int rr = i >> 5, dd = i & 31;
      sK[rr][dd] = K[base + (size_t)(kt + rr) * DD + dd];
      sV[rr][dd] = V[base + (size_t)(kt + rr) * DD + dd];
    }
    __syncthreads();
    for (int kk = 0; kk < 64; ++kk) {
      float s = 0.0f;
      #pragma unroll
      for (int d = 0; d < DHEAD; ++d) s += q[d] * sK[kk][d];
      s *= scale;
      if (s > m) {
        float corr = __expf(m - s);
        l *= corr;
        #pragma unroll
        for (int d = 0; d < DHEAD; ++d) o[d] *= corr;
        m = s;
      }
      float p = __expf(s - m);
      l += p;
      #pragma unroll
      for (int d = 0; d < DHEAD; ++d) o[d] += p * sV[kk][d];
    }
  }
  float inv = 1.0f / l;
  float* orow = O + base + (size_t)qrow * DD;
  #pragma unroll
  for (int d = 0; d < DHEAD; ++d) orow[d] = o[d] * inv;
}

// ---------------- fp32 copy-out with dst stride (d_out is float32) ----------
__global__ __launch_bounds__(256) void store_out_kernel(
    const float* __restrict__ src, float* __restrict__ dst, int dst_ld)
{
  int r = blockIdx.x;
  int j = threadIdx.x;
  dst[(size_t)r * dst_ld + j] = src[(size_t)r * DD + j];
}

// sentinel: error value identifies which runtime check failed
__global__ __launch_bounds__(256) void fill_kernel(float* p, long n, float v)
{
  long i = (long)blockIdx.x * 256 + threadIdx.x;
  if (i < n) p[i] = v;
}

extern "C" void kernel_launch(void* const* d_in, const int* in_sizes, int n_in,
                              void* d_out, int out_size, void* d_ws, size_t ws_size,
                              hipStream_t stream)
{
  const float* x     = (const float*)d_in[0];
  const int*   Acg_r = (const int*)d_in[1];
  const int*   Acg_c = (const int*)d_in[2];
  const float* Acg_v = (const float*)d_in[3];
  const int*   Ahy_r = (const int*)d_in[4];
  const int*   Ahy_c = (const int*)d_in[5];
  const float* Ahy_v = (const float*)d_in[6];
  const int*   Asg_r = (const int*)d_in[7];
  const int*   Asg_c = (const int*)d_in[8];
  const float* Asg_v = (const float*)d_in[9];
  const int*   Lcg_r = (const int*)d_in[10];
  const int*   Lcg_c = (const int*)d_in[11];
  const float* Lcg_v = (const float*)d_in[12];
  const int*   Lhy_r = (const int*)d_in[13];
  const int*   Lhy_c = (const int*)d_in[14];
  const float* Lhy_v = (const float*)d_in[15];
  const int*   Lsg_r = (const int*)d_in[16];
  const int*   Lsg_c = (const int*)d_in[17];
  const float* Lsg_v = (const float*)d_in[18];
  const float* cg_W  = (const float*)d_in[19];
  const float* cg_b  = (const float*)d_in[20];
  const float* hg_W  = (const float*)d_in[21];
  const float* hg_b  = (const float*)d_in[22];
  const float* sg_W  = (const float*)d_in[23];
  const float* sg_b  = (const float*)d_in[24];
  const float* snh_W = (const float*)d_in[25];
  const float* snh_b = (const float*)d_in[26];
  const float* snc_W = (const float*)d_in[27];
  const float* snc_b = (const float*)d_in[28];
  const float* sns_W = (const float*)d_in[29];
  const float* sns_b = (const float*)d_in[30];
  const float* spa_hyp_W  = (const float*)d_in[31];
  const float* spa_hyp_b  = (const float*)d_in[32];
  const float* spa_star_W = (const float*)d_in[33];
  const float* spa_star_b = (const float*)d_in[34];
  const float* spa_clq_W  = (const float*)d_in[35];
  const float* spa_clq_b  = (const float*)d_in[36];
  const float* spa_in_w   = (const float*)d_in[37];
  const float* spa_in_b   = (const float*)d_in[38];
  const float* spa_out_w  = (const float*)d_in[39];
  const float* spa_out_b  = (const float*)d_in[40];
  const float* spe_hyp_W  = (const float*)d_in[41];
  const float* spe_hyp_b  = (const float*)d_in[42];
  const float* spe_star_W = (const float*)d_in[43];
  const float* spe_star_b = (const float*)d_in[44];
  const float* spe_clq_W  = (const float*)d_in[45];
  const float* spe_clq_b  = (const float*)d_in[46];
  const float* spe_in_w   = (const float*)d_in[47];
  const float* spe_in_b   = (const float*)d_in[48];
  const float* spe_out_w  = (const float*)d_in[49];
  const float* spe_out_b  = (const float*)d_in[50];

  float* out = (float*)d_out;

  const size_t NF = (size_t)NN * DD;
  const size_t MF = (size_t)MM * DD;
  const size_t need = (3 * MF + 7 * NF) * sizeof(float);  // ~504 MB

  auto fill = [&](float v) {
    long tot = (long)out_size;
    fill_kernel<<<dim3((unsigned)((tot + 255) / 256)), 256, 0, stream>>>(out, tot, v);
  };
  // decodable sentinels: reported absmax error ~= fill value +- 0.3
  if (ws_size < need)                        { fill(12.0f); return; }
  if (n_in != 51)                            { fill(16.0f); return; }
  if (in_sizes[0] != NN * FD)                { fill(20.0f); return; }
  if (in_sizes[3] != NEN)                    { fill(24.0f); return; }
  if (in_sizes[9] != NEM)                    { fill(28.0f); return; }
  if (in_sizes[19] != 2 * FD * DD)           { fill(32.0f); return; }
  if (in_sizes[37] != 3 * DD * DD)           { fill(36.0f); return; }
  if (out_size != NN * 512 + NN * DD + EHN * DD) { fill(40.0f); return; }

  float* T  = (float*)d_ws;     // M-sized staging
  float* H  = T + MF;           // M-sized expan hidden
  float* SG = H + MF;           // sg_feat (M)
  float* CG = SG + MF;          // cg_feat (N)
  float* HG = CG + NF;          // hg_feat (N)
  float* XH = HG + NF;          // X_hyp (N)
  float* XC = XH + NF;          // X_cg (N)
  float* XS = XC + NF;          // X_sg[:N]
  float* KH = XS + NF;
  float* VH = KH + NF;
  float* QH = XS;               // alias: XS consumed before QH written
  float* AO = XH;               // alias: XH consumed before attention output

  auto gemm = [&](const float* A, const float* B, const float* bias, float* C,
                  int Mrows, bool transB, bool relu) {
    dim3 grid(DD / 64, Mrows / 64);
    if (transB)
      gemm_kernel<1><<<grid, 256, 0, stream>>>(A, B, bias, C, Mrows, DD, DD, relu ? 1 : 0);
    else
      gemm_kernel<0><<<grid, 256, 0, stream>>>(A, B, bias, C, Mrows, DD, DD, relu ? 1 : 0);
  };
  auto spmm = [&](const int* r, const int* c, const float* v, const float* X, float* Y,
                  int nnz, int srcR, int dstR) {
    hipMemsetAsync(Y, 0, (size_t)dstR * DD * sizeof(float), stream);
    spmm_kernel<<<dim3((nnz + 3) / 4), 256, 0, stream>>>(r, c, v, X, Y, nnz, srcR, dstR);
  };
  auto biasact = [&](float* Y, const float* b, int rows, bool relu) {
    bias_act_kernel<<<dim3(rows), 256, 0, stream>>>(Y, b, relu ? 1 : 0);
  };
  auto attn = [&](const float* Qp, const float* Kp, const float* Vp, float* Op) {
    attn_kernel<<<dim3(CHK / 256, NHEADS, NN / CHK), 256, 0, stream>>>(Qp, Kp, Vp, Op);
  };
  auto storeout = [&](const float* src, float* dst, int rows, int ldd) {
    store_out_kernel<<<dim3(rows), 256, 0, stream>>>(src, dst, ldd);
  };

  // ================= expansion nets =================
  gemm(x, cg_W, nullptr, T, NN, false, false);
  spmm(Acg_r, Acg_c, Acg_v, T, H, NEN, NN, NN);
  biasact(H, cg_b, NN, true);
  gemm(H, cg_W + FD * DD, nullptr, T, NN, false, false);
  spmm(Acg_r, Acg_c, Acg_v, T, CG, NEN, NN, NN);
  biasact(CG, cg_b + DD, NN, false);

  gemm(x, hg_W, nullptr, T, NN, false, false);
  spmm(Ahy_r, Ahy_c, Ahy_v, T, H, NEN, NN, NN);
  biasact(H, hg_b, NN, true);
  gemm(H, hg_W + FD * DD, nullptr, T, NN, false, false);
  spmm(Ahy_r, Ahy_c, Ahy_v, T, HG, NEN, NN, NN);
  biasact(HG, hg_b + DD, NN, false);

  // sg: x_star rows >= NN are zero -> src_rows=NN on first spmm
  gemm(x, sg_W, nullptr, T, NN, false, false);
  spmm(Asg_r, Asg_c, Asg_v, T, H, NEM, NN, MM);
  biasact(H, sg_b, MM, true);
  gemm(H, sg_W + FD * DD, nullptr, T, MM, false, false);
  spmm(Asg_r, Asg_c, Asg_v, T, SG, NEM, MM, MM);
  biasact(SG, sg_b + DD, MM, false);

  // outputs: X_star = sg_feat[:N], S_star = sg_feat[N:]  (fp32 out)
  storeout(SG, out + (size_t)NN * 512, NN, DD);
  storeout(SG + NF, out + (size_t)NN * 512 + NF, EHN, DD);

  // ================= sn projections + Laplacian spmm =================
  gemm(HG, snh_W, snh_b, T, NN, true, false);
  spmm(Lhy_r, Lhy_c, Lhy_v, T, XH, NEN, NN, NN);
  gemm(CG, snc_W, snc_b, T, NN, true, false);
  spmm(Lcg_r, Lcg_c, Lcg_v, T, XC, NEN, NN, NN);
  gemm(SG, sns_W, sns_b, T, MM, true, false);
  spmm(Lsg_r, Lsg_c, Lsg_v, T, XS, NEM, MM, NN);   // only rows < N kept

  // ================= spectral MHA (v, then q, then k) =================
  gemm(XS, spe_clq_W, spe_clq_b, T, NN, true, false);
  gemm(T, spe_in_w + 2 * DD * DD, spe_in_b + 2 * DD, VH, NN, true, false);
  gemm(XH, spe_hyp_W, spe_hyp_b, T, NN, true, false);
  gemm(T, spe_in_w, spe_in_b, QH, NN, true, false);
  gemm(XC, spe_star_W, spe_star_b, T, NN, true, false);
  gemm(T, spe_in_w + DD * DD, spe_in_b + DD, KH, NN, true, false);
  attn(QH, KH, VH, AO);
  gemm(AO, spe_out_w, spe_out_b, T, NN, true, false);
  storeout(T, out + DD, NN, 2 * DD);               // taa cols 256..511

  // ================= spatial MHA =================
  gemm(SG, spa_clq_W, spa_clq_b, T, NN, true, false);   // X_star = SG[:N]
  gemm(T, spa_in_w + 2 * DD * DD, spa_in_b + 2 * DD, VH, NN, true, false);
  gemm(HG, spa_hyp_W, spa_hyp_b, T, NN, true, false);
  gemm(T, spa_in_w, spa_in_b, QH, NN, true, false);
  gemm(CG, spa_star_W, spa_star_b, T, NN, true, false);
  gemm(T, spa_in_w + DD * DD, spa_in_b + DD, KH, NN, true, false);
  attn(QH, KH, VH, AO);
  gemm(AO, spa_out_w, spa_out_b, T, NN, true, false);
  storeout(T, out, NN, 2 * DD);                    // taa cols 0..255
}

// Round 3
// 6574.516 us; speedup vs baseline: 1.3132x; 1.3132x over previous
//
#include <hip/hip_runtime.h>

// Problem dims (fixed by reference)
#define NN 49152
#define EHN 8192
#define MM (NN + EHN)       // 57344
#define FD 256
#define DD 256
#define NHEADS 8
#define DHEAD 32
#define CHK 1024
#define NEN (10 * NN)       // 491520
#define NEM (10 * MM)       // 573440

typedef __bf16 bf16x8 __attribute__((ext_vector_type(8)));
typedef unsigned short u16x8 __attribute__((ext_vector_type(8)));
typedef float f32x4 __attribute__((ext_vector_type(4)));

// fp32 -> bf16 bits, round-to-nearest-even (matches HW cvt)
static __device__ __forceinline__ unsigned short f2bf(float f) {
  unsigned int u = __float_as_uint(f);
  unsigned int r = (u + 0x7FFFu + ((u >> 16) & 1u)) >> 16;
  return (unsigned short)r;
}

// ---------------- weight prep: cast (and optionally transpose) to bf16 ------
// dst[n*K + k] = bf16( T ? src[k*Nr + n] : src[n*K + k] ), K = 256
__global__ __launch_bounds__(256) void cast_w_kernel(
    const float* __restrict__ src, unsigned short* __restrict__ dst,
    int Nr, int T)
{
  int i = blockIdx.x * 256 + threadIdx.x;     // grid = Nr blocks -> Nr*256 elems
  int n = i >> 8, k = i & 255;
  float f = T ? src[(size_t)k * Nr + n] : src[i];
  dst[i] = f2bf(f);
}

// ---------------- bf16-MFMA GEMM: C[M][256] = A[M][256] * Wt^T --------------
// Wt is [256 n][256 k] bf16 (pre-transposed so both frags read 8 contiguous k).
// 512 threads = 8 waves (2x4), tile 128x256, BK=32, single-buffered LDS.
__global__ __launch_bounds__(512) void gemm_mfma_kernel(
    const float* __restrict__ A, const unsigned short* __restrict__ Wt,
    const float* __restrict__ bias, float* __restrict__ C,
    int M, int relu)
{
  __shared__ unsigned short sA[128][40];   // row stride 80B (16B-aligned)
  __shared__ unsigned short sB[256][40];
  const int bm = blockIdx.x * 128;
  const int tid = threadIdx.x;
  const int lane = tid & 63;
  const int wid = tid >> 6;          // 0..7
  const int wm = wid >> 2;           // 0..1  (64-row half)
  const int wn = wid & 3;            // 0..3  (64-col quarter)
  const int l15 = lane & 15, l4 = lane >> 4;

  f32x4 acc[4][4] = {};
  const int ar = tid >> 2;           // 0..127  A row
  const int aq = (tid & 3) * 8;      // A k-offset {0,8,16,24}
  const int br = tid >> 1;           // 0..255  B n-row
  const int bq = (tid & 1) * 16;     // B k-offset {0,16}

  for (int k0 = 0; k0 < 256; k0 += 32) {
    {
      const float* src = A + (size_t)(bm + ar) * 256 + k0 + aq;
      float4 f0 = *(const float4*)src;
      float4 f1 = *(const float4*)(src + 4);
      u16x8 v;
      v[0] = f2bf(f0.x); v[1] = f2bf(f0.y); v[2] = f2bf(f0.z); v[3] = f2bf(f0.w);
      v[4] = f2bf(f1.x); v[5] = f2bf(f1.y); v[6] = f2bf(f1.z); v[7] = f2bf(f1.w);
      *(u16x8*)&sA[ar][aq] = v;
    }
    {
      const unsigned short* src = Wt + (size_t)br * 256 + k0 + bq;
      u16x8 v0 = *(const u16x8*)src;
      u16x8 v1 = *(const u16x8*)(src + 8);
      *(u16x8*)&sB[br][bq] = v0;
      *(u16x8*)&sB[br][bq + 8] = v1;
    }
    __syncthreads();
    bf16x8 av[4], bv[4];
    #pragma unroll
    for (int mi = 0; mi < 4; ++mi)
      av[mi] = *(const bf16x8*)&sA[wm * 64 + mi * 16 + l15][l4 * 8];
    #pragma unroll
    for (int ni = 0; ni < 4; ++ni)
      bv[ni] = *(const bf16x8*)&sB[wn * 64 + ni * 16 + l15][l4 * 8];
    #pragma unroll
    for (int mi = 0; mi < 4; ++mi)
      #pragma unroll
      for (int ni = 0; ni < 4; ++ni)
        acc[mi][ni] = __builtin_amdgcn_mfma_f32_16x16x32_bf16(
            av[mi], bv[ni], acc[mi][ni], 0, 0, 0);
    __syncthreads();
  }
  #pragma unroll
  for (int mi = 0; mi < 4; ++mi) {
    #pragma unroll
    for (int ni = 0; ni < 4; ++ni) {
      int col = wn * 64 + ni * 16 + l15;
      int r0 = bm + wm * 64 + mi * 16 + l4 * 4;
      float bb = bias ? bias[col] : 0.0f;
      #pragma unroll
      for (int j = 0; j < 4; ++j) {
        float v = acc[mi][ni][j] + bb;
        if (relu) v = fmaxf(v, 0.0f);
        C[(size_t)(r0 + j) * 256 + col] = v;
      }
    }
  }
}

// ---------------- SpMM: Y[row] += val * X[col], D=256 features ----------------
__global__ __launch_bounds__(256) void spmm_kernel(
    const int* __restrict__ rw, const int* __restrict__ cl,
    const float* __restrict__ vl, const float* __restrict__ X,
    float* __restrict__ Y, int nnz, int src_rows, int dst_rows)
{
  int e0 = blockIdx.x * 4;
  int d = threadIdx.x;
  #pragma unroll
  for (int k = 0; k < 4; ++k) {
    int e = e0 + k;
    if (e >= nnz) return;
    int r = rw[e], c = cl[e];
    if (r < dst_rows && c < src_rows) {
      float v = vl[e];
      atomicAdd(&Y[(size_t)r * DD + d], v * X[(size_t)c * DD + d]);
    }
  }
}

// ---------------- bias (+optional relu), row-major rows x 256 ----------------
__global__ __launch_bounds__(256) void bias_act_kernel(
    float* __restrict__ Y, const float* __restrict__ b, int relu)
{
  size_t idx = (size_t)blockIdx.x * 256 + threadIdx.x;
  float v = Y[idx] + b[threadIdx.x];
  Y[idx] = relu ? fmaxf(v, 0.0f) : v;
}

// ---------------- flash attention, thread-per-query-row ----------------
__global__ __launch_bounds__(256) void attn_kernel(
    const float* __restrict__ Q, const float* __restrict__ K,
    const float* __restrict__ V, float* __restrict__ O)
{
  const int c = blockIdx.z;
  const int h = blockIdx.y;
  const int qrow = blockIdx.x * 256 + threadIdx.x;
  const size_t base = (size_t)c * CHK * DD + (size_t)h * DHEAD;
  const float* qr = Q + base + (size_t)qrow * DD;
  float q[DHEAD], o[DHEAD];
  #pragma unroll
  for (int d = 0; d < DHEAD; ++d) { q[d] = qr[d]; o[d] = 0.0f; }
  float m = -1e30f, l = 0.0f;
  __shared__ float sK[64][DHEAD];
  __shared__ float sV[64][DHEAD];
  const float scale = 0.17677669529663687f;  // 1/sqrt(32)
  for (int kt = 0; kt < CHK; kt += 64) {
    __syncthreads();
    for (int i = threadIdx.x; i < 64 * DHEAD; i += 256) {
      int rr = i >> 5, dd = i & 31;
      sK[rr][dd] = K[base + (size_t)(kt + rr) * DD + dd];
      sV[rr][dd] = V[base + (size_t)(kt + rr) * DD + dd];
    }
    __syncthreads();
    for (int kk = 0; kk < 64; ++kk) {
      float s = 0.0f;
      #pragma unroll
      for (int d = 0; d < DHEAD; ++d) s += q[d] * sK[kk][d];
      s *= scale;
      if (s > m) {
        float corr = __expf(m - s);
        l *= corr;
        #pragma unroll
        for (int d = 0; d < DHEAD; ++d) o[d] *= corr;
        m = s;
      }
      float p = __expf(s - m);
      l += p;
      #pragma unroll
      for (int d = 0; d < DHEAD; ++d) o[d] += p * sV[kk][d];
    }
  }
  float inv = 1.0f / l;
  float* orow = O + base + (size_t)qrow * DD;
  #pragma unroll
  for (int d = 0; d < DHEAD; ++d) orow[d] = o[d] * inv;
}

// ---------------- fp32 copy-out with dst stride ----------
__global__ __launch_bounds__(256) void store_out_kernel(
    const float* __restrict__ src, float* __restrict__ dst, int dst_ld)
{
  int r = blockIdx.x;
  int j = threadIdx.x;
  dst[(size_t)r * dst_ld + j] = src[(size_t)r * DD + j];
}

// sentinel: error value identifies which runtime check failed
__global__ __launch_bounds__(256) void fill_kernel(float* p, long n, float v)
{
  long i = (long)blockIdx.x * 256 + threadIdx.x;
  if (i < n) p[i] = v;
}

extern "C" void kernel_launch(void* const* d_in, const int* in_sizes, int n_in,
                              void* d_out, int out_size, void* d_ws, size_t ws_size,
                              hipStream_t stream)
{
  const float* x     = (const float*)d_in[0];
  const int*   Acg_r = (const int*)d_in[1];
  const int*   Acg_c = (const int*)d_in[2];
  const float* Acg_v = (const float*)d_in[3];
  const int*   Ahy_r = (const int*)d_in[4];
  const int*   Ahy_c = (const int*)d_in[5];
  const float* Ahy_v = (const float*)d_in[6];
  const int*   Asg_r = (const int*)d_in[7];
  const int*   Asg_c = (const int*)d_in[8];
  const float* Asg_v = (const float*)d_in[9];
  const int*   Lcg_r = (const int*)d_in[10];
  const int*   Lcg_c = (const int*)d_in[11];
  const float* Lcg_v = (const float*)d_in[12];
  const int*   Lhy_r = (const int*)d_in[13];
  const int*   Lhy_c = (const int*)d_in[14];
  const float* Lhy_v = (const float*)d_in[15];
  const int*   Lsg_r = (const int*)d_in[16];
  const int*   Lsg_c = (const int*)d_in[17];
  const float* Lsg_v = (const float*)d_in[18];
  const float* cg_W  = (const float*)d_in[19];
  const float* cg_b  = (const float*)d_in[20];
  const float* hg_W  = (const float*)d_in[21];
  const float* hg_b  = (const float*)d_in[22];
  const float* sg_W  = (const float*)d_in[23];
  const float* sg_b  = (const float*)d_in[24];
  const float* snh_W = (const float*)d_in[25];
  const float* snh_b = (const float*)d_in[26];
  const float* snc_W = (const float*)d_in[27];
  const float* snc_b = (const float*)d_in[28];
  const float* sns_W = (const float*)d_in[29];
  const float* sns_b = (const float*)d_in[30];
  const float* spa_hyp_W  = (const float*)d_in[31];
  const float* spa_hyp_b  = (const float*)d_in[32];
  const float* spa_star_W = (const float*)d_in[33];
  const float* spa_star_b = (const float*)d_in[34];
  const float* spa_clq_W  = (const float*)d_in[35];
  const float* spa_clq_b  = (const float*)d_in[36];
  const float* spa_in_w   = (const float*)d_in[37];
  const float* spa_in_b   = (const float*)d_in[38];
  const float* spa_out_w  = (const float*)d_in[39];
  const float* spa_out_b  = (const float*)d_in[40];
  const float* spe_hyp_W  = (const float*)d_in[41];
  const float* spe_hyp_b  = (const float*)d_in[42];
  const float* spe_star_W = (const float*)d_in[43];
  const float* spe_star_b = (const float*)d_in[44];
  const float* spe_clq_W  = (const float*)d_in[45];
  const float* spe_clq_b  = (const float*)d_in[46];
  const float* spe_in_w   = (const float*)d_in[47];
  const float* spe_in_b   = (const float*)d_in[48];
  const float* spe_out_w  = (const float*)d_in[49];
  const float* spe_out_b  = (const float*)d_in[50];

  float* out = (float*)d_out;

  const size_t NF = (size_t)NN * DD;
  const size_t MF = (size_t)MM * DD;
  const size_t WELEMS = 23u * 65536u;   // bf16 weight slab (23 slots of 256x256)
  const size_t need = (3 * MF + 7 * NF) * sizeof(float) + WELEMS * 2;

  auto fill = [&](float v) {
    long tot = (long)out_size;
    fill_kernel<<<dim3((unsigned)((tot + 255) / 256)), 256, 0, stream>>>(out, tot, v);
  };
  if (ws_size < need)                        { fill(12.0f); return; }
  if (n_in != 51)                            { fill(16.0f); return; }
  if (in_sizes[0] != NN * FD)                { fill(20.0f); return; }
  if (in_sizes[3] != NEN)                    { fill(24.0f); return; }
  if (in_sizes[9] != NEM)                    { fill(28.0f); return; }
  if (in_sizes[19] != 2 * FD * DD)           { fill(32.0f); return; }
  if (in_sizes[37] != 3 * DD * DD)           { fill(36.0f); return; }
  if (out_size != NN * 512 + NN * DD + EHN * DD) { fill(40.0f); return; }

  float* T  = (float*)d_ws;
  float* H  = T + MF;
  float* SG = H + MF;
  float* CG = SG + MF;
  float* HG = CG + NF;
  float* XH = HG + NF;
  float* XC = XH + NF;
  float* XS = XC + NF;
  float* KH = XS + NF;
  float* VH = KH + NF;
  float* QH = XS;               // alias: XS consumed before QH written
  float* AO = XH;               // alias: XH consumed before attention output
  unsigned short* WB = (unsigned short*)(VH + NF);

  // weight slab slots (each 65536 bf16): see castw calls below
  auto wslot = [&](int s) { return WB + (size_t)s * 65536; };

  auto castw = [&](const float* src, unsigned short* dst, int Nr, int T_) {
    cast_w_kernel<<<dim3(Nr), 256, 0, stream>>>(src, dst, Nr, T_);
  };
  auto gemm = [&](const float* A, const unsigned short* Wt, const float* bias,
                  float* C, int Mrows, bool relu) {
    gemm_mfma_kernel<<<dim3(Mrows / 128), 512, 0, stream>>>(
        A, Wt, bias, C, Mrows, relu ? 1 : 0);
  };
  auto spmm = [&](const int* r, const int* c, const float* v, const float* X, float* Y,
                  int nnz, int srcR, int dstR) {
    hipMemsetAsync(Y, 0, (size_t)dstR * DD * sizeof(float), stream);
    spmm_kernel<<<dim3((nnz + 3) / 4), 256, 0, stream>>>(r, c, v, X, Y, nnz, srcR, dstR);
  };
  auto biasact = [&](float* Y, const float* b, int rows, bool relu) {
    bias_act_kernel<<<dim3(rows), 256, 0, stream>>>(Y, b, relu ? 1 : 0);
  };
  auto attn = [&](const float* Qp, const float* Kp, const float* Vp, float* Op) {
    attn_kernel<<<dim3(CHK / 256, NHEADS, NN / CHK), 256, 0, stream>>>(Qp, Kp, Vp, Op);
  };
  auto storeout = [&](const float* src, float* dst, int rows, int ldd) {
    store_out_kernel<<<dim3(rows), 256, 0, stream>>>(src, dst, ldd);
  };

  // ================= weight prep (bf16, [n][k] layout) =================
  castw(cg_W,              wslot(0), 256, 1);   // x @ W0 : W is [K][N] -> transpose
  castw(cg_W + FD * DD,    wslot(1), 256, 1);
  castw(hg_W,              wslot(2), 256, 1);
  castw(hg_W + FD * DD,    wslot(3), 256, 1);
  castw(sg_W,              wslot(4), 256, 1);
  castw(sg_W + FD * DD,    wslot(5), 256, 1);
  castw(snh_W,             wslot(6), 256, 0);   // X @ W.T : W already [n][k]
  castw(snc_W,             wslot(7), 256, 0);
  castw(sns_W,             wslot(8), 256, 0);
  castw(spa_hyp_W,         wslot(9), 256, 0);
  castw(spa_star_W,        wslot(10), 256, 0);
  castw(spa_clq_W,         wslot(11), 256, 0);
  castw(spa_out_w,         wslot(12), 256, 0);
  castw(spa_in_w,          wslot(13), 768, 0);  // slots 13,14,15 = wq,wk,wv
  castw(spe_hyp_W,         wslot(16), 256, 0);
  castw(spe_star_W,        wslot(17), 256, 0);
  castw(spe_clq_W,         wslot(18), 256, 0);
  castw(spe_out_w,         wslot(19), 256, 0);
  castw(spe_in_w,          wslot(20), 768, 0);  // slots 20,21,22

  // ================= expansion nets =================
  gemm(x, wslot(0), nullptr, T, NN, false);
  spmm(Acg_r, Acg_c, Acg_v, T, H, NEN, NN, NN);
  biasact(H, cg_b, NN, true);
  gemm(H, wslot(1), nullptr, T, NN, false);
  spmm(Acg_r, Acg_c, Acg_v, T, CG, NEN, NN, NN);
  biasact(CG, cg_b + DD, NN, false);

  gemm(x, wslot(2), nullptr, T, NN, false);
  spmm(Ahy_r, Ahy_c, Ahy_v, T, H, NEN, NN, NN);
  biasact(H, hg_b, NN, true);
  gemm(H, wslot(3), nullptr, T, NN, false);
  spmm(Ahy_r, Ahy_c, Ahy_v, T, HG, NEN, NN, NN);
  biasact(HG, hg_b + DD, NN, false);

  // sg: x_star rows >= NN are zero -> src_rows=NN on first spmm
  gemm(x, wslot(4), nullptr, T, NN, false);
  spmm(Asg_r, Asg_c, Asg_v, T, H, NEM, NN, MM);
  biasact(H, sg_b, MM, true);
  gemm(H, wslot(5), nullptr, T, MM, false);
  spmm(Asg_r, Asg_c, Asg_v, T, SG, NEM, MM, MM);
  biasact(SG, sg_b + DD, MM, false);

  // outputs: X_star = sg_feat[:N], S_star = sg_feat[N:]
  storeout(SG, out + (size_t)NN * 512, NN, DD);
  storeout(SG + NF, out + (size_t)NN * 512 + NF, EHN, DD);

  // ================= sn projections + Laplacian spmm =================
  gemm(HG, wslot(6), snh_b, T, NN, false);
  spmm(Lhy_r, Lhy_c, Lhy_v, T, XH, NEN, NN, NN);
  gemm(CG, wslot(7), snc_b, T, NN, false);
  spmm(Lcg_r, Lcg_c, Lcg_v, T, XC, NEN, NN, NN);
  gemm(SG, wslot(8), sns_b, T, MM, false);
  spmm(Lsg_r, Lsg_c, Lsg_v, T, XS, NEM, MM, NN);   // only rows < N kept

  // ================= spectral MHA (v, then q, then k) =================
  gemm(XS, wslot(18), spe_clq_b, T, NN, false);
  gemm(T, wslot(22), spe_in_b + 2 * DD, VH, NN, false);
  gemm(XH, wslot(16), spe_hyp_b, T, NN, false);
  gemm(T, wslot(20), spe_in_b, QH, NN, false);
  gemm(XC, wslot(17), spe_star_b, T, NN, false);
  gemm(T, wslot(21), spe_in_b + DD, KH, NN, false);
  attn(QH, KH, VH, AO);
  gemm(AO, wslot(19), spe_out_b, T, NN, false);
  storeout(T, out + DD, NN, 2 * DD);               // taa cols 256..511

  // ================= spatial MHA =================
  gemm(SG, wslot(11), spa_clq_b, T, NN, false);    // X_star = SG[:N]
  gemm(T, wslot(15), spa_in_b + 2 * DD, VH, NN, false);
  gemm(HG, wslot(9), spa_hyp_b, T, NN, false);
  gemm(T, wslot(13), spa_in_b, QH, NN, false);
  gemm(CG, wslot(10), spa_star_b, T, NN, false);
  gemm(T, wslot(14), spa_in_b + DD, KH, NN, false);
  attn(QH, KH, VH, AO);
  gemm(AO, wslot(12), spa_out_b, T, NN, false);
  storeout(T, out, NN, 2 * DD);                    // taa cols 0..255
}

// Round 4
// 2862.856 us; speedup vs baseline: 3.0156x; 2.2965x over previous
//
#include <hip/hip_runtime.h>

// Problem dims (fixed by reference)
#define NN 49152
#define EHN 8192
#define MM (NN + EHN)       // 57344
#define FD 256
#define DD 256
#define NHEADS 8
#define DHEAD 32
#define CHK 1024
#define NEN (10 * NN)       // 491520
#define NEM (10 * MM)       // 573440

typedef __bf16 bf16x8 __attribute__((ext_vector_type(8)));
typedef unsigned short u16x8 __attribute__((ext_vector_type(8)));
typedef float f32x4 __attribute__((ext_vector_type(4)));

// fp32 -> bf16 bits, round-to-nearest-even
static __device__ __forceinline__ unsigned short f2bf(float f) {
  unsigned int u = __float_as_uint(f);
  unsigned int r = (u + 0x7FFFu + ((u >> 16) & 1u)) >> 16;
  return (unsigned short)r;
}

// ---------------- weight prep: cast (and optionally transpose) to bf16 ------
__global__ __launch_bounds__(256) void cast_w_kernel(
    const float* __restrict__ src, unsigned short* __restrict__ dst,
    int Nr, int T)
{
  int i = blockIdx.x * 256 + threadIdx.x;
  int n = i >> 8, k = i & 255;
  float f = T ? src[(size_t)k * Nr + n] : src[i];
  dst[i] = f2bf(f);
}

// ---------------- bf16-MFMA GEMM: C[M][256] = A[M][256] * Wt^T --------------
// (validated round 3) Wt is [256 n][256 k] bf16. 8 waves, tile 128x256, BK=32.
__global__ __launch_bounds__(512) void gemm_mfma_kernel(
    const float* __restrict__ A, const unsigned short* __restrict__ Wt,
    const float* __restrict__ bias, float* __restrict__ C,
    int M, int relu)
{
  __shared__ unsigned short sA[128][40];
  __shared__ unsigned short sB[256][40];
  const int bm = blockIdx.x * 128;
  const int tid = threadIdx.x;
  const int lane = tid & 63;
  const int wid = tid >> 6;
  const int wm = wid >> 2;
  const int wn = wid & 3;
  const int l15 = lane & 15, l4 = lane >> 4;

  f32x4 acc[4][4] = {};
  const int ar = tid >> 2;
  const int aq = (tid & 3) * 8;
  const int br = tid >> 1;
  const int bq = (tid & 1) * 16;

  for (int k0 = 0; k0 < 256; k0 += 32) {
    {
      const float* src = A + (size_t)(bm + ar) * 256 + k0 + aq;
      float4 f0 = *(const float4*)src;
      float4 f1 = *(const float4*)(src + 4);
      u16x8 v;
      v[0] = f2bf(f0.x); v[1] = f2bf(f0.y); v[2] = f2bf(f0.z); v[3] = f2bf(f0.w);
      v[4] = f2bf(f1.x); v[5] = f2bf(f1.y); v[6] = f2bf(f1.z); v[7] = f2bf(f1.w);
      *(u16x8*)&sA[ar][aq] = v;
    }
    {
      const unsigned short* src = Wt + (size_t)br * 256 + k0 + bq;
      u16x8 v0 = *(const u16x8*)src;
      u16x8 v1 = *(const u16x8*)(src + 8);
      *(u16x8*)&sB[br][bq] = v0;
      *(u16x8*)&sB[br][bq + 8] = v1;
    }
    __syncthreads();
    bf16x8 av[4], bv[4];
    #pragma unroll
    for (int mi = 0; mi < 4; ++mi)
      av[mi] = *(const bf16x8*)&sA[wm * 64 + mi * 16 + l15][l4 * 8];
    #pragma unroll
    for (int ni = 0; ni < 4; ++ni)
      bv[ni] = *(const bf16x8*)&sB[wn * 64 + ni * 16 + l15][l4 * 8];
    #pragma unroll
    for (int mi = 0; mi < 4; ++mi)
      #pragma unroll
      for (int ni = 0; ni < 4; ++ni)
        acc[mi][ni] = __builtin_amdgcn_mfma_f32_16x16x32_bf16(
            av[mi], bv[ni], acc[mi][ni], 0, 0, 0);
    __syncthreads();
  }
  #pragma unroll
  for (int mi = 0; mi < 4; ++mi) {
    #pragma unroll
    for (int ni = 0; ni < 4; ++ni) {
      int col = wn * 64 + ni * 16 + l15;
      int r0 = bm + wm * 64 + mi * 16 + l4 * 4;
      float bb = bias ? bias[col] : 0.0f;
      #pragma unroll
      for (int j = 0; j < 4; ++j) {
        float v = acc[mi][ni][j] + bb;
        if (relu) v = fmaxf(v, 0.0f);
        C[(size_t)(r0 + j) * 256 + col] = v;
      }
    }
  }
}

// ================= CSR build =================
__global__ __launch_bounds__(256) void count_kernel(
    const int* __restrict__ rw, int* __restrict__ cnt, int nnz)
{
  int e = blockIdx.x * 256 + threadIdx.x;
  if (e < nnz) atomicAdd(&cnt[rw[e]], 1);
}

__global__ __launch_bounds__(256) void scan1_kernel(
    const int* __restrict__ cnt, int* __restrict__ bsum, int n)
{
  __shared__ int sh[256];
  int i = blockIdx.x * 256 + threadIdx.x;
  sh[threadIdx.x] = (i < n) ? cnt[i] : 0;
  __syncthreads();
  for (int off = 128; off; off >>= 1) {
    if (threadIdx.x < off) sh[threadIdx.x] += sh[threadIdx.x + off];
    __syncthreads();
  }
  if (threadIdx.x == 0) bsum[blockIdx.x] = sh[0];
}

__global__ __launch_bounds__(256) void scan2_kernel(int* __restrict__ bsum, int nb)
{
  __shared__ int sh[256];
  int v = (threadIdx.x < nb) ? bsum[threadIdx.x] : 0;
  sh[threadIdx.x] = v;
  __syncthreads();
  for (int off = 1; off < 256; off <<= 1) {
    int add = (threadIdx.x >= off) ? sh[threadIdx.x - off] : 0;
    __syncthreads();
    sh[threadIdx.x] += add;
    __syncthreads();
  }
  if (threadIdx.x < nb) bsum[threadIdx.x] = sh[threadIdx.x] - v;  // exclusive
}

__global__ __launch_bounds__(256) void scan3_kernel(
    const int* __restrict__ cnt, const int* __restrict__ bsum,
    int* __restrict__ rowptr, int n)
{
  __shared__ int sh[256];
  int i = blockIdx.x * 256 + threadIdx.x;
  int v = (i < n) ? cnt[i] : 0;
  sh[threadIdx.x] = v;
  __syncthreads();
  for (int off = 1; off < 256; off <<= 1) {
    int add = (threadIdx.x >= off) ? sh[threadIdx.x - off] : 0;
    __syncthreads();
    sh[threadIdx.x] += add;
    __syncthreads();
  }
  int incl = sh[threadIdx.x];
  int base = bsum[blockIdx.x];
  if (i < n) rowptr[i] = base + incl - v;
  if (i == n - 1) rowptr[n] = base + incl;
}

__global__ __launch_bounds__(256) void fillcsr_kernel(
    const int* __restrict__ rw, const int* __restrict__ cl,
    const float* __restrict__ vl, const int* __restrict__ rowptr,
    int* __restrict__ cur, int* __restrict__ ecol, float* __restrict__ eval,
    int nnz)
{
  int e = blockIdx.x * 256 + threadIdx.x;
  if (e < nnz) {
    int r = rw[e];
    int pos = rowptr[r] + atomicAdd(&cur[r], 1);
    ecol[pos] = cl[e];
    eval[pos] = vl[e];
  }
}

// ---------------- CSR SpMM: one block per dst row; fused bias/relu ----------
__global__ __launch_bounds__(256) void csr_spmm_kernel(
    const int* __restrict__ rowptr, const int* __restrict__ ecol,
    const float* __restrict__ eval, const float* __restrict__ X,
    float* __restrict__ Y, int src_rows, const float* __restrict__ bias,
    int relu)
{
  int r = blockIdx.x, t = threadIdx.x;
  int beg = rowptr[r], end = rowptr[r + 1];
  float acc = 0.0f;
  for (int e = beg; e < end; ++e) {
    int c = ecol[e];
    float v = eval[e];
    if (c < src_rows) acc += v * X[(size_t)c * DD + t];
  }
  if (bias) acc += bias[t];
  if (relu) acc = fmaxf(acc, 0.0f);
  Y[(size_t)r * DD + t] = acc;
}

// ---------------- MFMA flash attention ----------------
// Block = 4 waves; wave owns 16 q rows (q = q0 + lane&15). KV tiles of 64.
// S^T = mfma(K_frag, Q_frag) -> lane-local softmax rows (4-lane shfl reduce).
// PV as O^T = mfma(Vt_frag, Pt_frag) with V transposed in LDS, P via LDS.
__global__ __launch_bounds__(256) void attn_mfma_kernel(
    const float* __restrict__ Q, const float* __restrict__ K,
    const float* __restrict__ V, float* __restrict__ O)
{
  __shared__ __align__(16) char sKb[4096];   // [64 key][32 d] bf16, swz (key&7)<<4
  __shared__ __align__(16) char sVb[4096];   // [32 d][64 key] bf16, swz (d&7)<<4
  __shared__ __align__(16) char sPb[8192];   // per-wave [16 q][64 key] bf16, swz (q&7)<<4
  const int c = blockIdx.z, h = blockIdx.y;
  const int tid = threadIdx.x, lane = tid & 63, wid = tid >> 6;
  const int l15 = lane & 15, l4 = lane >> 4;
  char* sPw = sPb + wid * 2048;
  const size_t base = (size_t)c * (CHK * DD) + (size_t)h * DHEAD;
  const int q0 = blockIdx.x * 64 + wid * 16;
  const float scale = 0.17677669529663687f;  // 1/sqrt(32)

  // Q fragment (B-operand): col=l15 -> row q0+l15; k = l4*8+j. Scale folded in.
  bf16x8 qf;
  {
    const float* qr = Q + base + (size_t)(q0 + l15) * DD + l4 * 8;
    float4 f0 = *(const float4*)qr;
    float4 f1 = *(const float4*)(qr + 4);
    union { u16x8 u; bf16x8 b; } qu;
    qu.u[0] = f2bf(f0.x * scale); qu.u[1] = f2bf(f0.y * scale);
    qu.u[2] = f2bf(f0.z * scale); qu.u[3] = f2bf(f0.w * scale);
    qu.u[4] = f2bf(f1.x * scale); qu.u[5] = f2bf(f1.y * scale);
    qu.u[6] = f2bf(f1.z * scale); qu.u[7] = f2bf(f1.w * scale);
    qf = qu.b;
  }

  f32x4 oacc[2] = {};
  float m = -1e30f, l = 0.0f;
  const f32x4 zero = {};

  for (int kt = 0; kt < CHK; kt += 64) {
    __syncthreads();   // previous tile's PV reads done
    {
      int key = tid >> 2, dq = (tid & 3) * 8;
      const float* kp = K + base + (size_t)(kt + key) * DD + dq;
      float4 a = *(const float4*)kp, b = *(const float4*)(kp + 4);
      u16x8 kv;
      kv[0] = f2bf(a.x); kv[1] = f2bf(a.y); kv[2] = f2bf(a.z); kv[3] = f2bf(a.w);
      kv[4] = f2bf(b.x); kv[5] = f2bf(b.y); kv[6] = f2bf(b.z); kv[7] = f2bf(b.w);
      int ba = (key << 6) + (dq << 1); ba ^= ((key & 7) << 4);
      *(u16x8*)(sKb + ba) = kv;
      const float* vp = V + base + (size_t)(kt + key) * DD + dq;
      float4 c4 = *(const float4*)vp, d4 = *(const float4*)(vp + 4);
      float vv[8] = {c4.x, c4.y, c4.z, c4.w, d4.x, d4.y, d4.z, d4.w};
      #pragma unroll
      for (int i = 0; i < 8; ++i) {
        int d = dq + i;
        int bb = (d << 7) + (key << 1); bb ^= ((d & 7) << 4);
        *(unsigned short*)(sVb + bb) = f2bf(vv[i]);
      }
    }
    __syncthreads();   // staging visible

    // S^T tiles: 4 key-subtiles of 16
    f32x4 s[4];
    #pragma unroll
    for (int s4 = 0; s4 < 4; ++s4) {
      int key = s4 * 16 + l15;
      int ba = (key << 6) + (l4 << 4); ba ^= ((key & 7) << 4);
      bf16x8 kf = *(const bf16x8*)(sKb + ba);
      s[s4] = __builtin_amdgcn_mfma_f32_16x16x32_bf16(kf, qf, zero, 0, 0, 0);
    }
    // softmax (lane owns q = q0+l15; keys s4*16 + l4*4 + j per subtile)
    float tmax = -1e30f;
    #pragma unroll
    for (int s4 = 0; s4 < 4; ++s4)
      #pragma unroll
      for (int j = 0; j < 4; ++j) tmax = fmaxf(tmax, s[s4][j]);
    tmax = fmaxf(tmax, __shfl_xor(tmax, 16));
    tmax = fmaxf(tmax, __shfl_xor(tmax, 32));
    float mnew = fmaxf(m, tmax);
    float corr = __expf(m - mnew);
    float psum = 0.0f;
    unsigned short pb[4][4];
    #pragma unroll
    for (int s4 = 0; s4 < 4; ++s4)
      #pragma unroll
      for (int j = 0; j < 4; ++j) {
        float p = __expf(s[s4][j] - mnew);
        psum += p;
        pb[s4][j] = f2bf(p);
      }
    psum += __shfl_xor(psum, 16);
    psum += __shfl_xor(psum, 32);
    l = l * corr + psum;
    m = mnew;
    oacc[0] *= corr;
    oacc[1] *= corr;
    // write P^T fragment source: sP[q=l15][key], 4 bf16 per subtile
    #pragma unroll
    for (int s4 = 0; s4 < 4; ++s4) {
      unsigned long long pk =
          (unsigned long long)pb[s4][0] | ((unsigned long long)pb[s4][1] << 16) |
          ((unsigned long long)pb[s4][2] << 32) | ((unsigned long long)pb[s4][3] << 48);
      int bp = (l15 << 7) + (s4 << 5) + (l4 << 3); bp ^= ((l15 & 7) << 4);
      *(unsigned long long*)(sPw + bp) = pk;
    }
    __syncthreads();   // sP visible (also orders lgkm)

    // PV: O^T[d][q] += V^T[d][keys] * P^T[keys][q]
    #pragma unroll
    for (int dh = 0; dh < 2; ++dh)
      #pragma unroll
      for (int kh = 0; kh < 2; ++kh) {
        int d = dh * 16 + l15;
        int ba = (d << 7) + ((kh * 32 + l4 * 8) << 1); ba ^= ((d & 7) << 4);
        bf16x8 vf = *(const bf16x8*)(sVb + ba);
        int bp = (l15 << 7) + (kh << 6) + (l4 << 4); bp ^= ((l15 & 7) << 4);
        bf16x8 pf = *(const bf16x8*)(sPw + bp);
        oacc[dh] = __builtin_amdgcn_mfma_f32_16x16x32_bf16(vf, pf, oacc[dh], 0, 0, 0);
      }
  }

  float inv = 1.0f / l;
  float* orow = O + base + (size_t)(q0 + l15) * DD;
  #pragma unroll
  for (int dh = 0; dh < 2; ++dh) {
    float4 o4 = {oacc[dh][0] * inv, oacc[dh][1] * inv,
                 oacc[dh][2] * inv, oacc[dh][3] * inv};
    *(float4*)&orow[dh * 16 + l4 * 4] = o4;
  }
}

// ---------------- fp32 copy-out with dst stride ----------
__global__ __launch_bounds__(256) void store_out_kernel(
    const float* __restrict__ src, float* __restrict__ dst, int dst_ld)
{
  int r = blockIdx.x;
  int j = threadIdx.x;
  dst[(size_t)r * dst_ld + j] = src[(size_t)r * DD + j];
}

__global__ __launch_bounds__(256) void fill_kernel(float* p, long n, float v)
{
  long i = (long)blockIdx.x * 256 + threadIdx.x;
  if (i < n) p[i] = v;
}

extern "C" void kernel_launch(void* const* d_in, const int* in_sizes, int n_in,
                              void* d_out, int out_size, void* d_ws, size_t ws_size,
                              hipStream_t stream)
{
  const float* x     = (const float*)d_in[0];
  const int*   Acg_r = (const int*)d_in[1];
  const int*   Acg_c = (const int*)d_in[2];
  const float* Acg_v = (const float*)d_in[3];
  const int*   Ahy_r = (const int*)d_in[4];
  const int*   Ahy_c = (const int*)d_in[5];
  const float* Ahy_v = (const float*)d_in[6];
  const int*   Asg_r = (const int*)d_in[7];
  const int*   Asg_c = (const int*)d_in[8];
  const float* Asg_v = (const float*)d_in[9];
  const int*   Lcg_r = (const int*)d_in[10];
  const int*   Lcg_c = (const int*)d_in[11];
  const float* Lcg_v = (const float*)d_in[12];
  const int*   Lhy_r = (const int*)d_in[13];
  const int*   Lhy_c = (const int*)d_in[14];
  const float* Lhy_v = (const float*)d_in[15];
  const int*   Lsg_r = (const int*)d_in[16];
  const int*   Lsg_c = (const int*)d_in[17];
  const float* Lsg_v = (const float*)d_in[18];
  const float* cg_W  = (const float*)d_in[19];
  const float* cg_b  = (const float*)d_in[20];
  const float* hg_W  = (const float*)d_in[21];
  const float* hg_b  = (const float*)d_in[22];
  const float* sg_W  = (const float*)d_in[23];
  const float* sg_b  = (const float*)d_in[24];
  const float* snh_W = (const float*)d_in[25];
  const float* snh_b = (const float*)d_in[26];
  const float* snc_W = (const float*)d_in[27];
  const float* snc_b = (const float*)d_in[28];
  const float* sns_W = (const float*)d_in[29];
  const float* sns_b = (const float*)d_in[30];
  const float* spa_hyp_W  = (const float*)d_in[31];
  const float* spa_hyp_b  = (const float*)d_in[32];
  const float* spa_star_W = (const float*)d_in[33];
  const float* spa_star_b = (const float*)d_in[34];
  const float* spa_clq_W  = (const float*)d_in[35];
  const float* spa_clq_b  = (const float*)d_in[36];
  const float* spa_in_w   = (const float*)d_in[37];
  const float* spa_in_b   = (const float*)d_in[38];
  const float* spa_out_w  = (const float*)d_in[39];
  const float* spa_out_b  = (const float*)d_in[40];
  const float* spe_hyp_W  = (const float*)d_in[41];
  const float* spe_hyp_b  = (const float*)d_in[42];
  const float* spe_star_W = (const float*)d_in[43];
  const float* spe_star_b = (const float*)d_in[44];
  const float* spe_clq_W  = (const float*)d_in[45];
  const float* spe_clq_b  = (const float*)d_in[46];
  const float* spe_in_w   = (const float*)d_in[47];
  const float* spe_in_b   = (const float*)d_in[48];
  const float* spe_out_w  = (const float*)d_in[49];
  const float* spe_out_b  = (const float*)d_in[50];

  float* out = (float*)d_out;

  const size_t NF = (size_t)NN * DD;
  const size_t MF = (size_t)MM * DD;
  const size_t WELEMS = 23u * 65536u;
  const size_t EDG_TOT = 4 * (size_t)NEN + 2 * (size_t)NEM;        // 3,112,960
  const size_t RP_TOT  = 4 * (size_t)(NN + 1) + 2 * (size_t)(MM + 1);
  const size_t need = (3 * MF + 6 * NF) * 4          // float buffers
                    + (RP_TOT + 2 * EDG_TOT + MM + 256) * 4  // csr ints/floats
                    + WELEMS * 2;                     // bf16 weights

  auto fill = [&](float v) {
    long tot = (long)out_size;
    fill_kernel<<<dim3((unsigned)((tot + 255) / 256)), 256, 0, stream>>>(out, tot, v);
  };
  if (ws_size < need)                        { fill(12.0f); return; }
  if (n_in != 51)                            { fill(16.0f); return; }
  if (in_sizes[0] != NN * FD)                { fill(20.0f); return; }
  if (in_sizes[3] != NEN)                    { fill(24.0f); return; }
  if (in_sizes[9] != NEM)                    { fill(28.0f); return; }
  if (in_sizes[19] != 2 * FD * DD)           { fill(32.0f); return; }
  if (in_sizes[37] != 3 * DD * DD)           { fill(36.0f); return; }
  if (out_size != NN * 512 + NN * DD + EHN * DD) { fill(40.0f); return; }

  // ---- float buffers ----
  float* T  = (float*)d_ws;     // M staging
  float* H  = T + MF;           // M expan hidden
  float* SG = H + MF;           // sg_feat (M)
  float* CG = SG + MF;          // cg_feat (N)
  float* HG = CG + NF;          // hg_feat (N)
  float* XH = HG + NF;          // X_hyp (N)
  float* XS = XH + NF;          // X_sg[:N]
  float* KH = XS + NF;          // K heads; also aliases XC (disjoint lifetime)
  float* VH = KH + NF;          // V heads
  float* XC = KH;               // alias: XC consumed into T before KH written
  float* QH = XS;               // alias: XS consumed before QH written
  float* AO = XH;               // alias: XH consumed before attention output

  // ---- int/bf16 region ----
  int* ip = (int*)(VH + NF);
  int* rp_cg  = ip;              ip += NN + 1;
  int* rp_hy  = ip;              ip += NN + 1;
  int* rp_sg  = ip;              ip += MM + 1;
  int* rp_Lcg = ip;              ip += NN + 1;
  int* rp_Lhy = ip;              ip += NN + 1;
  int* rp_Lsg = ip;              ip += MM + 1;
  int* ec_cg  = ip;              ip += NEN;
  int* ec_hy  = ip;              ip += NEN;
  int* ec_sg  = ip;              ip += NEM;
  int* ec_Lcg = ip;              ip += NEN;
  int* ec_Lhy = ip;              ip += NEN;
  int* ec_Lsg = ip;              ip += NEM;
  float* ev_cg  = (float*)ip;    ip += NEN;
  float* ev_hy  = (float*)ip;    ip += NEN;
  float* ev_sg  = (float*)ip;    ip += NEM;
  float* ev_Lcg = (float*)ip;    ip += NEN;
  float* ev_Lhy = (float*)ip;    ip += NEN;
  float* ev_Lsg = (float*)ip;    ip += NEM;
  int* cnt  = ip;                ip += MM;
  int* bsum = ip;                ip += 256;
  unsigned short* WB = (unsigned short*)ip;

  auto wslot = [&](int s) { return WB + (size_t)s * 65536; };
  auto castw = [&](const float* src, unsigned short* dst, int Nr, int T_) {
    cast_w_kernel<<<dim3(Nr), 256, 0, stream>>>(src, dst, Nr, T_);
  };
  auto gemm = [&](const float* A, const unsigned short* Wt, const float* bias,
                  float* C, int Mrows, bool relu) {
    gemm_mfma_kernel<<<dim3(Mrows / 128), 512, 0, stream>>>(
        A, Wt, bias, C, Mrows, relu ? 1 : 0);
  };
  auto build_csr = [&](const int* rw, const int* cl, const float* vl, int nnz,
                       int nrows, int* rowptr, int* ecol, float* eval) {
    hipMemsetAsync(cnt, 0, (size_t)nrows * 4, stream);
    count_kernel<<<dim3((nnz + 255) / 256), 256, 0, stream>>>(rw, cnt, nnz);
    int nb = (nrows + 255) / 256;
    scan1_kernel<<<dim3(nb), 256, 0, stream>>>(cnt, bsum, nrows);
    scan2_kernel<<<dim3(1), 256, 0, stream>>>(bsum, nb);
    scan3_kernel<<<dim3(nb), 256, 0, stream>>>(cnt, bsum, rowptr, nrows);
    hipMemsetAsync(cnt, 0, (size_t)nrows * 4, stream);
    fillcsr_kernel<<<dim3((nnz + 255) / 256), 256, 0, stream>>>(
        rw, cl, vl, rowptr, cnt, ecol, eval, nnz);
  };
  auto spmm = [&](const int* rowptr, const int* ecol, const float* eval,
                  const float* X, float* Y, int srcR, int dstR,
                  const float* bias, bool relu) {
    csr_spmm_kernel<<<dim3(dstR), 256, 0, stream>>>(
        rowptr, ecol, eval, X, Y, srcR, bias, relu ? 1 : 0);
  };
  auto attn = [&](const float* Qp, const float* Kp, const float* Vp, float* Op) {
    attn_mfma_kernel<<<dim3(CHK / 64, NHEADS, NN / CHK), 256, 0, stream>>>(
        Qp, Kp, Vp, Op);
  };
  auto storeout = [&](const float* src, float* dst, int rows, int ldd) {
    store_out_kernel<<<dim3(rows), 256, 0, stream>>>(src, dst, ldd);
  };

  // ================= weight prep =================
  castw(cg_W,           wslot(0), 256, 1);
  castw(cg_W + FD * DD, wslot(1), 256, 1);
  castw(hg_W,           wslot(2), 256, 1);
  castw(hg_W + FD * DD, wslot(3), 256, 1);
  castw(sg_W,           wslot(4), 256, 1);
  castw(sg_W + FD * DD, wslot(5), 256, 1);
  castw(snh_W,          wslot(6), 256, 0);
  castw(snc_W,          wslot(7), 256, 0);
  castw(sns_W,          wslot(8), 256, 0);
  castw(spa_hyp_W,      wslot(9), 256, 0);
  castw(spa_star_W,     wslot(10), 256, 0);
  castw(spa_clq_W,      wslot(11), 256, 0);
  castw(spa_out_w,      wslot(12), 256, 0);
  castw(spa_in_w,       wslot(13), 768, 0);  // 13,14,15 = wq,wk,wv
  castw(spe_hyp_W,      wslot(16), 256, 0);
  castw(spe_star_W,     wslot(17), 256, 0);
  castw(spe_clq_W,      wslot(18), 256, 0);
  castw(spe_out_w,      wslot(19), 256, 0);
  castw(spe_in_w,       wslot(20), 768, 0);  // 20,21,22

  // ================= CSR builds (6 graphs) =================
  build_csr(Acg_r, Acg_c, Acg_v, NEN, NN, rp_cg, ec_cg, ev_cg);
  build_csr(Ahy_r, Ahy_c, Ahy_v, NEN, NN, rp_hy, ec_hy, ev_hy);
  build_csr(Asg_r, Asg_c, Asg_v, NEM, MM, rp_sg, ec_sg, ev_sg);
  build_csr(Lcg_r, Lcg_c, Lcg_v, NEN, NN, rp_Lcg, ec_Lcg, ev_Lcg);
  build_csr(Lhy_r, Lhy_c, Lhy_v, NEN, NN, rp_Lhy, ec_Lhy, ev_Lhy);
  build_csr(Lsg_r, Lsg_c, Lsg_v, NEM, MM, rp_Lsg, ec_Lsg, ev_Lsg);

  // ================= expansion nets =================
  gemm(x, wslot(0), nullptr, T, NN, false);
  spmm(rp_cg, ec_cg, ev_cg, T, H, NN, NN, cg_b, true);
  gemm(H, wslot(1), nullptr, T, NN, false);
  spmm(rp_cg, ec_cg, ev_cg, T, CG, NN, NN, cg_b + DD, false);

  gemm(x, wslot(2), nullptr, T, NN, false);
  spmm(rp_hy, ec_hy, ev_hy, T, H, NN, NN, hg_b, true);
  gemm(H, wslot(3), nullptr, T, NN, false);
  spmm(rp_hy, ec_hy, ev_hy, T, HG, NN, NN, hg_b + DD, false);

  // sg: x_star rows >= NN are zero -> src_rows=NN on first spmm
  gemm(x, wslot(4), nullptr, T, NN, false);
  spmm(rp_sg, ec_sg, ev_sg, T, H, NN, MM, sg_b, true);
  gemm(H, wslot(5), nullptr, T, MM, false);
  spmm(rp_sg, ec_sg, ev_sg, T, SG, MM, MM, sg_b + DD, false);

  // outputs: X_star = sg_feat[:N], S_star = sg_feat[N:]
  storeout(SG, out + (size_t)NN * 512, NN, DD);
  storeout(SG + NF, out + (size_t)NN * 512 + NF, EHN, DD);

  // ================= sn projections + Laplacian spmm =================
  gemm(HG, wslot(6), snh_b, T, NN, false);
  spmm(rp_Lhy, ec_Lhy, ev_Lhy, T, XH, NN, NN, nullptr, false);
  gemm(CG, wslot(7), snc_b, T, NN, false);
  spmm(rp_Lcg, ec_Lcg, ev_Lcg, T, XC, NN, NN, nullptr, false);
  gemm(SG, wslot(8), sns_b, T, MM, false);
  spmm(rp_Lsg, ec_Lsg, ev_Lsg, T, XS, MM, NN, nullptr, false);  // rows < N only

  // ================= spectral MHA (v, then q, then k) =================
  gemm(XS, wslot(18), spe_clq_b, T, NN, false);
  gemm(T, wslot(22), spe_in_b + 2 * DD, VH, NN, false);
  gemm(XH, wslot(16), spe_hyp_b, T, NN, false);
  gemm(T, wslot(20), spe_in_b, QH, NN, false);
  gemm(XC, wslot(17), spe_star_b, T, NN, false);   // XC aliases KH; read first
  gemm(T, wslot(21), spe_in_b + DD, KH, NN, false);
  attn(QH, KH, VH, AO);
  gemm(AO, wslot(19), spe_out_b, T, NN, false);
  storeout(T, out + DD, NN, 2 * DD);               // taa cols 256..511

  // ================= spatial MHA =================
  gemm(SG, wslot(11), spa_clq_b, T, NN, false);    // X_star = SG[:N]
  gemm(T, wslot(15), spa_in_b + 2 * DD, VH, NN, false);
  gemm(HG, wslot(9), spa_hyp_b, T, NN, false);
  gemm(T, wslot(13), spa_in_b, QH, NN, false);
  gemm(CG, wslot(10), spa_star_b, T, NN, false);
  gemm(T, wslot(14), spa_in_b + DD, KH, NN, false);
  attn(QH, KH, VH, AO);
  gemm(AO, wslot(12), spa_out_b, T, NN, false);
  storeout(T, out, NN, 2 * DD);                    // taa cols 0..255
}

// Round 5
// 2538.006 us; speedup vs baseline: 3.4016x; 1.1280x over previous
//
#include <hip/hip_runtime.h>

// Problem dims (fixed by reference)
#define NN 49152
#define EHN 8192
#define MM (NN + EHN)       // 57344
#define FD 256
#define DD 256
#define NHEADS 8
#define DHEAD 32
#define CHK 1024
#define NEN (10 * NN)       // 491520
#define NEM (10 * MM)       // 573440

typedef __bf16 bf16x8 __attribute__((ext_vector_type(8)));
typedef unsigned short u16x8 __attribute__((ext_vector_type(8)));
typedef float f32x4 __attribute__((ext_vector_type(4)));

// fp32 -> bf16 bits, round-to-nearest-even
static __device__ __forceinline__ unsigned short f2bf(float f) {
  unsigned int u = __float_as_uint(f);
  unsigned int r = (u + 0x7FFFu + ((u >> 16) & 1u)) >> 16;
  return (unsigned short)r;
}

// ---------------- weight prep: cast (and optionally transpose) to bf16 ------
__global__ __launch_bounds__(256) void cast_w_kernel(
    const float* __restrict__ src, unsigned short* __restrict__ dst,
    int Nr, int T)
{
  int i = blockIdx.x * 256 + threadIdx.x;
  int n = i >> 8, k = i & 255;
  float f = T ? src[(size_t)k * Nr + n] : src[i];
  dst[i] = f2bf(f);
}

// ---------------- combined weight: Wc = Bw @ Aw (bf16), bc = Bw@ab + bb -----
// y = (u@Aw.T + ab)@Bw.T + bb  ==  u@Wc.T + bc.  fscale folds softmax scale.
__global__ __launch_bounds__(256) void combine_w_kernel(
    const float* __restrict__ Bw, const float* __restrict__ Aw,
    const float* __restrict__ ab, const float* __restrict__ bb,
    unsigned short* __restrict__ Wc, float* __restrict__ bc, float fscale)
{
  int n = blockIdx.x, t = threadIdx.x;
  __shared__ float shB[256];
  __shared__ float red[256];
  shB[t] = Bw[n * 256 + t];
  __syncthreads();
  float acc = 0.0f;
  #pragma unroll 8
  for (int j = 0; j < 256; ++j) acc += shB[j] * Aw[j * 256 + t];
  Wc[n * 256 + t] = f2bf(acc * fscale);
  red[t] = shB[t] * ab[t];
  __syncthreads();
  for (int off = 128; off; off >>= 1) {
    if (t < off) red[t] += red[t + off];
    __syncthreads();
  }
  if (t == 0) bc[n] = (red[0] + bb[n]) * fscale;
}

// ---------------- bf16-MFMA GEMM v2: C = A[M][256] * Wt^T  ------------------
// 64x256 tile, 256 threads (4 waves), BK=32, double-buffered LDS; loads for
// tile k+1 issued before computing tile k (latency hidden under MFMA + the
// 3 co-resident blocks/CU). OUTBF=1 writes bf16 (for QKV), else fp32 w/ ldc.
template<int OUTBF>
__global__ __launch_bounds__(256) void gemm2_kernel(
    const float* __restrict__ A, const unsigned short* __restrict__ Wt,
    const float* __restrict__ bias, void* __restrict__ Cout,
    int ldc, int coff, int relu)
{
  __shared__ __align__(16) char sA[2][4096];    // [64 r][32 k] bf16, swz
  __shared__ __align__(16) char sB[2][16384];   // [256 n][32 k] bf16, swz
  const int tid = threadIdx.x, lane = tid & 63, wid = tid >> 6;
  const int l15 = lane & 15, l4 = lane >> 4;
  const int bm = blockIdx.x * 64;

  f32x4 acc[16] = {};
  const int ar = tid >> 2, akq = (tid & 3) * 8;   // A stage: row, k-offset
  const int bn = tid;                              // B stage: n-row

  float4 fa0, fa1;
  u16x8 rb0, rb1, rb2, rb3;
  auto stage_load = [&](int k0) {
    const float* ap = A + (size_t)(bm + ar) * 256 + k0 + akq;
    fa0 = *(const float4*)ap;
    fa1 = *(const float4*)(ap + 4);
    const unsigned short* bp = Wt + (size_t)bn * 256 + k0;
    rb0 = *(const u16x8*)bp;       rb1 = *(const u16x8*)(bp + 8);
    rb2 = *(const u16x8*)(bp + 16); rb3 = *(const u16x8*)(bp + 24);
  };
  auto stage_write = [&](int buf) {
    u16x8 va;
    va[0] = f2bf(fa0.x); va[1] = f2bf(fa0.y); va[2] = f2bf(fa0.z); va[3] = f2bf(fa0.w);
    va[4] = f2bf(fa1.x); va[5] = f2bf(fa1.y); va[6] = f2bf(fa1.z); va[7] = f2bf(fa1.w);
    int aa = ((ar << 6) + (akq << 1)) ^ ((ar & 7) << 4);
    *(u16x8*)(sA[buf] + aa) = va;
    int bb = (bn << 6) ^ ((bn & 7) << 4);
    *(u16x8*)(sB[buf] + bb) = rb0;
    *(u16x8*)(sB[buf] + (bb ^ 16)) = rb1;   // +16B within row, swz-safe
    *(u16x8*)(sB[buf] + (bb ^ 32)) = rb2;
    *(u16x8*)(sB[buf] + (bb ^ 48)) = rb3;
  };

  stage_load(0);
  stage_write(0);
  __syncthreads();
  int cur = 0;
  for (int it = 0; it < 8; ++it) {
    if (it < 7) stage_load((it + 1) * 32);
    int ra = wid * 16 + l15;
    bf16x8 af = *(const bf16x8*)(sA[cur] + ((ra << 6) + (l4 << 4) ^ ((ra & 7) << 4)));
    #pragma unroll
    for (int n4 = 0; n4 < 16; ++n4) {
      int rn = n4 * 16 + l15;
      bf16x8 bf = *(const bf16x8*)(sB[cur] + ((rn << 6) + (l4 << 4) ^ ((rn & 7) << 4)));
      acc[n4] = __builtin_amdgcn_mfma_f32_16x16x32_bf16(af, bf, acc[n4], 0, 0, 0);
    }
    __syncthreads();
    if (it < 7) {
      stage_write(cur ^ 1);
      __syncthreads();
      cur ^= 1;
    }
  }
  const int row = bm + wid * 16 + l4 * 4;
  #pragma unroll
  for (int n4 = 0; n4 < 16; ++n4) {
    int col = n4 * 16 + l15;
    float bbv = bias ? bias[col] : 0.0f;
    #pragma unroll
    for (int j = 0; j < 4; ++j) {
      float v = acc[n4][j] + bbv;
      if (relu) v = fmaxf(v, 0.0f);
      if (OUTBF)
        ((unsigned short*)Cout)[(size_t)(row + j) * 256 + col] = f2bf(v);
      else
        ((float*)Cout)[(size_t)(row + j) * ldc + coff + col] = v;
    }
  }
}

// ================= CSR build =================
__global__ __launch_bounds__(256) void count_kernel(
    const int* __restrict__ rw, int* __restrict__ cnt, int nnz)
{
  int e = blockIdx.x * 256 + threadIdx.x;
  if (e < nnz) atomicAdd(&cnt[rw[e]], 1);
}

__global__ __launch_bounds__(256) void scan1_kernel(
    const int* __restrict__ cnt, int* __restrict__ bsum, int n)
{
  __shared__ int sh[256];
  int i = blockIdx.x * 256 + threadIdx.x;
  sh[threadIdx.x] = (i < n) ? cnt[i] : 0;
  __syncthreads();
  for (int off = 128; off; off >>= 1) {
    if (threadIdx.x < off) sh[threadIdx.x] += sh[threadIdx.x + off];
    __syncthreads();
  }
  if (threadIdx.x == 0) bsum[blockIdx.x] = sh[0];
}

__global__ __launch_bounds__(256) void scan2_kernel(int* __restrict__ bsum, int nb)
{
  __shared__ int sh[256];
  int v = (threadIdx.x < nb) ? bsum[threadIdx.x] : 0;
  sh[threadIdx.x] = v;
  __syncthreads();
  for (int off = 1; off < 256; off <<= 1) {
    int add = (threadIdx.x >= off) ? sh[threadIdx.x - off] : 0;
    __syncthreads();
    sh[threadIdx.x] += add;
    __syncthreads();
  }
  if (threadIdx.x < nb) bsum[threadIdx.x] = sh[threadIdx.x] - v;  // exclusive
}

__global__ __launch_bounds__(256) void scan3_kernel(
    const int* __restrict__ cnt, const int* __restrict__ bsum,
    int* __restrict__ rowptr, int n)
{
  __shared__ int sh[256];
  int i = blockIdx.x * 256 + threadIdx.x;
  int v = (i < n) ? cnt[i] : 0;
  sh[threadIdx.x] = v;
  __syncthreads();
  for (int off = 1; off < 256; off <<= 1) {
    int add = (threadIdx.x >= off) ? sh[threadIdx.x - off] : 0;
    __syncthreads();
    sh[threadIdx.x] += add;
    __syncthreads();
  }
  int incl = sh[threadIdx.x];
  int base = bsum[blockIdx.x];
  if (i < n) rowptr[i] = base + incl - v;
  if (i == n - 1) rowptr[n] = base + incl;
}

__global__ __launch_bounds__(256) void fillcsr_kernel(
    const int* __restrict__ rw, const int* __restrict__ cl,
    const float* __restrict__ vl, const int* __restrict__ rowptr,
    int* __restrict__ cur, int* __restrict__ ecol, float* __restrict__ eval,
    int nnz)
{
  int e = blockIdx.x * 256 + threadIdx.x;
  if (e < nnz) {
    int r = rw[e];
    int pos = rowptr[r] + atomicAdd(&cur[r], 1);
    ecol[pos] = cl[e];
    eval[pos] = vl[e];
  }
}

// ---------------- CSR SpMM: one block per dst row; fused bias/relu ----------
// Optional dual write Y2 (used to emit X_star/S_star directly to d_out).
__global__ __launch_bounds__(256) void csr_spmm_kernel(
    const int* __restrict__ rowptr, const int* __restrict__ ecol,
    const float* __restrict__ eval, const float* __restrict__ X,
    float* __restrict__ Y, int src_rows, const float* __restrict__ bias,
    int relu, float* __restrict__ Y2)
{
  int r = blockIdx.x, t = threadIdx.x;
  int beg = rowptr[r], end = rowptr[r + 1];
  float acc = 0.0f;
  for (int e = beg; e < end; ++e) {
    int c = ecol[e];
    float v = eval[e];
    if (c < src_rows) acc += v * X[(size_t)c * DD + t];
  }
  if (bias) acc += bias[t];
  if (relu) acc = fmaxf(acc, 0.0f);
  Y[(size_t)r * DD + t] = acc;
  if (Y2) Y2[(size_t)r * DD + t] = acc;
}

// ---------------- MFMA flash attention (bf16 Q/K/V; scale pre-folded) -------
__global__ __launch_bounds__(256) void attn_mfma_kernel(
    const unsigned short* __restrict__ Q, const unsigned short* __restrict__ K,
    const unsigned short* __restrict__ V, float* __restrict__ O)
{
  __shared__ __align__(16) char sKb[4096];   // [64 key][32 d], swz (key&7)<<4
  __shared__ __align__(16) char sVb[4096];   // [32 d][64 key], swz d-fold
  __shared__ __align__(16) char sPb[8192];   // per-wave [16 q][64 key]
  const int c = blockIdx.z, h = blockIdx.y;
  const int tid = threadIdx.x, lane = tid & 63, wid = tid >> 6;
  const int l15 = lane & 15, l4 = lane >> 4;
  char* sPw = sPb + wid * 2048;
  const size_t base = (size_t)c * (CHK * DD) + (size_t)h * DHEAD;
  const int q0 = blockIdx.x * 64 + wid * 16;

  bf16x8 qf = *(const bf16x8*)(Q + base + (size_t)(q0 + l15) * DD + l4 * 8);

  f32x4 oacc[2] = {};
  float m = -1e30f, l = 0.0f;
  const f32x4 zero = {};

  for (int kt = 0; kt < CHK; kt += 64) {
    __syncthreads();
    {
      int key = tid >> 2, dq = (tid & 3) * 8;
      u16x8 kv = *(const u16x8*)(K + base + (size_t)(kt + key) * DD + dq);
      int ba = (key << 6) + (dq << 1); ba ^= ((key & 7) << 4);
      *(u16x8*)(sKb + ba) = kv;
      u16x8 vv = *(const u16x8*)(V + base + (size_t)(kt + key) * DD + dq);
      #pragma unroll
      for (int i = 0; i < 8; ++i) {
        int d = dq + i;
        int bb = (d << 7) + (key << 1);
        bb ^= ((d & 7) << 4) ^ (((d >> 3) & 3) << 5);
        *(unsigned short*)(sVb + bb) = vv[i];
      }
    }
    __syncthreads();

    f32x4 s[4];
    #pragma unroll
    for (int s4 = 0; s4 < 4; ++s4) {
      int key = s4 * 16 + l15;
      int ba = (key << 6) + (l4 << 4); ba ^= ((key & 7) << 4);
      bf16x8 kf = *(const bf16x8*)(sKb + ba);
      s[s4] = __builtin_amdgcn_mfma_f32_16x16x32_bf16(kf, qf, zero, 0, 0, 0);
    }
    float tmax = -1e30f;
    #pragma unroll
    for (int s4 = 0; s4 < 4; ++s4)
      #pragma unroll
      for (int j = 0; j < 4; ++j) tmax = fmaxf(tmax, s[s4][j]);
    tmax = fmaxf(tmax, __shfl_xor(tmax, 16));
    tmax = fmaxf(tmax, __shfl_xor(tmax, 32));
    float mnew = fmaxf(m, tmax);
    float corr = __expf(m - mnew);
    float psum = 0.0f;
    unsigned short pb[4][4];
    #pragma unroll
    for (int s4 = 0; s4 < 4; ++s4)
      #pragma unroll
      for (int j = 0; j < 4; ++j) {
        float p = __expf(s[s4][j] - mnew);
        psum += p;
        pb[s4][j] = f2bf(p);
      }
    psum += __shfl_xor(psum, 16);
    psum += __shfl_xor(psum, 32);
    l = l * corr + psum;
    m = mnew;
    oacc[0] *= corr;
    oacc[1] *= corr;
    #pragma unroll
    for (int s4 = 0; s4 < 4; ++s4) {
      unsigned long long pk =
          (unsigned long long)pb[s4][0] | ((unsigned long long)pb[s4][1] << 16) |
          ((unsigned long long)pb[s4][2] << 32) | ((unsigned long long)pb[s4][3] << 48);
      int bp = (l15 << 7) + (s4 << 5) + (l4 << 3); bp ^= ((l15 & 7) << 4);
      *(unsigned long long*)(sPw + bp) = pk;
    }
    __syncthreads();

    #pragma unroll
    for (int dh = 0; dh < 2; ++dh)
      #pragma unroll
      for (int kh = 0; kh < 2; ++kh) {
        int d = dh * 16 + l15;
        int ba = (d << 7) + ((kh * 32 + l4 * 8) << 1);
        ba ^= ((d & 7) << 4) ^ (((d >> 3) & 3) << 5);
        bf16x8 vf = *(const bf16x8*)(sVb + ba);
        int bp = (l15 << 7) + (kh << 6) + (l4 << 4); bp ^= ((l15 & 7) << 4);
        bf16x8 pf = *(const bf16x8*)(sPw + bp);
        oacc[dh] = __builtin_amdgcn_mfma_f32_16x16x32_bf16(vf, pf, oacc[dh], 0, 0, 0);
      }
  }

  float inv = 1.0f / l;
  float* orow = O + base + (size_t)(q0 + l15) * DD;
  #pragma unroll
  for (int dh = 0; dh < 2; ++dh) {
    float4 o4 = {oacc[dh][0] * inv, oacc[dh][1] * inv,
                 oacc[dh][2] * inv, oacc[dh][3] * inv};
    *(float4*)&orow[dh * 16 + l4 * 4] = o4;
  }
}

// sentinel: error value identifies which runtime check failed
__global__ __launch_bounds__(256) void fill_kernel(float* p, long n, float v)
{
  long i = (long)blockIdx.x * 256 + threadIdx.x;
  if (i < n) p[i] = v;
}

extern "C" void kernel_launch(void* const* d_in, const int* in_sizes, int n_in,
                              void* d_out, int out_size, void* d_ws, size_t ws_size,
                              hipStream_t stream)
{
  const float* x     = (const float*)d_in[0];
  const int*   Acg_r = (const int*)d_in[1];
  const int*   Acg_c = (const int*)d_in[2];
  const float* Acg_v = (const float*)d_in[3];
  const int*   Ahy_r = (const int*)d_in[4];
  const int*   Ahy_c = (const int*)d_in[5];
  const float* Ahy_v = (const float*)d_in[6];
  const int*   Asg_r = (const int*)d_in[7];
  const int*   Asg_c = (const int*)d_in[8];
  const float* Asg_v = (const float*)d_in[9];
  const int*   Lcg_r = (const int*)d_in[10];
  const int*   Lcg_c = (const int*)d_in[11];
  const float* Lcg_v = (const float*)d_in[12];
  const int*   Lhy_r = (const int*)d_in[13];
  const int*   Lhy_c = (const int*)d_in[14];
  const float* Lhy_v = (const float*)d_in[15];
  const int*   Lsg_r = (const int*)d_in[16];
  const int*   Lsg_c = (const int*)d_in[17];
  const float* Lsg_v = (const float*)d_in[18];
  const float* cg_W  = (const float*)d_in[19];
  const float* cg_b  = (const float*)d_in[20];
  const float* hg_W  = (const float*)d_in[21];
  const float* hg_b  = (const float*)d_in[22];
  const float* sg_W  = (const float*)d_in[23];
  const float* sg_b  = (const float*)d_in[24];
  const float* snh_W = (const float*)d_in[25];
  const float* snh_b = (const float*)d_in[26];
  const float* snc_W = (const float*)d_in[27];
  const float* snc_b = (const float*)d_in[28];
  const float* sns_W = (const float*)d_in[29];
  const float* sns_b = (const float*)d_in[30];
  const float* spa_hyp_W  = (const float*)d_in[31];
  const float* spa_hyp_b  = (const float*)d_in[32];
  const float* spa_star_W = (const float*)d_in[33];
  const float* spa_star_b = (const float*)d_in[34];
  const float* spa_clq_W  = (const float*)d_in[35];
  const float* spa_clq_b  = (const float*)d_in[36];
  const float* spa_in_w   = (const float*)d_in[37];
  const float* spa_in_b   = (const float*)d_in[38];
  const float* spa_out_w  = (const float*)d_in[39];
  const float* spa_out_b  = (const float*)d_in[40];
  const float* spe_hyp_W  = (const float*)d_in[41];
  const float* spe_hyp_b  = (const float*)d_in[42];
  const float* spe_star_W = (const float*)d_in[43];
  const float* spe_star_b = (const float*)d_in[44];
  const float* spe_clq_W  = (const float*)d_in[45];
  const float* spe_clq_b  = (const float*)d_in[46];
  const float* spe_in_w   = (const float*)d_in[47];
  const float* spe_in_b   = (const float*)d_in[48];
  const float* spe_out_w  = (const float*)d_in[49];
  const float* spe_out_b  = (const float*)d_in[50];

  float* out = (float*)d_out;

  const size_t NF = (size_t)NN * DD;
  const size_t MF = (size_t)MM * DD;
  const size_t EDG_TOT = 4 * (size_t)NEN + 2 * (size_t)NEM;
  const size_t RP_TOT  = 4 * (size_t)(NN + 1) + 2 * (size_t)(MM + 1);
  const size_t WELEMS  = 17u * 65536u;
  const size_t need = (3 * MF + 5 * NF) * 4        // fp32 buffers
                    + NF * 2                        // VHu (bf16)
                    + (RP_TOT + 2 * EDG_TOT + MM + 256) * 4
                    + WELEMS * 2 + 1536 * 4;

  auto fill = [&](float v) {
    long tot = (long)out_size;
    fill_kernel<<<dim3((unsigned)((tot + 255) / 256)), 256, 0, stream>>>(out, tot, v);
  };
  if (ws_size < need)                        { fill(12.0f); return; }
  if (n_in != 51)                            { fill(16.0f); return; }
  if (in_sizes[0] != NN * FD)                { fill(20.0f); return; }
  if (in_sizes[3] != NEN)                    { fill(24.0f); return; }
  if (in_sizes[9] != NEM)                    { fill(28.0f); return; }
  if (in_sizes[19] != 2 * FD * DD)           { fill(32.0f); return; }
  if (in_sizes[37] != 3 * DD * DD)           { fill(36.0f); return; }
  if (out_size != NN * 512 + NN * DD + EHN * DD) { fill(40.0f); return; }

  // ---- fp32 buffers ----
  float* T  = (float*)d_ws;     // M staging
  float* H  = T + MF;           // M expan hidden
  float* SG = H + MF;           // sg_feat (M)
  float* CG = SG + MF;          // cg_feat (N)
  float* HG = CG + NF;          // hg_feat (N)
  float* XH = HG + NF;          // X_hyp (N)
  float* XC = XH + NF;          // X_cg (N)
  float* XS = XC + NF;          // X_sg[:N]
  unsigned short* VHu = (unsigned short*)(XS + NF);    // V heads bf16
  // aliases (disjoint lifetimes, verified in sequence below):
  unsigned short* QHu = (unsigned short*)XS;           // after XS consumed
  unsigned short* KHu = (unsigned short*)XH;           // after XH consumed
  float* AO = XC;                                      // after XC consumed

  // ---- int / weight region ----
  int* ip = (int*)(VHu + NF);
  int* rp_cg  = ip;              ip += NN + 1;
  int* rp_hy  = ip;              ip += NN + 1;
  int* rp_sg  = ip;              ip += MM + 1;
  int* rp_Lcg = ip;              ip += NN + 1;
  int* rp_Lhy = ip;              ip += NN + 1;
  int* rp_Lsg = ip;              ip += MM + 1;
  int* ec_cg  = ip;              ip += NEN;
  int* ec_hy  = ip;              ip += NEN;
  int* ec_sg  = ip;              ip += NEM;
  int* ec_Lcg = ip;              ip += NEN;
  int* ec_Lhy = ip;              ip += NEN;
  int* ec_Lsg = ip;              ip += NEM;
  float* ev_cg  = (float*)ip;    ip += NEN;
  float* ev_hy  = (float*)ip;    ip += NEN;
  float* ev_sg  = (float*)ip;    ip += NEM;
  float* ev_Lcg = (float*)ip;    ip += NEN;
  float* ev_Lhy = (float*)ip;    ip += NEN;
  float* ev_Lsg = (float*)ip;    ip += NEM;
  int* cnt  = ip;                ip += MM;
  int* bsum = ip;                ip += 256;
  unsigned short* WB = (unsigned short*)ip;
  float* CB = (float*)(WB + WELEMS);   // 6 combined biases x 256

  auto wslot = [&](int s) { return WB + (size_t)s * 65536; };
  auto cb    = [&](int s) { return CB + (size_t)s * 256; };

  auto castw = [&](const float* src, unsigned short* dst, int Nr, int T_) {
    cast_w_kernel<<<dim3(Nr), 256, 0, stream>>>(src, dst, Nr, T_);
  };
  auto combine = [&](const float* Bw, const float* Aw, const float* ab,
                     const float* bb, unsigned short* Wc, float* bcp, float fs) {
    combine_w_kernel<<<dim3(256), 256, 0, stream>>>(Bw, Aw, ab, bb, Wc, bcp, fs);
  };
  auto gemm32 = [&](const float* A, const unsigned short* Wt, const float* bias,
                    float* C, int Mrows, bool relu, int ldc = 256, int coff = 0) {
    gemm2_kernel<0><<<dim3(Mrows / 64), 256, 0, stream>>>(
        A, Wt, bias, C, ldc, coff, relu ? 1 : 0);
  };
  auto gemmbf = [&](const float* A, const unsigned short* Wt, const float* bias,
                    unsigned short* C, int Mrows) {
    gemm2_kernel<1><<<dim3(Mrows / 64), 256, 0, stream>>>(
        A, Wt, bias, C, 256, 0, 0);
  };
  auto build_csr = [&](const int* rw, const int* cl, const float* vl, int nnz,
                       int nrows, int* rowptr, int* ecol, float* eval) {
    hipMemsetAsync(cnt, 0, (size_t)nrows * 4, stream);
    count_kernel<<<dim3((nnz + 255) / 256), 256, 0, stream>>>(rw, cnt, nnz);
    int nb = (nrows + 255) / 256;
    scan1_kernel<<<dim3(nb), 256, 0, stream>>>(cnt, bsum, nrows);
    scan2_kernel<<<dim3(1), 256, 0, stream>>>(bsum, nb);
    scan3_kernel<<<dim3(nb), 256, 0, stream>>>(cnt, bsum, rowptr, nrows);
    hipMemsetAsync(cnt, 0, (size_t)nrows * 4, stream);
    fillcsr_kernel<<<dim3((nnz + 255) / 256), 256, 0, stream>>>(
        rw, cl, vl, rowptr, cnt, ecol, eval, nnz);
  };
  auto spmm = [&](const int* rowptr, const int* ecol, const float* eval,
                  const float* X, float* Y, int srcR, int dstR,
                  const float* bias, bool relu, float* Y2 = nullptr) {
    csr_spmm_kernel<<<dim3(dstR), 256, 0, stream>>>(
        rowptr, ecol, eval, X, Y, srcR, bias, relu ? 1 : 0, Y2);
  };
  auto attn = [&](const unsigned short* Qp, const unsigned short* Kp,
                  const unsigned short* Vp, float* Op) {
    attn_mfma_kernel<<<dim3(CHK / 64, NHEADS, NN / CHK), 256, 0, stream>>>(
        Qp, Kp, Vp, Op);
  };

  const float scale = 0.17677669529663687f;  // 1/sqrt(32), folded into Q proj

  // ================= weight prep =================
  castw(cg_W,           wslot(0), 256, 1);
  castw(cg_W + FD * DD, wslot(1), 256, 1);
  castw(hg_W,           wslot(2), 256, 1);
  castw(hg_W + FD * DD, wslot(3), 256, 1);
  castw(sg_W,           wslot(4), 256, 1);
  castw(sg_W + FD * DD, wslot(5), 256, 1);
  castw(snh_W,          wslot(6), 256, 0);
  castw(snc_W,          wslot(7), 256, 0);
  castw(sns_W,          wslot(8), 256, 0);
  castw(spa_out_w,      wslot(12), 256, 0);
  castw(spe_out_w,      wslot(16), 256, 0);
  // combined QKV projections (proj then in_w slice)
  combine(spa_in_w,                 spa_hyp_W,  spa_hyp_b,  spa_in_b,            wslot(9),  cb(0), scale);
  combine(spa_in_w + DD * DD,       spa_star_W, spa_star_b, spa_in_b + DD,       wslot(10), cb(1), 1.0f);
  combine(spa_in_w + 2 * DD * DD,   spa_clq_W,  spa_clq_b,  spa_in_b + 2 * DD,   wslot(11), cb(2), 1.0f);
  combine(spe_in_w,                 spe_hyp_W,  spe_hyp_b,  spe_in_b,            wslot(13), cb(3), scale);
  combine(spe_in_w + DD * DD,       spe_star_W, spe_star_b, spe_in_b + DD,       wslot(14), cb(4), 1.0f);
  combine(spe_in_w + 2 * DD * DD,   spe_clq_W,  spe_clq_b,  spe_in_b + 2 * DD,   wslot(15), cb(5), 1.0f);

  // ================= CSR builds (6 graphs) =================
  build_csr(Acg_r, Acg_c, Acg_v, NEN, NN, rp_cg, ec_cg, ev_cg);
  build_csr(Ahy_r, Ahy_c, Ahy_v, NEN, NN, rp_hy, ec_hy, ev_hy);
  build_csr(Asg_r, Asg_c, Asg_v, NEM, MM, rp_sg, ec_sg, ev_sg);
  build_csr(Lcg_r, Lcg_c, Lcg_v, NEN, NN, rp_Lcg, ec_Lcg, ev_Lcg);
  build_csr(Lhy_r, Lhy_c, Lhy_v, NEN, NN, rp_Lhy, ec_Lhy, ev_Lhy);
  build_csr(Lsg_r, Lsg_c, Lsg_v, NEM, MM, rp_Lsg, ec_Lsg, ev_Lsg);

  // ================= expansion nets =================
  gemm32(x, wslot(0), nullptr, T, NN, false);
  spmm(rp_cg, ec_cg, ev_cg, T, H, NN, NN, cg_b, true);
  gemm32(H, wslot(1), nullptr, T, NN, false);
  spmm(rp_cg, ec_cg, ev_cg, T, CG, NN, NN, cg_b + DD, false);

  gemm32(x, wslot(2), nullptr, T, NN, false);
  spmm(rp_hy, ec_hy, ev_hy, T, H, NN, NN, hg_b, true);
  gemm32(H, wslot(3), nullptr, T, NN, false);
  spmm(rp_hy, ec_hy, ev_hy, T, HG, NN, NN, hg_b + DD, false);

  // sg: x_star rows >= NN are zero -> src_rows=NN on first spmm
  gemm32(x, wslot(4), nullptr, T, NN, false);
  spmm(rp_sg, ec_sg, ev_sg, T, H, NN, MM, sg_b, true);
  gemm32(H, wslot(5), nullptr, T, MM, false);
  // dual write: SG (ws) + X_star/S_star directly into d_out (contiguous)
  spmm(rp_sg, ec_sg, ev_sg, T, SG, MM, MM, sg_b + DD, false, out + (size_t)NN * 512);

  // ================= sn projections + Laplacian spmm =================
  gemm32(HG, wslot(6), snh_b, T, NN, false);
  spmm(rp_Lhy, ec_Lhy, ev_Lhy, T, XH, NN, NN, nullptr, false);
  gemm32(CG, wslot(7), snc_b, T, NN, false);
  spmm(rp_Lcg, ec_Lcg, ev_Lcg, T, XC, NN, NN, nullptr, false);
  gemm32(SG, wslot(8), sns_b, T, MM, false);
  spmm(rp_Lsg, ec_Lsg, ev_Lsg, T, XS, MM, NN, nullptr, false);  // rows < N only

  // ================= spectral MHA (combined projections) =================
  gemmbf(XS, wslot(15), cb(5), VHu, NN);     // V  (XS consumed)
  gemmbf(XH, wslot(13), cb(3), QHu, NN);     // Q -> XS region (XH consumed)
  gemmbf(XC, wslot(14), cb(4), KHu, NN);     // K -> XH region (XC consumed)
  attn(QHu, KHu, VHu, AO);                   // AO -> XC region
  gemm32(AO, wslot(16), spe_out_b, out, NN, false, 512, 256);  // taa cols 256..511

  // ================= spatial MHA =================
  gemmbf(SG, wslot(11), cb(2), VHu, NN);     // V = X_star proj (SG consumed)
  gemmbf(HG, wslot(9),  cb(0), QHu, NN);     // Q
  gemmbf(CG, wslot(10), cb(1), KHu, NN);     // K
  attn(QHu, KHu, VHu, AO);
  gemm32(AO, wslot(12), spa_out_b, out, NN, false, 512, 0);    // taa cols 0..255
}

// Round 7
// 2466.620 us; speedup vs baseline: 3.5001x; 1.0289x over previous
//
#include <hip/hip_runtime.h>

// Problem dims (fixed by reference)
#define NN 49152
#define EHN 8192
#define MM (NN + EHN)       // 57344
#define FD 256
#define DD 256
#define NHEADS 8
#define DHEAD 32
#define CHK 1024
#define NEN (10 * NN)       // 491520
#define NEM (10 * MM)       // 573440

typedef __bf16 bf16x8 __attribute__((ext_vector_type(8)));
typedef unsigned short u16x8 __attribute__((ext_vector_type(8)));
typedef float f32x4 __attribute__((ext_vector_type(4)));

// fp32 -> bf16 bits, round-to-nearest-even (identical to v_cvt_pk_bf16_f32)
static __device__ __forceinline__ unsigned short f2bf(float f) {
  unsigned int u = __float_as_uint(f);
  unsigned int r = (u + 0x7FFFu + ((u >> 16) & 1u)) >> 16;
  return (unsigned short)r;
}
static __device__ __forceinline__ float bf2f(unsigned short u) {
  return __uint_as_float((unsigned int)u << 16);
}
// pack two fp32 -> one u32 of 2 bf16 (lo=a, hi=b), HW RTNE
static __device__ __forceinline__ unsigned int cvtpk(float a, float b) {
  unsigned int r;
  asm("v_cvt_pk_bf16_f32 %0, %1, %2" : "=v"(r) : "v"(a), "v"(b));
  return r;
}

// ---------------- weight prep ----------------
__global__ __launch_bounds__(256) void cast_w_kernel(
    const float* __restrict__ src, unsigned short* __restrict__ dst,
    int Nr, int T)
{
  int i = blockIdx.x * 256 + threadIdx.x;
  int n = i >> 8, k = i & 255;
  float f = T ? src[(size_t)k * Nr + n] : src[i];
  dst[i] = f2bf(f);
}

// Wc = Bw @ Aw (bf16), bc = fs*(Bw@ab + bb)   [2-chain combine, spatial QKV]
__global__ __launch_bounds__(256) void combine_w_kernel(
    const float* __restrict__ Bw, const float* __restrict__ Aw,
    const float* __restrict__ ab, const float* __restrict__ bb,
    unsigned short* __restrict__ Wc, float* __restrict__ bc, float fscale)
{
  int n = blockIdx.x, t = threadIdx.x;
  __shared__ float shB[256];
  __shared__ float red[256];
  shB[t] = Bw[n * 256 + t];
  __syncthreads();
  float acc = 0.0f;
  #pragma unroll 8
  for (int j = 0; j < 256; ++j) acc += shB[j] * Aw[j * 256 + t];
  Wc[n * 256 + t] = f2bf(acc * fscale);
  red[t] = shB[t] * ab[t];
  __syncthreads();
  for (int off = 128; off; off >>= 1) {
    if (t < off) red[t] += red[t + off];
    __syncthreads();
  }
  if (t == 0) bc[n] = (red[0] + bb[n]) * fscale;
}

// C[256][256] fp32 = A @ B
__global__ __launch_bounds__(256) void mm256f_kernel(
    const float* __restrict__ A, const float* __restrict__ B,
    float* __restrict__ C)
{
  int n = blockIdx.x, t = threadIdx.x;
  __shared__ float sa[256];
  sa[t] = A[n * 256 + t];
  __syncthreads();
  float acc = 0.0f;
  #pragma unroll 8
  for (int j = 0; j < 256; ++j) acc += sa[j] * B[j * 256 + t];
  C[n * 256 + t] = acc;
}

// W[256][256] bf16 = fs * (A @ B)
__global__ __launch_bounds__(256) void mm256b_kernel(
    const float* __restrict__ A, const float* __restrict__ B,
    unsigned short* __restrict__ W, float fs)
{
  int n = blockIdx.x, t = threadIdx.x;
  __shared__ float sa[256];
  sa[t] = A[n * 256 + t];
  __syncthreads();
  float acc = 0.0f;
  #pragma unroll 8
  for (int j = 0; j < 256; ++j) acc += sa[j] * B[j * 256 + t];
  W[n * 256 + t] = f2bf(acc * fs);
}

// out[n] = fs * (W @ v + add)   (single block)
__global__ __launch_bounds__(256) void mv256_kernel(
    const float* __restrict__ W, const float* __restrict__ v,
    const float* __restrict__ add, float* __restrict__ outv, float fs)
{
  int t = threadIdx.x;
  __shared__ float sv[256];
  sv[t] = v[t];
  __syncthreads();
  float acc = 0.0f;
  #pragma unroll 8
  for (int k = 0; k < 256; ++k) acc += W[t * 256 + k] * sv[k];
  if (add) acc += add[t];
  outv[t] = fs * acc;
}

// ---------------- bf16-MFMA GEMM: C = A[M][256] * Wt^T ----------------
// ABF: A is bf16 (else fp32).  OUTBF: C bf16 [M][256] (else fp32 w/ ldc,coff).
// bias modes: rs!=null -> v += rs[row]*cvec[col] + c0[col]; else v += c0[col].
template<int ABF, int OUTBF>
__global__ __launch_bounds__(256) void gemm2_kernel(
    const void* __restrict__ Ain, const unsigned short* __restrict__ Wt,
    const float* __restrict__ c0, const float* __restrict__ rs,
    const float* __restrict__ cvec, void* __restrict__ Cout,
    int ldc, int coff, int relu)
{
  __shared__ __align__(16) char sA[2][4096];    // [64 r][32 k] bf16, swz
  __shared__ __align__(16) char sB[2][16384];   // [256 n][32 k] bf16, swz
  const int tid = threadIdx.x, lane = tid & 63, wid = tid >> 6;
  const int l15 = lane & 15, l4 = lane >> 4;
  const int bm = blockIdx.x * 64;

  f32x4 acc[16] = {};
  const int ar = tid >> 2, akq = (tid & 3) * 8;
  const int bn = tid;

  float4 fa0, fa1;
  u16x8 ua;
  u16x8 rb0, rb1, rb2, rb3;
  auto stage_load = [&](int k0) {
    if (ABF) {
      ua = *(const u16x8*)((const unsigned short*)Ain +
                           (size_t)(bm + ar) * 256 + k0 + akq);
    } else {
      const float* ap = (const float*)Ain + (size_t)(bm + ar) * 256 + k0 + akq;
      fa0 = *(const float4*)ap;
      fa1 = *(const float4*)(ap + 4);
    }
    const unsigned short* bp = Wt + (size_t)bn * 256 + k0;
    rb0 = *(const u16x8*)bp;        rb1 = *(const u16x8*)(bp + 8);
    rb2 = *(const u16x8*)(bp + 16); rb3 = *(const u16x8*)(bp + 24);
  };
  auto stage_write = [&](int buf) {
    u16x8 va;
    if (ABF) {
      va = ua;
    } else {
      va[0] = f2bf(fa0.x); va[1] = f2bf(fa0.y); va[2] = f2bf(fa0.z); va[3] = f2bf(fa0.w);
      va[4] = f2bf(fa1.x); va[5] = f2bf(fa1.y); va[6] = f2bf(fa1.z); va[7] = f2bf(fa1.w);
    }
    int aa = ((ar << 6) + (akq << 1)) ^ ((ar & 7) << 4);
    *(u16x8*)(sA[buf] + aa) = va;
    int bb = (bn << 6) ^ ((bn & 7) << 4);
    *(u16x8*)(sB[buf] + bb) = rb0;
    *(u16x8*)(sB[buf] + (bb ^ 16)) = rb1;
    *(u16x8*)(sB[buf] + (bb ^ 32)) = rb2;
    *(u16x8*)(sB[buf] + (bb ^ 48)) = rb3;
  };

  stage_load(0);
  stage_write(0);
  __syncthreads();
  int cur = 0;
  for (int it = 0; it < 8; ++it) {
    if (it < 7) stage_load((it + 1) * 32);
    int ra = wid * 16 + l15;
    bf16x8 af = *(const bf16x8*)(sA[cur] + ((ra << 6) + (l4 << 4) ^ ((ra & 7) << 4)));
    #pragma unroll
    for (int n4 = 0; n4 < 16; ++n4) {
      int rn = n4 * 16 + l15;
      bf16x8 bf = *(const bf16x8*)(sB[cur] + ((rn << 6) + (l4 << 4) ^ ((rn & 7) << 4)));
      acc[n4] = __builtin_amdgcn_mfma_f32_16x16x32_bf16(af, bf, acc[n4], 0, 0, 0);
    }
    __syncthreads();
    if (it < 7) {
      stage_write(cur ^ 1);
      __syncthreads();
      cur ^= 1;
    }
  }
  const int row = bm + wid * 16 + l4 * 4;
  float rsv[4];
  if (rs) {
    #pragma unroll
    for (int j = 0; j < 4; ++j) rsv[j] = rs[row + j];
  }
  #pragma unroll
  for (int n4 = 0; n4 < 16; ++n4) {
    int col = n4 * 16 + l15;
    float base = c0 ? c0[col] : 0.0f;
    float cv = rs ? cvec[col] : 0.0f;
    #pragma unroll
    for (int j = 0; j < 4; ++j) {
      float v = acc[n4][j] + base;
      if (rs) v += rsv[j] * cv;
      if (relu) v = fmaxf(v, 0.0f);
      if (OUTBF)
        ((unsigned short*)Cout)[(size_t)(row + j) * 256 + col] = f2bf(v);
      else
        ((float*)Cout)[(size_t)(row + j) * ldc + coff + col] = v;
    }
  }
}

// ================= CSR build =================
__global__ __launch_bounds__(256) void count_kernel(
    const int* __restrict__ rw, int* __restrict__ cnt, int nnz)
{
  int e = blockIdx.x * 256 + threadIdx.x;
  if (e < nnz) atomicAdd(&cnt[rw[e]], 1);
}

__global__ __launch_bounds__(256) void scan1_kernel(
    const int* __restrict__ cnt, int* __restrict__ bsum, int n)
{
  __shared__ int sh[256];
  int i = blockIdx.x * 256 + threadIdx.x;
  sh[threadIdx.x] = (i < n) ? cnt[i] : 0;
  __syncthreads();
  for (int off = 128; off; off >>= 1) {
    if (threadIdx.x < off) sh[threadIdx.x] += sh[threadIdx.x + off];
    __syncthreads();
  }
  if (threadIdx.x == 0) bsum[blockIdx.x] = sh[0];
}

__global__ __launch_bounds__(256) void scan2_kernel(int* __restrict__ bsum, int nb)
{
  __shared__ int sh[256];
  int v = (threadIdx.x < nb) ? bsum[threadIdx.x] : 0;
  sh[threadIdx.x] = v;
  __syncthreads();
  for (int off = 1; off < 256; off <<= 1) {
    int add = (threadIdx.x >= off) ? sh[threadIdx.x - off] : 0;
    __syncthreads();
    sh[threadIdx.x] += add;
    __syncthreads();
  }
  if (threadIdx.x < nb) bsum[threadIdx.x] = sh[threadIdx.x] - v;  // exclusive
}

__global__ __launch_bounds__(256) void scan3_kernel(
    const int* __restrict__ cnt, const int* __restrict__ bsum,
    int* __restrict__ rowptr, int n)
{
  __shared__ int sh[256];
  int i = blockIdx.x * 256 + threadIdx.x;
  int v = (i < n) ? cnt[i] : 0;
  sh[threadIdx.x] = v;
  __syncthreads();
  for (int off = 1; off < 256; off <<= 1) {
    int add = (threadIdx.x >= off) ? sh[threadIdx.x - off] : 0;
    __syncthreads();
    sh[threadIdx.x] += add;
    __syncthreads();
  }
  int incl = sh[threadIdx.x];
  int base = bsum[blockIdx.x];
  if (i < n) rowptr[i] = base + incl - v;
  if (i == n - 1) rowptr[n] = base + incl;
}

__global__ __launch_bounds__(256) void fillcsr_kernel(
    const int* __restrict__ rw, const int* __restrict__ cl,
    const float* __restrict__ vl, const int* __restrict__ rowptr,
    int* __restrict__ cur, int* __restrict__ ecol, float* __restrict__ eval,
    int nnz)
{
  int e = blockIdx.x * 256 + threadIdx.x;
  if (e < nnz) {
    int r = rw[e];
    int pos = rowptr[r] + atomicAdd(&cur[r], 1);
    ecol[pos] = cl[e];
    eval[pos] = vl[e];
  }
}

// rs[r] = sum of eval over row r
__global__ __launch_bounds__(256) void rowsum_kernel(
    const int* __restrict__ rowptr, const float* __restrict__ eval,
    float* __restrict__ rs, int n)
{
  int i = blockIdx.x * 256 + threadIdx.x;
  if (i >= n) return;
  float s = 0.0f;
  int end = rowptr[i + 1];
  for (int e = rowptr[i]; e < end; ++e) s += eval[e];
  rs[i] = s;
}

// ---------------- CSR SpMM (bf16 gather, bf16 out, opt fp32 dual write) -----
__global__ __launch_bounds__(256) void csr_spmm_kernel(
    const int* __restrict__ rowptr, const int* __restrict__ ecol,
    const float* __restrict__ eval, const unsigned short* __restrict__ X,
    unsigned short* __restrict__ Y, int src_rows,
    const float* __restrict__ bias, int relu, float* __restrict__ Y2)
{
  int r = blockIdx.x, t = threadIdx.x;
  int beg = rowptr[r], end = rowptr[r + 1];
  float acc = 0.0f;
  for (int e = beg; e < end; ++e) {
    int c = ecol[e];
    float v = eval[e];
    if (c < src_rows) acc += v * bf2f(X[(size_t)c * DD + t]);
  }
  if (bias) acc += bias[t];
  if (relu) acc = fmaxf(acc, 0.0f);
  Y[(size_t)r * DD + t] = f2bf(acc);
  if (Y2) Y2[(size_t)r * DD + t] = acc;
}

// ---------------- MFMA flash attention (bf16 in/out, exp2 domain) ----------
// Q pre-scaled by (1/sqrt(32))*log2(e) at weight prep.
__global__ __launch_bounds__(256) void attn_mfma_kernel(
    const unsigned short* __restrict__ Q, const unsigned short* __restrict__ K,
    const unsigned short* __restrict__ V, unsigned short* __restrict__ O)
{
  __shared__ __align__(16) char sKb[4096];   // [64 key][32 d], swz (key&7)<<4
  __shared__ __align__(16) char sVb[4096];   // [32 d][64 key], swz d-fold
  __shared__ __align__(16) char sPb[8192];   // per-wave [16 q][64 key]
  const int c = blockIdx.z, h = blockIdx.y;
  const int tid = threadIdx.x, lane = tid & 63, wid = tid >> 6;
  const int l15 = lane & 15, l4 = lane >> 4;
  char* sPw = sPb + wid * 2048;
  const size_t base = (size_t)c * (CHK * DD) + (size_t)h * DHEAD;
  const int q0 = blockIdx.x * 64 + wid * 16;

  bf16x8 qf = *(const bf16x8*)(Q + base + (size_t)(q0 + l15) * DD + l4 * 8);

  const int key_s = tid >> 2, dq = (tid & 3) * 8;
  const unsigned short* Kp = K + base + (size_t)key_s * DD + dq;
  const unsigned short* Vp = V + base + (size_t)key_s * DD + dq;
  const int kaddr = ((key_s << 6) + (dq << 1)) ^ ((key_s & 7) << 4);

  f32x4 oacc[2] = {};
  float m = -1e30f, l = 0.0f;
  const f32x4 zero = {};

  for (int kt = 0; kt < CHK; kt += 64) {
    __syncthreads();
    u16x8 kv = *(const u16x8*)Kp;  Kp += 64 * DD;
    u16x8 vv = *(const u16x8*)Vp;  Vp += 64 * DD;
    *(u16x8*)(sKb + kaddr) = kv;
    #pragma unroll
    for (int i = 0; i < 8; ++i) {
      // full XOR swizzle per element (r5-proven form; do NOT fold into an add)
      int d = dq + i;
      int bb = ((d << 7) + (key_s << 1))
             ^ ((d & 7) << 4) ^ (((d >> 3) & 3) << 5);
      *(unsigned short*)(sVb + bb) = vv[i];
    }
    __syncthreads();

    f32x4 s[4];
    #pragma unroll
    for (int s4 = 0; s4 < 4; ++s4) {
      int key = s4 * 16 + l15;
      int ba = ((key << 6) + (l4 << 4)) ^ ((key & 7) << 4);
      bf16x8 kf = *(const bf16x8*)(sKb + ba);
      s[s4] = __builtin_amdgcn_mfma_f32_16x16x32_bf16(kf, qf, zero, 0, 0, 0);
    }
    float tmax = -1e30f;
    #pragma unroll
    for (int s4 = 0; s4 < 4; ++s4)
      #pragma unroll
      for (int j = 0; j < 4; ++j) tmax = fmaxf(tmax, s[s4][j]);
    tmax = fmaxf(tmax, __shfl_xor(tmax, 16));
    tmax = fmaxf(tmax, __shfl_xor(tmax, 32));
    float mnew = fmaxf(m, tmax);
    float corr = __builtin_amdgcn_exp2f(m - mnew);
    float psum = 0.0f;
    float p[4][4];
    #pragma unroll
    for (int s4 = 0; s4 < 4; ++s4)
      #pragma unroll
      for (int j = 0; j < 4; ++j) {
        p[s4][j] = __builtin_amdgcn_exp2f(s[s4][j] - mnew);
        psum += p[s4][j];
      }
    psum += __shfl_xor(psum, 16);
    psum += __shfl_xor(psum, 32);
    l = l * corr + psum;
    m = mnew;
    oacc[0] *= corr;
    oacc[1] *= corr;
    #pragma unroll
    for (int s4 = 0; s4 < 4; ++s4) {
      uint2 pk = { cvtpk(p[s4][0], p[s4][1]), cvtpk(p[s4][2], p[s4][3]) };
      int bp = ((l15 << 7) + (s4 << 5) + (l4 << 3)) ^ ((l15 & 7) << 4);
      *(uint2*)(sPw + bp) = pk;
    }
    __syncthreads();

    #pragma unroll
    for (int dh = 0; dh < 2; ++dh)
      #pragma unroll
      for (int kh = 0; kh < 2; ++kh) {
        int d = dh * 16 + l15;
        int ba = ((d << 7) + ((kh * 32 + l4 * 8) << 1))
               ^ ((d & 7) << 4) ^ (((d >> 3) & 3) << 5);
        bf16x8 vf = *(const bf16x8*)(sVb + ba);
        int bp = ((l15 << 7) + (kh << 6) + (l4 << 4)) ^ ((l15 & 7) << 4);
        bf16x8 pf = *(const bf16x8*)(sPw + bp);
        oacc[dh] = __builtin_amdgcn_mfma_f32_16x16x32_bf16(vf, pf, oacc[dh], 0, 0, 0);
      }
  }

  float inv = 1.0f / l;
  unsigned short* orow = O + base + (size_t)(q0 + l15) * DD;
  #pragma unroll
  for (int dh = 0; dh < 2; ++dh) {
    uint2 o2 = { cvtpk(oacc[dh][0] * inv, oacc[dh][1] * inv),
                 cvtpk(oacc[dh][2] * inv, oacc[dh][3] * inv) };
    *(uint2*)(orow + dh * 16 + l4 * 4) = o2;
  }
}

// sentinel: error value identifies which runtime check failed
__global__ __launch_bounds__(256) void fill_kernel(float* p, long n, float v)
{
  long i = (long)blockIdx.x * 256 + threadIdx.x;
  if (i < n) p[i] = v;
}

extern "C" void kernel_launch(void* const* d_in, const int* in_sizes, int n_in,
                              void* d_out, int out_size, void* d_ws, size_t ws_size,
                              hipStream_t stream)
{
  const float* x     = (const float*)d_in[0];
  const int*   Acg_r = (const int*)d_in[1];
  const int*   Acg_c = (const int*)d_in[2];
  const float* Acg_v = (const float*)d_in[3];
  const int*   Ahy_r = (const int*)d_in[4];
  const int*   Ahy_c = (const int*)d_in[5];
  const float* Ahy_v = (const float*)d_in[6];
  const int*   Asg_r = (const int*)d_in[7];
  const int*   Asg_c = (const int*)d_in[8];
  const float* Asg_v = (const float*)d_in[9];
  const int*   Lcg_r = (const int*)d_in[10];
  const int*   Lcg_c = (const int*)d_in[11];
  const float* Lcg_v = (const float*)d_in[12];
  const int*   Lhy_r = (const int*)d_in[13];
  const int*   Lhy_c = (const int*)d_in[14];
  const float* Lhy_v = (const float*)d_in[15];
  const int*   Lsg_r = (const int*)d_in[16];
  const int*   Lsg_c = (const int*)d_in[17];
  const float* Lsg_v = (const float*)d_in[18];
  const float* cg_W  = (const float*)d_in[19];
  const float* cg_b  = (const float*)d_in[20];
  const float* hg_W  = (const float*)d_in[21];
  const float* hg_b  = (const float*)d_in[22];
  const float* sg_W  = (const float*)d_in[23];
  const float* sg_b  = (const float*)d_in[24];
  const float* snh_W = (const float*)d_in[25];
  const float* snh_b = (const float*)d_in[26];
  const float* snc_W = (const float*)d_in[27];
  const float* snc_b = (const float*)d_in[28];
  const float* sns_W = (const float*)d_in[29];
  const float* sns_b = (const float*)d_in[30];
  const float* spa_hyp_W  = (const float*)d_in[31];
  const float* spa_hyp_b  = (const float*)d_in[32];
  const float* spa_star_W = (const float*)d_in[33];
  const float* spa_star_b = (const float*)d_in[34];
  const float* spa_clq_W  = (const float*)d_in[35];
  const float* spa_clq_b  = (const float*)d_in[36];
  const float* spa_in_w   = (const float*)d_in[37];
  const float* spa_in_b   = (const float*)d_in[38];
  const float* spa_out_w  = (const float*)d_in[39];
  const float* spa_out_b  = (const float*)d_in[40];
  const float* spe_hyp_W  = (const float*)d_in[41];
  const float* spe_hyp_b  = (const float*)d_in[42];
  const float* spe_star_W = (const float*)d_in[43];
  const float* spe_star_b = (const float*)d_in[44];
  const float* spe_clq_W  = (const float*)d_in[45];
  const float* spe_clq_b  = (const float*)d_in[46];
  const float* spe_in_w   = (const float*)d_in[47];
  const float* spe_in_b   = (const float*)d_in[48];
  const float* spe_out_w  = (const float*)d_in[49];
  const float* spe_out_b  = (const float*)d_in[50];

  float* out = (float*)d_out;

  const size_t NF = (size_t)NN * DD;
  const size_t MF = (size_t)MM * DD;
  const size_t EDG_TOT = 4 * (size_t)NEN + 2 * (size_t)NEM;
  const size_t RP_TOT  = 4 * (size_t)(NN + 1) + 2 * (size_t)(MM + 1);
  const size_t WELEMS  = 14u * 65536u;
  const size_t need = (3 * MF + 9 * NF) * 2                       // bf16 bufs
                    + ((size_t)3 * NN + 65536 + 256 + 4096) * 4   // fp32 small
                    + (RP_TOT + 2 * EDG_TOT + MM + 256) * 4       // csr
                    + WELEMS * 2;

  auto fill = [&](float v) {
    long tot = (long)out_size;
    fill_kernel<<<dim3((unsigned)((tot + 255) / 256)), 256, 0, stream>>>(out, tot, v);
  };
  if (ws_size < need)                        { fill(12.0f); return; }
  if (n_in != 51)                            { fill(16.0f); return; }
  if (in_sizes[0] != NN * FD)                { fill(20.0f); return; }
  if (in_sizes[3] != NEN)                    { fill(24.0f); return; }
  if (in_sizes[9] != NEM)                    { fill(28.0f); return; }
  if (in_sizes[19] != 2 * FD * DD)           { fill(32.0f); return; }
  if (in_sizes[37] != 3 * DD * DD)           { fill(36.0f); return; }
  if (out_size != NN * 512 + NN * DD + EHN * DD) { fill(40.0f); return; }

  // ---- bf16 buffers ----
  unsigned short* T  = (unsigned short*)d_ws;   // M staging (gemm out -> spmm in)
  unsigned short* H  = T + MF;                  // M expan hidden
  unsigned short* SG = H + MF;                  // sg_feat (M)
  unsigned short* CG = SG + MF;                 // cg_feat (N)
  unsigned short* HG = CG + NF;                 // hg_feat (N)
  unsigned short* LH = HG + NF;                 // L_hyp . HG
  unsigned short* LC = LH + NF;                 // L_cg  . CG
  unsigned short* LS = LC + NF;                 // L_sg  . SG (first N rows)
  unsigned short* QH = LS + NF;
  unsigned short* KH = QH + NF;
  unsigned short* VH = KH + NF;
  unsigned short* AO = VH + NF;

  // ---- fp32 small ----
  float* fp = (float*)(AO + NF);
  float* rs_h = fp;            fp += NN;
  float* rs_c = fp;            fp += NN;
  float* rs_s = fp;            fp += NN;
  float* tmp256 = fp;          fp += 65536;
  float* tmpv = fp;            fp += 256;
  float* CB = fp;              fp += 4096;   // bias vectors, 16 slots of 256

  // ---- int / weight region ----
  int* ip = (int*)fp;
  int* rp_cg  = ip;              ip += NN + 1;
  int* rp_hy  = ip;              ip += NN + 1;
  int* rp_sg  = ip;              ip += MM + 1;
  int* rp_Lcg = ip;              ip += NN + 1;
  int* rp_Lhy = ip;              ip += NN + 1;
  int* rp_Lsg = ip;              ip += MM + 1;
  int* ec_cg  = ip;              ip += NEN;
  int* ec_hy  = ip;              ip += NEN;
  int* ec_sg  = ip;              ip += NEM;
  int* ec_Lcg = ip;              ip += NEN;
  int* ec_Lhy = ip;              ip += NEN;
  int* ec_Lsg = ip;              ip += NEM;
  float* ev_cg  = (float*)ip;    ip += NEN;
  float* ev_hy  = (float*)ip;    ip += NEN;
  float* ev_sg  = (float*)ip;    ip += NEM;
  float* ev_Lcg = (float*)ip;    ip += NEN;
  float* ev_Lhy = (float*)ip;    ip += NEN;
  float* ev_Lsg = (float*)ip;    ip += NEM;
  int* cnt  = ip;                ip += MM;
  int* bsum = ip;                ip += 256;
  unsigned short* WB = (unsigned short*)ip;

  auto wslot = [&](int s) { return WB + (size_t)s * 65536; };
  auto cb    = [&](int s) { return CB + (size_t)s * 256; };

  auto castw = [&](const float* src, unsigned short* dst, int T_) {
    cast_w_kernel<<<dim3(256), 256, 0, stream>>>(src, dst, 256, T_);
  };
  auto combine = [&](const float* Bw, const float* Aw, const float* ab,
                     const float* bb, unsigned short* Wc, float* bcp, float fs) {
    combine_w_kernel<<<dim3(256), 256, 0, stream>>>(Bw, Aw, ab, bb, Wc, bcp, fs);
  };
  // triple chain: W = fs*(w3 @ pW @ sW); cvec = fs*(w3 @ (pW@sb)); c0 = fs*(w3@pb + b3)
  auto combine3 = [&](const float* w3, const float* b3, const float* pW,
                      const float* pb, const float* sW, const float* sb,
                      unsigned short* Wc, float* cvecp, float* c0p, float fs) {
    mm256f_kernel<<<dim3(256), 256, 0, stream>>>(pW, sW, tmp256);
    mm256b_kernel<<<dim3(256), 256, 0, stream>>>(w3, tmp256, Wc, fs);
    mv256_kernel<<<dim3(1), 256, 0, stream>>>(pW, sb, nullptr, tmpv, 1.0f);
    mv256_kernel<<<dim3(1), 256, 0, stream>>>(w3, tmpv, nullptr, cvecp, fs);
    mv256_kernel<<<dim3(1), 256, 0, stream>>>(w3, pb, b3, c0p, fs);
  };
  auto gemm32in = [&](const float* A, const unsigned short* Wt,
                      unsigned short* C, int Mrows) {
    gemm2_kernel<0, 1><<<dim3(Mrows / 64), 256, 0, stream>>>(
        A, Wt, nullptr, nullptr, nullptr, C, 256, 0, 0);
  };
  auto gemmbb = [&](const unsigned short* A, const unsigned short* Wt,
                    const float* c0, unsigned short* C, int Mrows) {
    gemm2_kernel<1, 1><<<dim3(Mrows / 64), 256, 0, stream>>>(
        A, Wt, c0, nullptr, nullptr, C, 256, 0, 0);
  };
  auto gemmrs = [&](const unsigned short* A, const unsigned short* Wt,
                    const float* c0, const float* rs, const float* cvec,
                    unsigned short* C, int Mrows) {
    gemm2_kernel<1, 1><<<dim3(Mrows / 64), 256, 0, stream>>>(
        A, Wt, c0, rs, cvec, C, 256, 0, 0);
  };
  auto gemmout = [&](const unsigned short* A, const unsigned short* Wt,
                     const float* c0, float* C, int coff) {
    gemm2_kernel<1, 0><<<dim3(NN / 64), 256, 0, stream>>>(
        A, Wt, c0, nullptr, nullptr, C, 512, coff, 0);
  };
  auto build_csr = [&](const int* rw, const int* cl, const float* vl, int nnz,
                       int nrows, int* rowptr, int* ecol, float* eval) {
    hipMemsetAsync(cnt, 0, (size_t)nrows * 4, stream);
    count_kernel<<<dim3((nnz + 255) / 256), 256, 0, stream>>>(rw, cnt, nnz);
    int nb = (nrows + 255) / 256;
    scan1_kernel<<<dim3(nb), 256, 0, stream>>>(cnt, bsum, nrows);
    scan2_kernel<<<dim3(1), 256, 0, stream>>>(bsum, nb);
    scan3_kernel<<<dim3(nb), 256, 0, stream>>>(cnt, bsum, rowptr, nrows);
    hipMemsetAsync(cnt, 0, (size_t)nrows * 4, stream);
    fillcsr_kernel<<<dim3((nnz + 255) / 256), 256, 0, stream>>>(
        rw, cl, vl, rowptr, cnt, ecol, eval, nnz);
  };
  auto spmm = [&](const int* rowptr, const int* ecol, const float* eval,
                  const unsigned short* X, unsigned short* Y, int srcR, int dstR,
                  const float* bias, bool relu, float* Y2 = nullptr) {
    csr_spmm_kernel<<<dim3(dstR), 256, 0, stream>>>(
        rowptr, ecol, eval, X, Y, srcR, bias, relu ? 1 : 0, Y2);
  };
  auto attn = [&](const unsigned short* Qp, const unsigned short* Kp,
                  const unsigned short* Vp, unsigned short* Op) {
    attn_mfma_kernel<<<dim3(CHK / 64, NHEADS, NN / CHK), 256, 0, stream>>>(
        Qp, Kp, Vp, Op);
  };

  // softmax scale * log2(e): attention works in exp2 domain
  const float fsQ = 0.17677669529663687f * 1.4426950408889634f;

  // ================= weight prep =================
  castw(cg_W,           wslot(0), 1);
  castw(cg_W + FD * DD, wslot(1), 1);
  castw(hg_W,           wslot(2), 1);
  castw(hg_W + FD * DD, wslot(3), 1);
  castw(sg_W,           wslot(4), 1);
  castw(sg_W + FD * DD, wslot(5), 1);
  castw(spa_out_w,      wslot(12), 0);
  castw(spe_out_w,      wslot(13), 0);
  // spatial QKV (2-chain)
  combine(spa_in_w,                spa_hyp_W,  spa_hyp_b,  spa_in_b,          wslot(6), cb(0), fsQ);
  combine(spa_in_w + DD * DD,      spa_star_W, spa_star_b, spa_in_b + DD,     wslot(7), cb(1), 1.0f);
  combine(spa_in_w + 2 * DD * DD,  spa_clq_W,  spa_clq_b,  spa_in_b + 2 * DD, wslot(8), cb(2), 1.0f);
  // spectral QKV (3-chain: sn-projection folded in; Laplacian bias via rowsum)
  combine3(spe_in_w,               spe_in_b,            spe_hyp_W,  spe_hyp_b,  snh_W, snh_b, wslot(9),  cb(3), cb(4), fsQ);
  combine3(spe_in_w + DD * DD,     spe_in_b + DD,       spe_star_W, spe_star_b, snc_W, snc_b, wslot(10), cb(5), cb(6), 1.0f);
  combine3(spe_in_w + 2 * DD * DD, spe_in_b + 2 * DD,   spe_clq_W,  spe_clq_b,  sns_W, sns_b, wslot(11), cb(7), cb(8), 1.0f);

  // ================= CSR builds (6 graphs) + Laplacian rowsums ============
  build_csr(Acg_r, Acg_c, Acg_v, NEN, NN, rp_cg, ec_cg, ev_cg);
  build_csr(Ahy_r, Ahy_c, Ahy_v, NEN, NN, rp_hy, ec_hy, ev_hy);
  build_csr(Asg_r, Asg_c, Asg_v, NEM, MM, rp_sg, ec_sg, ev_sg);
  build_csr(Lcg_r, Lcg_c, Lcg_v, NEN, NN, rp_Lcg, ec_Lcg, ev_Lcg);
  build_csr(Lhy_r, Lhy_c, Lhy_v, NEN, NN, rp_Lhy, ec_Lhy, ev_Lhy);
  build_csr(Lsg_r, Lsg_c, Lsg_v, NEM, MM, rp_Lsg, ec_Lsg, ev_Lsg);
  rowsum_kernel<<<dim3(NN / 256), 256, 0, stream>>>(rp_Lhy, ev_Lhy, rs_h, NN);
  rowsum_kernel<<<dim3(NN / 256), 256, 0, stream>>>(rp_Lcg, ev_Lcg, rs_c, NN);
  rowsum_kernel<<<dim3(NN / 256), 256, 0, stream>>>(rp_Lsg, ev_Lsg, rs_s, NN);

  // ================= expansion nets =================
  gemm32in(x, wslot(0), T, NN);
  spmm(rp_cg, ec_cg, ev_cg, T, H, NN, NN, cg_b, true);
  gemmbb(H, wslot(1), nullptr, T, NN);
  spmm(rp_cg, ec_cg, ev_cg, T, CG, NN, NN, cg_b + DD, false);

  gemm32in(x, wslot(2), T, NN);
  spmm(rp_hy, ec_hy, ev_hy, T, H, NN, NN, hg_b, true);
  gemmbb(H, wslot(3), nullptr, T, NN);
  spmm(rp_hy, ec_hy, ev_hy, T, HG, NN, NN, hg_b + DD, false);

  // sg: x_star rows >= NN are zero -> src_rows=NN on first spmm
  gemm32in(x, wslot(4), T, NN);
  spmm(rp_sg, ec_sg, ev_sg, T, H, NN, MM, sg_b, true);
  gemmbb(H, wslot(5), nullptr, T, MM);
  // dual write: SG bf16 + X_star/S_star fp32 directly into d_out
  spmm(rp_sg, ec_sg, ev_sg, T, SG, MM, MM, sg_b + DD, false, out + (size_t)NN * 512);

  // ================= Laplacian spmms (sn-projection folded into QKV) ======
  spmm(rp_Lhy, ec_Lhy, ev_Lhy, HG, LH, NN, NN, nullptr, false);
  spmm(rp_Lcg, ec_Lcg, ev_Lcg, CG, LC, NN, NN, nullptr, false);
  spmm(rp_Lsg, ec_Lsg, ev_Lsg, SG, LS, MM, NN, nullptr, false);  // rows < N only

  // ================= spectral MHA =================
  gemmrs(LH, wslot(9),  cb(4), rs_h, cb(3), QH, NN);
  gemmrs(LC, wslot(10), cb(6), rs_c, cb(5), KH, NN);
  gemmrs(LS, wslot(11), cb(8), rs_s, cb(7), VH, NN);
  attn(QH, KH, VH, AO);
  gemmout(AO, wslot(13), spe_out_b, out, 256);   // taa cols 256..511

  // ================= spatial MHA =================
  gemmbb(HG, wslot(6), cb(0), QH, NN);
  gemmbb(CG, wslot(7), cb(1), KH, NN);
  gemmbb(SG, wslot(8), cb(2), VH, NN);
  attn(QH, KH, VH, AO);
  gemmout(AO, wslot(12), spa_out_b, out, 0);     // taa cols 0..255
}

// Round 8
// 1874.878 us; speedup vs baseline: 4.6047x; 1.3156x over previous
//
#include <hip/hip_runtime.h>

// Problem dims (fixed by reference)
#define NN 49152
#define EHN 8192
#define MM (NN + EHN)       // 57344
#define FD 256
#define DD 256
#define NHEADS 8
#define DHEAD 32
#define CHK 1024
#define NEN (10 * NN)       // 491520
#define NEM (10 * MM)       // 573440

typedef __bf16 bf16x8 __attribute__((ext_vector_type(8)));
typedef unsigned short u16x8 __attribute__((ext_vector_type(8)));
typedef float f32x4 __attribute__((ext_vector_type(4)));

// fp32 -> bf16 bits, round-to-nearest-even (identical to v_cvt_pk_bf16_f32)
static __device__ __forceinline__ unsigned short f2bf(float f) {
  unsigned int u = __float_as_uint(f);
  unsigned int r = (u + 0x7FFFu + ((u >> 16) & 1u)) >> 16;
  return (unsigned short)r;
}
static __device__ __forceinline__ float bf2f(unsigned short u) {
  return __uint_as_float((unsigned int)u << 16);
}
// pack two fp32 -> one u32 of 2 bf16 (lo=a, hi=b), HW RTNE
static __device__ __forceinline__ unsigned int cvtpk(float a, float b) {
  unsigned int r;
  asm("v_cvt_pk_bf16_f32 %0, %1, %2" : "=v"(r) : "v"(a), "v"(b));
  return r;
}

// ---------------- weight prep ----------------
// batched cast of 8 256x256 weights (one dispatch instead of 8)
struct CastJobs {
  const float* src[8];
  unsigned short* dst[8];
  int trans[8];
};
__global__ __launch_bounds__(256) void cast_w8_kernel(CastJobs jobs)
{
  int job = blockIdx.x >> 8;
  int i = (blockIdx.x & 255) * 256 + threadIdx.x;
  int n = i >> 8, k = i & 255;
  const float* src = jobs.src[job];
  float f = jobs.trans[job] ? src[(size_t)k * 256 + n] : src[i];
  jobs.dst[job][i] = f2bf(f);
}

// Wc = Bw @ Aw (bf16), bc = fs*(Bw@ab + bb)   [2-chain combine, spatial QKV]
__global__ __launch_bounds__(256) void combine_w_kernel(
    const float* __restrict__ Bw, const float* __restrict__ Aw,
    const float* __restrict__ ab, const float* __restrict__ bb,
    unsigned short* __restrict__ Wc, float* __restrict__ bc, float fscale)
{
  int n = blockIdx.x, t = threadIdx.x;
  __shared__ float shB[256];
  __shared__ float red[256];
  shB[t] = Bw[n * 256 + t];
  __syncthreads();
  float acc = 0.0f;
  #pragma unroll 8
  for (int j = 0; j < 256; ++j) acc += shB[j] * Aw[j * 256 + t];
  Wc[n * 256 + t] = f2bf(acc * fscale);
  red[t] = shB[t] * ab[t];
  __syncthreads();
  for (int off = 128; off; off >>= 1) {
    if (t < off) red[t] += red[t + off];
    __syncthreads();
  }
  if (t == 0) bc[n] = (red[0] + bb[n]) * fscale;
}

// C[256][256] fp32 = A @ B
__global__ __launch_bounds__(256) void mm256f_kernel(
    const float* __restrict__ A, const float* __restrict__ B,
    float* __restrict__ C)
{
  int n = blockIdx.x, t = threadIdx.x;
  __shared__ float sa[256];
  sa[t] = A[n * 256 + t];
  __syncthreads();
  float acc = 0.0f;
  #pragma unroll 8
  for (int j = 0; j < 256; ++j) acc += sa[j] * B[j * 256 + t];
  C[n * 256 + t] = acc;
}

// W[256][256] bf16 = fs * (A @ B)
__global__ __launch_bounds__(256) void mm256b_kernel(
    const float* __restrict__ A, const float* __restrict__ B,
    unsigned short* __restrict__ W, float fs)
{
  int n = blockIdx.x, t = threadIdx.x;
  __shared__ float sa[256];
  sa[t] = A[n * 256 + t];
  __syncthreads();
  float acc = 0.0f;
  #pragma unroll 8
  for (int j = 0; j < 256; ++j) acc += sa[j] * B[j * 256 + t];
  W[n * 256 + t] = f2bf(acc * fs);
}

// out[n] = fs * (W @ v + add)   (single block)
__global__ __launch_bounds__(256) void mv256_kernel(
    const float* __restrict__ W, const float* __restrict__ v,
    const float* __restrict__ add, float* __restrict__ outv, float fs)
{
  int t = threadIdx.x;
  __shared__ float sv[256];
  sv[t] = v[t];
  __syncthreads();
  float acc = 0.0f;
  #pragma unroll 8
  for (int k = 0; k < 256; ++k) acc += W[t * 256 + k] * sv[k];
  if (add) acc += add[t];
  outv[t] = fs * acc;
}

// ---------------- bf16-MFMA GEMM: C = A[M][256] * Wt^T ----------------
// ABF: A is bf16 (else fp32).  OUTBF: C bf16 [M][256] (else fp32 w/ ldc,coff).
// bias modes: rs!=null -> v += rs[row]*cvec[col] + c0[col]; else v += c0[col].
template<int ABF, int OUTBF>
__global__ __launch_bounds__(256) void gemm2_kernel(
    const void* __restrict__ Ain, const unsigned short* __restrict__ Wt,
    const float* __restrict__ c0, const float* __restrict__ rs,
    const float* __restrict__ cvec, void* __restrict__ Cout,
    int ldc, int coff, int relu)
{
  __shared__ __align__(16) char sA[2][4096];    // [64 r][32 k] bf16, swz
  __shared__ __align__(16) char sB[2][16384];   // [256 n][32 k] bf16, swz
  const int tid = threadIdx.x, lane = tid & 63, wid = tid >> 6;
  const int l15 = lane & 15, l4 = lane >> 4;
  const int bm = blockIdx.x * 64;

  f32x4 acc[16] = {};
  const int ar = tid >> 2, akq = (tid & 3) * 8;
  const int bn = tid;

  float4 fa0, fa1;
  u16x8 ua;
  u16x8 rb0, rb1, rb2, rb3;
  auto stage_load = [&](int k0) {
    if (ABF) {
      ua = *(const u16x8*)((const unsigned short*)Ain +
                           (size_t)(bm + ar) * 256 + k0 + akq);
    } else {
      const float* ap = (const float*)Ain + (size_t)(bm + ar) * 256 + k0 + akq;
      fa0 = *(const float4*)ap;
      fa1 = *(const float4*)(ap + 4);
    }
    const unsigned short* bp = Wt + (size_t)bn * 256 + k0;
    rb0 = *(const u16x8*)bp;        rb1 = *(const u16x8*)(bp + 8);
    rb2 = *(const u16x8*)(bp + 16); rb3 = *(const u16x8*)(bp + 24);
  };
  auto stage_write = [&](int buf) {
    u16x8 va;
    if (ABF) {
      va = ua;
    } else {
      va[0] = f2bf(fa0.x); va[1] = f2bf(fa0.y); va[2] = f2bf(fa0.z); va[3] = f2bf(fa0.w);
      va[4] = f2bf(fa1.x); va[5] = f2bf(fa1.y); va[6] = f2bf(fa1.z); va[7] = f2bf(fa1.w);
    }
    int aa = ((ar << 6) + (akq << 1)) ^ ((ar & 7) << 4);
    *(u16x8*)(sA[buf] + aa) = va;
    int bb = (bn << 6) ^ ((bn & 7) << 4);
    *(u16x8*)(sB[buf] + bb) = rb0;
    *(u16x8*)(sB[buf] + (bb ^ 16)) = rb1;
    *(u16x8*)(sB[buf] + (bb ^ 32)) = rb2;
    *(u16x8*)(sB[buf] + (bb ^ 48)) = rb3;
  };

  stage_load(0);
  stage_write(0);
  __syncthreads();
  int cur = 0;
  for (int it = 0; it < 8; ++it) {
    if (it < 7) stage_load((it + 1) * 32);
    int ra = wid * 16 + l15;
    bf16x8 af = *(const bf16x8*)(sA[cur] + ((ra << 6) + (l4 << 4) ^ ((ra & 7) << 4)));
    #pragma unroll
    for (int n4 = 0; n4 < 16; ++n4) {
      int rn = n4 * 16 + l15;
      bf16x8 bf = *(const bf16x8*)(sB[cur] + ((rn << 6) + (l4 << 4) ^ ((rn & 7) << 4)));
      acc[n4] = __builtin_amdgcn_mfma_f32_16x16x32_bf16(af, bf, acc[n4], 0, 0, 0);
    }
    __syncthreads();
    if (it < 7) {
      stage_write(cur ^ 1);
      __syncthreads();
      cur ^= 1;
    }
  }
  const int row = bm + wid * 16 + l4 * 4;
  float rsv[4];
  if (rs) {
    #pragma unroll
    for (int j = 0; j < 4; ++j) rsv[j] = rs[row + j];
  }
  #pragma unroll
  for (int n4 = 0; n4 < 16; ++n4) {
    int col = n4 * 16 + l15;
    float base = c0 ? c0[col] : 0.0f;
    float cv = rs ? cvec[col] : 0.0f;
    #pragma unroll
    for (int j = 0; j < 4; ++j) {
      float v = acc[n4][j] + base;
      if (rs) v += rsv[j] * cv;
      if (relu) v = fmaxf(v, 0.0f);
      if (OUTBF)
        ((unsigned short*)Cout)[(size_t)(row + j) * 256 + col] = f2bf(v);
      else
        ((float*)Cout)[(size_t)(row + j) * ldc + coff + col] = v;
    }
  }
}

// ================= CSR build =================
__global__ __launch_bounds__(256) void count_kernel(
    const int* __restrict__ rw, int* __restrict__ cnt, int nnz)
{
  int e = blockIdx.x * 256 + threadIdx.x;
  if (e < nnz) atomicAdd(&cnt[rw[e]], 1);
}

__global__ __launch_bounds__(256) void scan1_kernel(
    const int* __restrict__ cnt, int* __restrict__ bsum, int n)
{
  __shared__ int sh[256];
  int i = blockIdx.x * 256 + threadIdx.x;
  sh[threadIdx.x] = (i < n) ? cnt[i] : 0;
  __syncthreads();
  for (int off = 128; off; off >>= 1) {
    if (threadIdx.x < off) sh[threadIdx.x] += sh[threadIdx.x + off];
    __syncthreads();
  }
  if (threadIdx.x == 0) bsum[blockIdx.x] = sh[0];
}

__global__ __launch_bounds__(256) void scan2_kernel(int* __restrict__ bsum, int nb)
{
  __shared__ int sh[256];
  int v = (threadIdx.x < nb) ? bsum[threadIdx.x] : 0;
  sh[threadIdx.x] = v;
  __syncthreads();
  for (int off = 1; off < 256; off <<= 1) {
    int add = (threadIdx.x >= off) ? sh[threadIdx.x - off] : 0;
    __syncthreads();
    sh[threadIdx.x] += add;
    __syncthreads();
  }
  if (threadIdx.x < nb) bsum[threadIdx.x] = sh[threadIdx.x] - v;  // exclusive
}

__global__ __launch_bounds__(256) void scan3_kernel(
    const int* __restrict__ cnt, const int* __restrict__ bsum,
    int* __restrict__ rowptr, int n)
{
  __shared__ int sh[256];
  int i = blockIdx.x * 256 + threadIdx.x;
  int v = (i < n) ? cnt[i] : 0;
  sh[threadIdx.x] = v;
  __syncthreads();
  for (int off = 1; off < 256; off <<= 1) {
    int add = (threadIdx.x >= off) ? sh[threadIdx.x - off] : 0;
    __syncthreads();
    sh[threadIdx.x] += add;
    __syncthreads();
  }
  int incl = sh[threadIdx.x];
  int base = bsum[blockIdx.x];
  if (i < n) rowptr[i] = base + incl - v;
  if (i == n - 1) rowptr[n] = base + incl;
}

__global__ __launch_bounds__(256) void fillcsr_kernel(
    const int* __restrict__ rw, const int* __restrict__ cl,
    const float* __restrict__ vl, const int* __restrict__ rowptr,
    int* __restrict__ cur, int* __restrict__ ecol, float* __restrict__ eval,
    int nnz)
{
  int e = blockIdx.x * 256 + threadIdx.x;
  if (e < nnz) {
    int r = rw[e];
    int pos = rowptr[r] + atomicAdd(&cur[r], 1);
    ecol[pos] = cl[e];
    eval[pos] = vl[e];
  }
}

// rs[r] = sum of eval over row r
__global__ __launch_bounds__(256) void rowsum_kernel(
    const int* __restrict__ rowptr, const float* __restrict__ eval,
    float* __restrict__ rs, int n)
{
  int i = blockIdx.x * 256 + threadIdx.x;
  if (i >= n) return;
  float s = 0.0f;
  int end = rowptr[i + 1];
  for (int e = rowptr[i]; e < end; ++e) s += eval[e];
  rs[i] = s;
}

// ---------------- CSR SpMM v2: wave-per-row, ushort4 gathers ----------------
// 256 threads = 4 waves = 4 rows/block. Lane owns features [lane*4, lane*4+4).
// 2-edge unrolled gather for ILP. bf16 out (+opt fp32 dual write).
__global__ __launch_bounds__(256) void csr_spmm_kernel(
    const int* __restrict__ rowptr, const int* __restrict__ ecol,
    const float* __restrict__ eval, const unsigned short* __restrict__ X,
    unsigned short* __restrict__ Y, int src_rows,
    const float* __restrict__ bias, int relu, float* __restrict__ Y2)
{
  const int wave = threadIdx.x >> 6, lane = threadIdx.x & 63;
  const int r = blockIdx.x * 4 + wave;
  const int f0 = lane * 4;
  int e = rowptr[r], end = rowptr[r + 1];
  float a0 = 0.0f, a1 = 0.0f, a2 = 0.0f, a3 = 0.0f;
  for (; e + 1 < end; e += 2) {
    int c0i = ecol[e], c1i = ecol[e + 1];
    float v0 = eval[e], v1 = eval[e + 1];
    ushort4 x0 = {0, 0, 0, 0}, x1 = {0, 0, 0, 0};
    if (c0i < src_rows) x0 = *(const ushort4*)(X + (size_t)c0i * DD + f0);
    if (c1i < src_rows) x1 = *(const ushort4*)(X + (size_t)c1i * DD + f0);
    if (c0i < src_rows) {
      a0 += v0 * bf2f(x0.x); a1 += v0 * bf2f(x0.y);
      a2 += v0 * bf2f(x0.z); a3 += v0 * bf2f(x0.w);
    }
    if (c1i < src_rows) {
      a0 += v1 * bf2f(x1.x); a1 += v1 * bf2f(x1.y);
      a2 += v1 * bf2f(x1.z); a3 += v1 * bf2f(x1.w);
    }
  }
  if (e < end) {
    int c = ecol[e];
    float v = eval[e];
    if (c < src_rows) {
      ushort4 xx = *(const ushort4*)(X + (size_t)c * DD + f0);
      a0 += v * bf2f(xx.x); a1 += v * bf2f(xx.y);
      a2 += v * bf2f(xx.z); a3 += v * bf2f(xx.w);
    }
  }
  if (bias) {
    a0 += bias[f0]; a1 += bias[f0 + 1]; a2 += bias[f0 + 2]; a3 += bias[f0 + 3];
  }
  if (relu) {
    a0 = fmaxf(a0, 0.0f); a1 = fmaxf(a1, 0.0f);
    a2 = fmaxf(a2, 0.0f); a3 = fmaxf(a3, 0.0f);
  }
  uint2 yb = { cvtpk(a0, a1), cvtpk(a2, a3) };
  *(uint2*)(Y + (size_t)r * DD + f0) = yb;
  if (Y2) {
    float4 yf = {a0, a1, a2, a3};
    *(float4*)(Y2 + (size_t)r * DD + f0) = yf;
  }
}

// ---------------- MFMA flash attention (bf16 in/out, exp2 domain) ----------
// Q pre-scaled by (1/sqrt(32))*log2(e) at weight prep.
__global__ __launch_bounds__(256) void attn_mfma_kernel(
    const unsigned short* __restrict__ Q, const unsigned short* __restrict__ K,
    const unsigned short* __restrict__ V, unsigned short* __restrict__ O)
{
  __shared__ __align__(16) char sKb[4096];   // [64 key][32 d], swz (key&7)<<4
  __shared__ __align__(16) char sVb[4096];   // [32 d][64 key], swz d-fold
  __shared__ __align__(16) char sPb[8192];   // per-wave [16 q][64 key]
  const int c = blockIdx.z, h = blockIdx.y;
  const int tid = threadIdx.x, lane = tid & 63, wid = tid >> 6;
  const int l15 = lane & 15, l4 = lane >> 4;
  char* sPw = sPb + wid * 2048;
  const size_t base = (size_t)c * (CHK * DD) + (size_t)h * DHEAD;
  const int q0 = blockIdx.x * 64 + wid * 16;

  bf16x8 qf = *(const bf16x8*)(Q + base + (size_t)(q0 + l15) * DD + l4 * 8);

  const int key_s = tid >> 2, dq = (tid & 3) * 8;
  const unsigned short* Kp = K + base + (size_t)key_s * DD + dq;
  const unsigned short* Vp = V + base + (size_t)key_s * DD + dq;
  const int kaddr = ((key_s << 6) + (dq << 1)) ^ ((key_s & 7) << 4);

  f32x4 oacc[2] = {};
  float m = -1e30f, l = 0.0f;
  const f32x4 zero = {};

  for (int kt = 0; kt < CHK; kt += 64) {
    __syncthreads();
    u16x8 kv = *(const u16x8*)Kp;  Kp += 64 * DD;
    u16x8 vv = *(const u16x8*)Vp;  Vp += 64 * DD;
    *(u16x8*)(sKb + kaddr) = kv;
    #pragma unroll
    for (int i = 0; i < 8; ++i) {
      // full XOR swizzle per element (r5-proven form; do NOT fold into an add)
      int d = dq + i;
      int bb = ((d << 7) + (key_s << 1))
             ^ ((d & 7) << 4) ^ (((d >> 3) & 3) << 5);
      *(unsigned short*)(sVb + bb) = vv[i];
    }
    __syncthreads();

    f32x4 s[4];
    #pragma unroll
    for (int s4 = 0; s4 < 4; ++s4) {
      int key = s4 * 16 + l15;
      int ba = ((key << 6) + (l4 << 4)) ^ ((key & 7) << 4);
      bf16x8 kf = *(const bf16x8*)(sKb + ba);
      s[s4] = __builtin_amdgcn_mfma_f32_16x16x32_bf16(kf, qf, zero, 0, 0, 0);
    }
    float tmax = -1e30f;
    #pragma unroll
    for (int s4 = 0; s4 < 4; ++s4)
      #pragma unroll
      for (int j = 0; j < 4; ++j) tmax = fmaxf(tmax, s[s4][j]);
    tmax = fmaxf(tmax, __shfl_xor(tmax, 16));
    tmax = fmaxf(tmax, __shfl_xor(tmax, 32));
    float mnew = fmaxf(m, tmax);
    float corr = __builtin_amdgcn_exp2f(m - mnew);
    float psum = 0.0f;
    float p[4][4];
    #pragma unroll
    for (int s4 = 0; s4 < 4; ++s4)
      #pragma unroll
      for (int j = 0; j < 4; ++j) {
        p[s4][j] = __builtin_amdgcn_exp2f(s[s4][j] - mnew);
        psum += p[s4][j];
      }
    psum += __shfl_xor(psum, 16);
    psum += __shfl_xor(psum, 32);
    l = l * corr + psum;
    m = mnew;
    oacc[0] *= corr;
    oacc[1] *= corr;
    #pragma unroll
    for (int s4 = 0; s4 < 4; ++s4) {
      uint2 pk = { cvtpk(p[s4][0], p[s4][1]), cvtpk(p[s4][2], p[s4][3]) };
      int bp = ((l15 << 7) + (s4 << 5) + (l4 << 3)) ^ ((l15 & 7) << 4);
      *(uint2*)(sPw + bp) = pk;
    }
    __syncthreads();

    #pragma unroll
    for (int dh = 0; dh < 2; ++dh)
      #pragma unroll
      for (int kh = 0; kh < 2; ++kh) {
        int d = dh * 16 + l15;
        int ba = ((d << 7) + ((kh * 32 + l4 * 8) << 1))
               ^ ((d & 7) << 4) ^ (((d >> 3) & 3) << 5);
        bf16x8 vf = *(const bf16x8*)(sVb + ba);
        int bp = ((l15 << 7) + (kh << 6) + (l4 << 4)) ^ ((l15 & 7) << 4);
        bf16x8 pf = *(const bf16x8*)(sPw + bp);
        oacc[dh] = __builtin_amdgcn_mfma_f32_16x16x32_bf16(vf, pf, oacc[dh], 0, 0, 0);
      }
  }

  float inv = 1.0f / l;
  unsigned short* orow = O + base + (size_t)(q0 + l15) * DD;
  #pragma unroll
  for (int dh = 0; dh < 2; ++dh) {
    uint2 o2 = { cvtpk(oacc[dh][0] * inv, oacc[dh][1] * inv),
                 cvtpk(oacc[dh][2] * inv, oacc[dh][3] * inv) };
    *(uint2*)(orow + dh * 16 + l4 * 4) = o2;
  }
}

// sentinel: error value identifies which runtime check failed
__global__ __launch_bounds__(256) void fill_kernel(float* p, long n, float v)
{
  long i = (long)blockIdx.x * 256 + threadIdx.x;
  if (i < n) p[i] = v;
}

extern "C" void kernel_launch(void* const* d_in, const int* in_sizes, int n_in,
                              void* d_out, int out_size, void* d_ws, size_t ws_size,
                              hipStream_t stream)
{
  const float* x     = (const float*)d_in[0];
  const int*   Acg_r = (const int*)d_in[1];
  const int*   Acg_c = (const int*)d_in[2];
  const float* Acg_v = (const float*)d_in[3];
  const int*   Ahy_r = (const int*)d_in[4];
  const int*   Ahy_c = (const int*)d_in[5];
  const float* Ahy_v = (const float*)d_in[6];
  const int*   Asg_r = (const int*)d_in[7];
  const int*   Asg_c = (const int*)d_in[8];
  const float* Asg_v = (const float*)d_in[9];
  const int*   Lcg_r = (const int*)d_in[10];
  const int*   Lcg_c = (const int*)d_in[11];
  const float* Lcg_v = (const float*)d_in[12];
  const int*   Lhy_r = (const int*)d_in[13];
  const int*   Lhy_c = (const int*)d_in[14];
  const float* Lhy_v = (const float*)d_in[15];
  const int*   Lsg_r = (const int*)d_in[16];
  const int*   Lsg_c = (const int*)d_in[17];
  const float* Lsg_v = (const float*)d_in[18];
  const float* cg_W  = (const float*)d_in[19];
  const float* cg_b  = (const float*)d_in[20];
  const float* hg_W  = (const float*)d_in[21];
  const float* hg_b  = (const float*)d_in[22];
  const float* sg_W  = (const float*)d_in[23];
  const float* sg_b  = (const float*)d_in[24];
  const float* snh_W = (const float*)d_in[25];
  const float* snh_b = (const float*)d_in[26];
  const float* snc_W = (const float*)d_in[27];
  const float* snc_b = (const float*)d_in[28];
  const float* sns_W = (const float*)d_in[29];
  const float* sns_b = (const float*)d_in[30];
  const float* spa_hyp_W  = (const float*)d_in[31];
  const float* spa_hyp_b  = (const float*)d_in[32];
  const float* spa_star_W = (const float*)d_in[33];
  const float* spa_star_b = (const float*)d_in[34];
  const float* spa_clq_W  = (const float*)d_in[35];
  const float* spa_clq_b  = (const float*)d_in[36];
  const float* spa_in_w   = (const float*)d_in[37];
  const float* spa_in_b   = (const float*)d_in[38];
  const float* spa_out_w  = (const float*)d_in[39];
  const float* spa_out_b  = (const float*)d_in[40];
  const float* spe_hyp_W  = (const float*)d_in[41];
  const float* spe_hyp_b  = (const float*)d_in[42];
  const float* spe_star_W = (const float*)d_in[43];
  const float* spe_star_b = (const float*)d_in[44];
  const float* spe_clq_W  = (const float*)d_in[45];
  const float* spe_clq_b  = (const float*)d_in[46];
  const float* spe_in_w   = (const float*)d_in[47];
  const float* spe_in_b   = (const float*)d_in[48];
  const float* spe_out_w  = (const float*)d_in[49];
  const float* spe_out_b  = (const float*)d_in[50];

  float* out = (float*)d_out;

  const size_t NF = (size_t)NN * DD;
  const size_t MF = (size_t)MM * DD;
  const size_t EDG_TOT = 4 * (size_t)NEN + 2 * (size_t)NEM;
  const size_t RP_TOT  = 4 * (size_t)(NN + 1) + 2 * (size_t)(MM + 1);
  const size_t WELEMS  = 14u * 65536u;
  const size_t need = (3 * MF + 9 * NF) * 2                       // bf16 bufs
                    + ((size_t)3 * NN + 65536 + 256 + 4096) * 4   // fp32 small
                    + (RP_TOT + 2 * EDG_TOT + MM + 256) * 4       // csr
                    + WELEMS * 2;

  auto fill = [&](float v) {
    long tot = (long)out_size;
    fill_kernel<<<dim3((unsigned)((tot + 255) / 256)), 256, 0, stream>>>(out, tot, v);
  };
  if (ws_size < need)                        { fill(12.0f); return; }
  if (n_in != 51)                            { fill(16.0f); return; }
  if (in_sizes[0] != NN * FD)                { fill(20.0f); return; }
  if (in_sizes[3] != NEN)                    { fill(24.0f); return; }
  if (in_sizes[9] != NEM)                    { fill(28.0f); return; }
  if (in_sizes[19] != 2 * FD * DD)           { fill(32.0f); return; }
  if (in_sizes[37] != 3 * DD * DD)           { fill(36.0f); return; }
  if (out_size != NN * 512 + NN * DD + EHN * DD) { fill(40.0f); return; }

  // ---- bf16 buffers ----
  unsigned short* T  = (unsigned short*)d_ws;   // M staging (gemm out -> spmm in)
  unsigned short* H  = T + MF;                  // M expan hidden
  unsigned short* SG = H + MF;                  // sg_feat (M)
  unsigned short* CG = SG + MF;                 // cg_feat (N)
  unsigned short* HG = CG + NF;                 // hg_feat (N)
  unsigned short* LH = HG + NF;                 // L_hyp . HG
  unsigned short* LC = LH + NF;                 // L_cg  . CG
  unsigned short* LS = LC + NF;                 // L_sg  . SG (first N rows)
  unsigned short* QH = LS + NF;
  unsigned short* KH = QH + NF;
  unsigned short* VH = KH + NF;
  unsigned short* AO = VH + NF;

  // ---- fp32 small ----
  float* fp = (float*)(AO + NF);
  float* rs_h = fp;            fp += NN;
  float* rs_c = fp;            fp += NN;
  float* rs_s = fp;            fp += NN;
  float* tmp256 = fp;          fp += 65536;
  float* tmpv = fp;            fp += 256;
  float* CB = fp;              fp += 4096;   // bias vectors, 16 slots of 256

  // ---- int / weight region ----
  int* ip = (int*)fp;
  int* rp_cg  = ip;              ip += NN + 1;
  int* rp_hy  = ip;              ip += NN + 1;
  int* rp_sg  = ip;              ip += MM + 1;
  int* rp_Lcg = ip;              ip += NN + 1;
  int* rp_Lhy = ip;              ip += NN + 1;
  int* rp_Lsg = ip;              ip += MM + 1;
  int* ec_cg  = ip;              ip += NEN;
  int* ec_hy  = ip;              ip += NEN;
  int* ec_sg  = ip;              ip += NEM;
  int* ec_Lcg = ip;              ip += NEN;
  int* ec_Lhy = ip;              ip += NEN;
  int* ec_Lsg = ip;              ip += NEM;
  float* ev_cg  = (float*)ip;    ip += NEN;
  float* ev_hy  = (float*)ip;    ip += NEN;
  float* ev_sg  = (float*)ip;    ip += NEM;
  float* ev_Lcg = (float*)ip;    ip += NEN;
  float* ev_Lhy = (float*)ip;    ip += NEN;
  float* ev_Lsg = (float*)ip;    ip += NEM;
  int* cnt  = ip;                ip += MM;
  int* bsum = ip;                ip += 256;
  unsigned short* WB = (unsigned short*)ip;

  auto wslot = [&](int s) { return WB + (size_t)s * 65536; };
  auto cb    = [&](int s) { return CB + (size_t)s * 256; };

  auto combine = [&](const float* Bw, const float* Aw, const float* ab,
                     const float* bb, unsigned short* Wc, float* bcp, float fs) {
    combine_w_kernel<<<dim3(256), 256, 0, stream>>>(Bw, Aw, ab, bb, Wc, bcp, fs);
  };
  // triple chain: W = fs*(w3 @ pW @ sW); cvec = fs*(w3 @ (pW@sb)); c0 = fs*(w3@pb + b3)
  auto combine3 = [&](const float* w3, const float* b3, const float* pW,
                      const float* pb, const float* sW, const float* sb,
                      unsigned short* Wc, float* cvecp, float* c0p, float fs) {
    mm256f_kernel<<<dim3(256), 256, 0, stream>>>(pW, sW, tmp256);
    mm256b_kernel<<<dim3(256), 256, 0, stream>>>(w3, tmp256, Wc, fs);
    mv256_kernel<<<dim3(1), 256, 0, stream>>>(pW, sb, nullptr, tmpv, 1.0f);
    mv256_kernel<<<dim3(1), 256, 0, stream>>>(w3, tmpv, nullptr, cvecp, fs);
    mv256_kernel<<<dim3(1), 256, 0, stream>>>(w3, pb, b3, c0p, fs);
  };
  auto gemm32in = [&](const float* A, const unsigned short* Wt,
                      unsigned short* C, int Mrows) {
    gemm2_kernel<0, 1><<<dim3(Mrows / 64), 256, 0, stream>>>(
        A, Wt, nullptr, nullptr, nullptr, C, 256, 0, 0);
  };
  auto gemmbb = [&](const unsigned short* A, const unsigned short* Wt,
                    const float* c0, unsigned short* C, int Mrows) {
    gemm2_kernel<1, 1><<<dim3(Mrows / 64), 256, 0, stream>>>(
        A, Wt, c0, nullptr, nullptr, C, 256, 0, 0);
  };
  auto gemmrs = [&](const unsigned short* A, const unsigned short* Wt,
                    const float* c0, const float* rs, const float* cvec,
                    unsigned short* C, int Mrows) {
    gemm2_kernel<1, 1><<<dim3(Mrows / 64), 256, 0, stream>>>(
        A, Wt, c0, rs, cvec, C, 256, 0, 0);
  };
  auto gemmout = [&](const unsigned short* A, const unsigned short* Wt,
                     const float* c0, float* C, int coff) {
    gemm2_kernel<1, 0><<<dim3(NN / 64), 256, 0, stream>>>(
        A, Wt, c0, nullptr, nullptr, C, 512, coff, 0);
  };
  auto build_csr = [&](const int* rw, const int* cl, const float* vl, int nnz,
                       int nrows, int* rowptr, int* ecol, float* eval) {
    hipMemsetAsync(cnt, 0, (size_t)nrows * 4, stream);
    count_kernel<<<dim3((nnz + 255) / 256), 256, 0, stream>>>(rw, cnt, nnz);
    int nb = (nrows + 255) / 256;
    scan1_kernel<<<dim3(nb), 256, 0, stream>>>(cnt, bsum, nrows);
    scan2_kernel<<<dim3(1), 256, 0, stream>>>(bsum, nb);
    scan3_kernel<<<dim3(nb), 256, 0, stream>>>(cnt, bsum, rowptr, nrows);
    hipMemsetAsync(cnt, 0, (size_t)nrows * 4, stream);
    fillcsr_kernel<<<dim3((nnz + 255) / 256), 256, 0, stream>>>(
        rw, cl, vl, rowptr, cnt, ecol, eval, nnz);
  };
  auto spmm = [&](const int* rowptr, const int* ecol, const float* eval,
                  const unsigned short* X, unsigned short* Y, int srcR, int dstR,
                  const float* bias, bool relu, float* Y2 = nullptr) {
    csr_spmm_kernel<<<dim3(dstR / 4), 256, 0, stream>>>(
        rowptr, ecol, eval, X, Y, srcR, bias, relu ? 1 : 0, Y2);
  };
  auto attn = [&](const unsigned short* Qp, const unsigned short* Kp,
                  const unsigned short* Vp, unsigned short* Op) {
    attn_mfma_kernel<<<dim3(CHK / 64, NHEADS, NN / CHK), 256, 0, stream>>>(
        Qp, Kp, Vp, Op);
  };

  // softmax scale * log2(e): attention works in exp2 domain
  const float fsQ = 0.17677669529663687f * 1.4426950408889634f;

  // ================= weight prep =================
  {
    CastJobs jobs;
    jobs.src[0] = cg_W;           jobs.dst[0] = wslot(0);  jobs.trans[0] = 1;
    jobs.src[1] = cg_W + FD * DD; jobs.dst[1] = wslot(1);  jobs.trans[1] = 1;
    jobs.src[2] = hg_W;           jobs.dst[2] = wslot(2);  jobs.trans[2] = 1;
    jobs.src[3] = hg_W + FD * DD; jobs.dst[3] = wslot(3);  jobs.trans[3] = 1;
    jobs.src[4] = sg_W;           jobs.dst[4] = wslot(4);  jobs.trans[4] = 1;
    jobs.src[5] = sg_W + FD * DD; jobs.dst[5] = wslot(5);  jobs.trans[5] = 1;
    jobs.src[6] = spa_out_w;      jobs.dst[6] = wslot(12); jobs.trans[6] = 0;
    jobs.src[7] = spe_out_w;      jobs.dst[7] = wslot(13); jobs.trans[7] = 0;
    cast_w8_kernel<<<dim3(8 * 256), 256, 0, stream>>>(jobs);
  }
  // spatial QKV (2-chain)
  combine(spa_in_w,                spa_hyp_W,  spa_hyp_b,  spa_in_b,          wslot(6), cb(0), fsQ);
  combine(spa_in_w + DD * DD,      spa_star_W, spa_star_b, spa_in_b + DD,     wslot(7), cb(1), 1.0f);
  combine(spa_in_w + 2 * DD * DD,  spa_clq_W,  spa_clq_b,  spa_in_b + 2 * DD, wslot(8), cb(2), 1.0f);
  // spectral QKV (3-chain: sn-projection folded in; Laplacian bias via rowsum)
  combine3(spe_in_w,               spe_in_b,            spe_hyp_W,  spe_hyp_b,  snh_W, snh_b, wslot(9),  cb(3), cb(4), fsQ);
  combine3(spe_in_w + DD * DD,     spe_in_b + DD,       spe_star_W, spe_star_b, snc_W, snc_b, wslot(10), cb(5), cb(6), 1.0f);
  combine3(spe_in_w + 2 * DD * DD, spe_in_b + 2 * DD,   spe_clq_W,  spe_clq_b,  sns_W, sns_b, wslot(11), cb(7), cb(8), 1.0f);

  // ================= CSR builds (6 graphs) + Laplacian rowsums ============
  build_csr(Acg_r, Acg_c, Acg_v, NEN, NN, rp_cg, ec_cg, ev_cg);
  build_csr(Ahy_r, Ahy_c, Ahy_v, NEN, NN, rp_hy, ec_hy, ev_hy);
  build_csr(Asg_r, Asg_c, Asg_v, NEM, MM, rp_sg, ec_sg, ev_sg);
  build_csr(Lcg_r, Lcg_c, Lcg_v, NEN, NN, rp_Lcg, ec_Lcg, ev_Lcg);
  build_csr(Lhy_r, Lhy_c, Lhy_v, NEN, NN, rp_Lhy, ec_Lhy, ev_Lhy);
  build_csr(Lsg_r, Lsg_c, Lsg_v, NEM, MM, rp_Lsg, ec_Lsg, ev_Lsg);
  rowsum_kernel<<<dim3(NN / 256), 256, 0, stream>>>(rp_Lhy, ev_Lhy, rs_h, NN);
  rowsum_kernel<<<dim3(NN / 256), 256, 0, stream>>>(rp_Lcg, ev_Lcg, rs_c, NN);
  rowsum_kernel<<<dim3(NN / 256), 256, 0, stream>>>(rp_Lsg, ev_Lsg, rs_s, NN);

  // ================= expansion nets =================
  gemm32in(x, wslot(0), T, NN);
  spmm(rp_cg, ec_cg, ev_cg, T, H, NN, NN, cg_b, true);
  gemmbb(H, wslot(1), nullptr, T, NN);
  spmm(rp_cg, ec_cg, ev_cg, T, CG, NN, NN, cg_b + DD, false);

  gemm32in(x, wslot(2), T, NN);
  spmm(rp_hy, ec_hy, ev_hy, T, H, NN, NN, hg_b, true);
  gemmbb(H, wslot(3), nullptr, T, NN);
  spmm(rp_hy, ec_hy, ev_hy, T, HG, NN, NN, hg_b + DD, false);

  // sg: x_star rows >= NN are zero -> src_rows=NN on first spmm
  gemm32in(x, wslot(4), T, NN);
  spmm(rp_sg, ec_sg, ev_sg, T, H, NN, MM, sg_b, true);
  gemmbb(H, wslot(5), nullptr, T, MM);
  // dual write: SG bf16 + X_star/S_star fp32 directly into d_out
  spmm(rp_sg, ec_sg, ev_sg, T, SG, MM, MM, sg_b + DD, false, out + (size_t)NN * 512);

  // ================= Laplacian spmms (sn-projection folded into QKV) ======
  spmm(rp_Lhy, ec_Lhy, ev_Lhy, HG, LH, NN, NN, nullptr, false);
  spmm(rp_Lcg, ec_Lcg, ev_Lcg, CG, LC, NN, NN, nullptr, false);
  spmm(rp_Lsg, ec_Lsg, ev_Lsg, SG, LS, MM, NN, nullptr, false);  // rows < N only

  // ================= spectral MHA =================
  gemmrs(LH, wslot(9),  cb(4), rs_h, cb(3), QH, NN);
  gemmrs(LC, wslot(10), cb(6), rs_c, cb(5), KH, NN);
  gemmrs(LS, wslot(11), cb(8), rs_s, cb(7), VH, NN);
  attn(QH, KH, VH, AO);
  gemmout(AO, wslot(13), spe_out_b, out, 256);   // taa cols 256..511

  // ================= spatial MHA =================
  gemmbb(HG, wslot(6), cb(0), QH, NN);
  gemmbb(CG, wslot(7), cb(1), KH, NN);
  gemmbb(SG, wslot(8), cb(2), VH, NN);
  attn(QH, KH, VH, AO);
  gemmout(AO, wslot(12), spa_out_b, out, 0);     // taa cols 0..255
}

// Round 9
// 1676.726 us; speedup vs baseline: 5.1489x; 1.1182x over previous
//
#include <hip/hip_runtime.h>

// Problem dims (fixed by reference)
#define NN 49152
#define EHN 8192
#define MM (NN + EHN)       // 57344
#define FD 256
#define DD 256
#define NHEADS 8
#define DHEAD 32
#define CHK 1024
#define NEN (10 * NN)       // 491520
#define NEM (10 * MM)       // 573440
#define ROWS_TOT (4 * NN + 2 * MM)   // 311296 (exact multiple of 256)
#define ETOT (4 * NEN + 2 * NEM)     // 3,112,960

typedef __bf16 bf16x8 __attribute__((ext_vector_type(8)));
typedef unsigned short u16x8 __attribute__((ext_vector_type(8)));
typedef float f32x4 __attribute__((ext_vector_type(4)));

// fp32 -> bf16 bits, round-to-nearest-even (identical to v_cvt_pk_bf16_f32)
static __device__ __forceinline__ unsigned short f2bf(float f) {
  unsigned int u = __float_as_uint(f);
  unsigned int r = (u + 0x7FFFu + ((u >> 16) & 1u)) >> 16;
  return (unsigned short)r;
}
static __device__ __forceinline__ float bf2f(unsigned short u) {
  return __uint_as_float((unsigned int)u << 16);
}
static __device__ __forceinline__ unsigned int cvtpk(float a, float b) {
  unsigned int r;
  asm("v_cvt_pk_bf16_f32 %0, %1, %2" : "=v"(r) : "v"(a), "v"(b));
  return r;
}

// ---------------- weight prep ----------------
struct CastJobs {
  const float* src[8];
  unsigned short* dst[8];
  int trans[8];
};
__global__ __launch_bounds__(256) void cast_w8_kernel(CastJobs jobs)
{
  int job = blockIdx.x >> 8;
  int i = (blockIdx.x & 255) * 256 + threadIdx.x;
  int n = i >> 8, k = i & 255;
  const float* src = jobs.src[job];
  float f = jobs.trans[job] ? src[(size_t)k * 256 + n] : src[i];
  jobs.dst[job][i] = f2bf(f);
}

// Wc = Bw @ Aw (bf16), bc = fs*(Bw@ab + bb)
__global__ __launch_bounds__(256) void combine_w_kernel(
    const float* __restrict__ Bw, const float* __restrict__ Aw,
    const float* __restrict__ ab, const float* __restrict__ bb,
    unsigned short* __restrict__ Wc, float* __restrict__ bc, float fscale)
{
  int n = blockIdx.x, t = threadIdx.x;
  __shared__ float shB[256];
  __shared__ float red[256];
  shB[t] = Bw[n * 256 + t];
  __syncthreads();
  float acc = 0.0f;
  #pragma unroll 8
  for (int j = 0; j < 256; ++j) acc += shB[j] * Aw[j * 256 + t];
  Wc[n * 256 + t] = f2bf(acc * fscale);
  red[t] = shB[t] * ab[t];
  __syncthreads();
  for (int off = 128; off; off >>= 1) {
    if (t < off) red[t] += red[t + off];
    __syncthreads();
  }
  if (t == 0) bc[n] = (red[0] + bb[n]) * fscale;
}

__global__ __launch_bounds__(256) void mm256f_kernel(
    const float* __restrict__ A, const float* __restrict__ B,
    float* __restrict__ C)
{
  int n = blockIdx.x, t = threadIdx.x;
  __shared__ float sa[256];
  sa[t] = A[n * 256 + t];
  __syncthreads();
  float acc = 0.0f;
  #pragma unroll 8
  for (int j = 0; j < 256; ++j) acc += sa[j] * B[j * 256 + t];
  C[n * 256 + t] = acc;
}

__global__ __launch_bounds__(256) void mm256b_kernel(
    const float* __restrict__ A, const float* __restrict__ B,
    unsigned short* __restrict__ W, float fs)
{
  int n = blockIdx.x, t = threadIdx.x;
  __shared__ float sa[256];
  sa[t] = A[n * 256 + t];
  __syncthreads();
  float acc = 0.0f;
  #pragma unroll 8
  for (int j = 0; j < 256; ++j) acc += sa[j] * B[j * 256 + t];
  W[n * 256 + t] = f2bf(acc * fs);
}

__global__ __launch_bounds__(256) void mv256_kernel(
    const float* __restrict__ W, const float* __restrict__ v,
    const float* __restrict__ add, float* __restrict__ outv, float fs)
{
  int t = threadIdx.x;
  __shared__ float sv[256];
  sv[t] = v[t];
  __syncthreads();
  float acc = 0.0f;
  #pragma unroll 8
  for (int k = 0; k < 256; ++k) acc += W[t * 256 + k] * sv[k];
  if (add) acc += add[t];
  outv[t] = fs * acc;
}

// ---------------- bf16-MFMA GEMM: C = A[M][256] * Wt^T ----------------
template<int ABF, int OUTBF>
__global__ __launch_bounds__(256) void gemm2_kernel(
    const void* __restrict__ Ain, const unsigned short* __restrict__ Wt,
    const float* __restrict__ c0, const float* __restrict__ rs,
    const float* __restrict__ cvec, void* __restrict__ Cout,
    int ldc, int coff, int relu)
{
  __shared__ __align__(16) char sA[2][4096];    // [64 r][32 k] bf16, swz
  __shared__ __align__(16) char sB[2][16384];   // [256 n][32 k] bf16, swz
  const int tid = threadIdx.x, lane = tid & 63, wid = tid >> 6;
  const int l15 = lane & 15, l4 = lane >> 4;
  const int bm = blockIdx.x * 64;

  f32x4 acc[16] = {};
  const int ar = tid >> 2, akq = (tid & 3) * 8;
  const int bn = tid;

  float4 fa0, fa1;
  u16x8 ua;
  u16x8 rb0, rb1, rb2, rb3;
  auto stage_load = [&](int k0) {
    if (ABF) {
      ua = *(const u16x8*)((const unsigned short*)Ain +
                           (size_t)(bm + ar) * 256 + k0 + akq);
    } else {
      const float* ap = (const float*)Ain + (size_t)(bm + ar) * 256 + k0 + akq;
      fa0 = *(const float4*)ap;
      fa1 = *(const float4*)(ap + 4);
    }
    const unsigned short* bp = Wt + (size_t)bn * 256 + k0;
    rb0 = *(const u16x8*)bp;        rb1 = *(const u16x8*)(bp + 8);
    rb2 = *(const u16x8*)(bp + 16); rb3 = *(const u16x8*)(bp + 24);
  };
  auto stage_write = [&](int buf) {
    u16x8 va;
    if (ABF) {
      va = ua;
    } else {
      va[0] = f2bf(fa0.x); va[1] = f2bf(fa0.y); va[2] = f2bf(fa0.z); va[3] = f2bf(fa0.w);
      va[4] = f2bf(fa1.x); va[5] = f2bf(fa1.y); va[6] = f2bf(fa1.z); va[7] = f2bf(fa1.w);
    }
    int aa = ((ar << 6) + (akq << 1)) ^ ((ar & 7) << 4);
    *(u16x8*)(sA[buf] + aa) = va;
    int bb = (bn << 6) ^ ((bn & 7) << 4);
    *(u16x8*)(sB[buf] + bb) = rb0;
    *(u16x8*)(sB[buf] + (bb ^ 16)) = rb1;
    *(u16x8*)(sB[buf] + (bb ^ 32)) = rb2;
    *(u16x8*)(sB[buf] + (bb ^ 48)) = rb3;
  };

  stage_load(0);
  stage_write(0);
  __syncthreads();
  int cur = 0;
  for (int it = 0; it < 8; ++it) {
    if (it < 7) stage_load((it + 1) * 32);
    int ra = wid * 16 + l15;
    bf16x8 af = *(const bf16x8*)(sA[cur] + ((ra << 6) + (l4 << 4) ^ ((ra & 7) << 4)));
    #pragma unroll
    for (int n4 = 0; n4 < 16; ++n4) {
      int rn = n4 * 16 + l15;
      bf16x8 bf = *(const bf16x8*)(sB[cur] + ((rn << 6) + (l4 << 4) ^ ((rn & 7) << 4)));
      acc[n4] = __builtin_amdgcn_mfma_f32_16x16x32_bf16(af, bf, acc[n4], 0, 0, 0);
    }
    __syncthreads();
    if (it < 7) {
      stage_write(cur ^ 1);
      __syncthreads();
      cur ^= 1;
    }
  }
  const int row = bm + wid * 16 + l4 * 4;
  float rsv[4];
  if (rs) {
    #pragma unroll
    for (int j = 0; j < 4; ++j) rsv[j] = rs[row + j];
  }
  #pragma unroll
  for (int n4 = 0; n4 < 16; ++n4) {
    int col = n4 * 16 + l15;
    float base = c0 ? c0[col] : 0.0f;
    float cv = rs ? cvec[col] : 0.0f;
    #pragma unroll
    for (int j = 0; j < 4; ++j) {
      float v = acc[n4][j] + base;
      if (rs) v += rsv[j] * cv;
      if (relu) v = fmaxf(v, 0.0f);
      if (OUTBF)
        ((unsigned short*)Cout)[(size_t)(row + j) * 256 + col] = f2bf(v);
      else
        ((float*)Cout)[(size_t)(row + j) * ldc + coff + col] = v;
    }
  }
}

// ================= batched CSR build (all 6 graphs, one row/edge space) =====
// graph order: [A_cg, A_hy, A_sg, L_cg, L_hy, L_sg]
// row bases:    0,    NN,   2NN,  2NN+MM, 3NN+MM, 4NN+MM
// edge blocks per graph (x256): 1920,1920,2240,1920,1920,2240 (cum 12160)
struct CooPtrs {
  const int* rw[6];
  const int* cl[6];
  const float* vl[6];
};
static __device__ __forceinline__ void coo_block_resolve(
    int b, int& g, int& eb, int& rb)
{
  if      (b < 1920) { g = 0; eb = 0;    rb = 0; }
  else if (b < 3840) { g = 1; eb = 1920; rb = NN; }
  else if (b < 6080) { g = 2; eb = 3840; rb = 2 * NN; }
  else if (b < 8000) { g = 3; eb = 6080; rb = 2 * NN + MM; }
  else if (b < 9920) { g = 4; eb = 8000; rb = 3 * NN + MM; }
  else               { g = 5; eb = 9920; rb = 4 * NN + MM; }
}

__global__ __launch_bounds__(256) void count_all_kernel(
    CooPtrs coo, int* __restrict__ cnt)
{
  int g, eb, rb;
  coo_block_resolve(blockIdx.x, g, eb, rb);
  int e = (blockIdx.x - eb) * 256 + threadIdx.x;
  atomicAdd(&cnt[rb + coo.rw[g][e]], 1);
}

__global__ __launch_bounds__(256) void scan1_kernel(
    const int* __restrict__ cnt, int* __restrict__ bsum, int n)
{
  __shared__ int sh[256];
  int i = blockIdx.x * 256 + threadIdx.x;
  sh[threadIdx.x] = (i < n) ? cnt[i] : 0;
  __syncthreads();
  for (int off = 128; off; off >>= 1) {
    if (threadIdx.x < off) sh[threadIdx.x] += sh[threadIdx.x + off];
    __syncthreads();
  }
  if (threadIdx.x == 0) bsum[blockIdx.x] = sh[0];
}

// multi-pass exclusive scan of nb block sums, single block
__global__ __launch_bounds__(256) void scan2_kernel(int* __restrict__ bsum, int nb)
{
  __shared__ int sh[256];
  int t = threadIdx.x;
  int carry = 0;
  for (int base = 0; base < nb; base += 256) {
    int i = base + t;
    int v = (i < nb) ? bsum[i] : 0;
    sh[t] = v;
    __syncthreads();
    for (int off = 1; off < 256; off <<= 1) {
      int add = (t >= off) ? sh[t - off] : 0;
      __syncthreads();
      sh[t] += add;
      __syncthreads();
    }
    int incl = sh[t];
    int tot = sh[255];
    if (i < nb) bsum[i] = carry + incl - v;
    carry += tot;
    __syncthreads();
  }
}

// writes global rowptr P; re-zeroes cnt (saves a memset dispatch)
__global__ __launch_bounds__(256) void scan3_kernel(
    const int* __restrict__ cnt, const int* __restrict__ bsum,
    int* __restrict__ rowptr, int* __restrict__ cntz, int n)
{
  __shared__ int sh[256];
  int i = blockIdx.x * 256 + threadIdx.x;
  int v = (i < n) ? cnt[i] : 0;
  sh[threadIdx.x] = v;
  __syncthreads();
  for (int off = 1; off < 256; off <<= 1) {
    int add = (threadIdx.x >= off) ? sh[threadIdx.x - off] : 0;
    __syncthreads();
    sh[threadIdx.x] += add;
    __syncthreads();
  }
  int incl = sh[threadIdx.x];
  int base = bsum[blockIdx.x];
  if (i < n) { rowptr[i] = base + incl - v; cntz[i] = 0; }
  if (i == n - 1) rowptr[n] = base + incl;
}

__global__ __launch_bounds__(256) void fill_all_kernel(
    CooPtrs coo, const int* __restrict__ P, int* __restrict__ cur,
    int* __restrict__ ecol, float* __restrict__ eval)
{
  int g, eb, rb;
  coo_block_resolve(blockIdx.x, g, eb, rb);
  int e = (blockIdx.x - eb) * 256 + threadIdx.x;
  int grow = rb + coo.rw[g][e];
  int pos = P[grow] + atomicAdd(&cur[grow], 1);
  ecol[pos] = coo.cl[g][e];
  eval[pos] = coo.vl[g][e];
}

// rowsums for the 3 Laplacians' first NN rows: rsAll = [rs_Lcg|rs_Lhy|rs_Lsg]
__global__ __launch_bounds__(256) void rowsum_all_kernel(
    const int* __restrict__ P, const float* __restrict__ eval,
    float* __restrict__ rsAll)
{
  int j = blockIdx.x * 256 + threadIdx.x;   // 0 .. 3*NN
  int g = j / NN;
  int r = j - g * NN;
  int grow = (g == 0 ? 2 * NN + MM : g == 1 ? 3 * NN + MM : 4 * NN + MM) + r;
  float s = 0.0f;
  int end = P[grow + 1];
  for (int e = P[grow]; e < end; ++e) s += eval[e];
  rsAll[j] = s;
}

// ---------------- CSR SpMM: wave-per-row, ushort4 gathers, 4-edge unroll ----
__global__ __launch_bounds__(256) void csr_spmm_kernel(
    const int* __restrict__ rowptr, const int* __restrict__ ecol,
    const float* __restrict__ eval, const unsigned short* __restrict__ X,
    unsigned short* __restrict__ Y, int src_rows,
    const float* __restrict__ bias, int relu, float* __restrict__ Y2)
{
  const int wave = threadIdx.x >> 6, lane = threadIdx.x & 63;
  const int r = blockIdx.x * 4 + wave;
  const int f0 = lane * 4;
  int e = rowptr[r], end = rowptr[r + 1];
  float a0 = 0.0f, a1 = 0.0f, a2 = 0.0f, a3 = 0.0f;
  for (; e + 3 < end; e += 4) {
    int c0i = ecol[e], c1i = ecol[e + 1], c2i = ecol[e + 2], c3i = ecol[e + 3];
    float v0 = eval[e], v1 = eval[e + 1], v2 = eval[e + 2], v3 = eval[e + 3];
    ushort4 x0 = {0,0,0,0}, x1 = {0,0,0,0}, x2 = {0,0,0,0}, x3 = {0,0,0,0};
    if (c0i < src_rows) x0 = *(const ushort4*)(X + (size_t)c0i * DD + f0);
    if (c1i < src_rows) x1 = *(const ushort4*)(X + (size_t)c1i * DD + f0);
    if (c2i < src_rows) x2 = *(const ushort4*)(X + (size_t)c2i * DD + f0);
    if (c3i < src_rows) x3 = *(const ushort4*)(X + (size_t)c3i * DD + f0);
    if (c0i < src_rows) { a0 += v0*bf2f(x0.x); a1 += v0*bf2f(x0.y); a2 += v0*bf2f(x0.z); a3 += v0*bf2f(x0.w); }
    if (c1i < src_rows) { a0 += v1*bf2f(x1.x); a1 += v1*bf2f(x1.y); a2 += v1*bf2f(x1.z); a3 += v1*bf2f(x1.w); }
    if (c2i < src_rows) { a0 += v2*bf2f(x2.x); a1 += v2*bf2f(x2.y); a2 += v2*bf2f(x2.z); a3 += v2*bf2f(x2.w); }
    if (c3i < src_rows) { a0 += v3*bf2f(x3.x); a1 += v3*bf2f(x3.y); a2 += v3*bf2f(x3.z); a3 += v3*bf2f(x3.w); }
  }
  for (; e < end; ++e) {
    int c = ecol[e];
    float v = eval[e];
    if (c < src_rows) {
      ushort4 xx = *(const ushort4*)(X + (size_t)c * DD + f0);
      a0 += v * bf2f(xx.x); a1 += v * bf2f(xx.y);
      a2 += v * bf2f(xx.z); a3 += v * bf2f(xx.w);
    }
  }
  if (bias) {
    a0 += bias[f0]; a1 += bias[f0 + 1]; a2 += bias[f0 + 2]; a3 += bias[f0 + 3];
  }
  if (relu) {
    a0 = fmaxf(a0, 0.0f); a1 = fmaxf(a1, 0.0f);
    a2 = fmaxf(a2, 0.0f); a3 = fmaxf(a3, 0.0f);
  }
  uint2 yb = { cvtpk(a0, a1), cvtpk(a2, a3) };
  *(uint2*)(Y + (size_t)r * DD + f0) = yb;
  if (Y2) {
    float4 yf = {a0, a1, a2, a3};
    *(float4*)(Y2 + (size_t)r * DD + f0) = yf;
  }
}

// ---------------- MFMA flash attention (bf16 in/out, exp2 domain) ----------
// 1D grid 6144, XCD-swizzled so each XCD owns whole chunks (K/V L2 locality).
// Defer-max: skip O/l rescale while tile max stays within 8 of running max.
__global__ __launch_bounds__(256) void attn_mfma_kernel(
    const unsigned short* __restrict__ Q, const unsigned short* __restrict__ K,
    const unsigned short* __restrict__ V, unsigned short* __restrict__ O)
{
  __shared__ __align__(16) char sKb[4096];
  __shared__ __align__(16) char sVb[4096];
  __shared__ __align__(16) char sPb[8192];
  // XCD swizzle: 6144 blocks, 8 XCDs -> 768 contiguous wgids per XCD
  const int wgid = (blockIdx.x & 7) * 768 + (blockIdx.x >> 3);
  const int qb = wgid & 15, h = (wgid >> 4) & 7, c = wgid >> 7;
  const int tid = threadIdx.x, lane = tid & 63, wid = tid >> 6;
  const int l15 = lane & 15, l4 = lane >> 4;
  char* sPw = sPb + wid * 2048;
  const size_t base = (size_t)c * (CHK * DD) + (size_t)h * DHEAD;
  const int q0 = qb * 64 + wid * 16;

  bf16x8 qf = *(const bf16x8*)(Q + base + (size_t)(q0 + l15) * DD + l4 * 8);

  const int key_s = tid >> 2, dq = (tid & 3) * 8;
  const unsigned short* Kp = K + base + (size_t)key_s * DD + dq;
  const unsigned short* Vp = V + base + (size_t)key_s * DD + dq;
  const int kaddr = ((key_s << 6) + (dq << 1)) ^ ((key_s & 7) << 4);

  f32x4 oacc[2] = {};
  float m = -1e30f, l = 0.0f;
  const f32x4 zero = {};

  for (int kt = 0; kt < CHK; kt += 64) {
    __syncthreads();
    u16x8 kv = *(const u16x8*)Kp;  Kp += 64 * DD;
    u16x8 vv = *(const u16x8*)Vp;  Vp += 64 * DD;
    *(u16x8*)(sKb + kaddr) = kv;
    #pragma unroll
    for (int i = 0; i < 8; ++i) {
      int d = dq + i;
      int bb = ((d << 7) + (key_s << 1))
             ^ ((d & 7) << 4) ^ (((d >> 3) & 3) << 5);
      *(unsigned short*)(sVb + bb) = vv[i];
    }
    __syncthreads();

    f32x4 s[4];
    #pragma unroll
    for (int s4 = 0; s4 < 4; ++s4) {
      int key = s4 * 16 + l15;
      int ba = ((key << 6) + (l4 << 4)) ^ ((key & 7) << 4);
      bf16x8 kf = *(const bf16x8*)(sKb + ba);
      s[s4] = __builtin_amdgcn_mfma_f32_16x16x32_bf16(kf, qf, zero, 0, 0, 0);
    }
    float tmax = -1e30f;
    #pragma unroll
    for (int s4 = 0; s4 < 4; ++s4)
      #pragma unroll
      for (int j = 0; j < 4; ++j) tmax = fmaxf(tmax, s[s4][j]);
    tmax = fmaxf(tmax, __shfl_xor(tmax, 16));
    tmax = fmaxf(tmax, __shfl_xor(tmax, 32));
    // defer-max (T13): P bounded by 2^8 in exp2 domain; bf16/fp32 tolerate
    bool skip = __all(tmax - m <= 8.0f);
    float mnew = skip ? m : fmaxf(m, tmax);
    if (!skip) {
      float corr = __builtin_amdgcn_exp2f(m - mnew);
      l *= corr;
      oacc[0] *= corr;
      oacc[1] *= corr;
    }
    float psum = 0.0f;
    float p[4][4];
    #pragma unroll
    for (int s4 = 0; s4 < 4; ++s4)
      #pragma unroll
      for (int j = 0; j < 4; ++j) {
        p[s4][j] = __builtin_amdgcn_exp2f(s[s4][j] - mnew);
        psum += p[s4][j];
      }
    psum += __shfl_xor(psum, 16);
    psum += __shfl_xor(psum, 32);
    l += psum;
    m = mnew;
    #pragma unroll
    for (int s4 = 0; s4 < 4; ++s4) {
      uint2 pk = { cvtpk(p[s4][0], p[s4][1]), cvtpk(p[s4][2], p[s4][3]) };
      int bp = ((l15 << 7) + (s4 << 5) + (l4 << 3)) ^ ((l15 & 7) << 4);
      *(uint2*)(sPw + bp) = pk;
    }
    __syncthreads();

    #pragma unroll
    for (int dh = 0; dh < 2; ++dh)
      #pragma unroll
      for (int kh = 0; kh < 2; ++kh) {
        int d = dh * 16 + l15;
        int ba = ((d << 7) + ((kh * 32 + l4 * 8) << 1))
               ^ ((d & 7) << 4) ^ (((d >> 3) & 3) << 5);
        bf16x8 vf = *(const bf16x8*)(sVb + ba);
        int bp = ((l15 << 7) + (kh << 6) + (l4 << 4)) ^ ((l15 & 7) << 4);
        bf16x8 pf = *(const bf16x8*)(sPw + bp);
        oacc[dh] = __builtin_amdgcn_mfma_f32_16x16x32_bf16(vf, pf, oacc[dh], 0, 0, 0);
      }
  }

  float inv = 1.0f / l;
  unsigned short* orow = O + base + (size_t)(q0 + l15) * DD;
  #pragma unroll
  for (int dh = 0; dh < 2; ++dh) {
    uint2 o2 = { cvtpk(oacc[dh][0] * inv, oacc[dh][1] * inv),
                 cvtpk(oacc[dh][2] * inv, oacc[dh][3] * inv) };
    *(uint2*)(orow + dh * 16 + l4 * 4) = o2;
  }
}

// sentinel: error value identifies which runtime check failed
__global__ __launch_bounds__(256) void fill_kernel(float* p, long n, float v)
{
  long i = (long)blockIdx.x * 256 + threadIdx.x;
  if (i < n) p[i] = v;
}

extern "C" void kernel_launch(void* const* d_in, const int* in_sizes, int n_in,
                              void* d_out, int out_size, void* d_ws, size_t ws_size,
                              hipStream_t stream)
{
  const float* x     = (const float*)d_in[0];
  const int*   Acg_r = (const int*)d_in[1];
  const int*   Acg_c = (const int*)d_in[2];
  const float* Acg_v = (const float*)d_in[3];
  const int*   Ahy_r = (const int*)d_in[4];
  const int*   Ahy_c = (const int*)d_in[5];
  const float* Ahy_v = (const float*)d_in[6];
  const int*   Asg_r = (const int*)d_in[7];
  const int*   Asg_c = (const int*)d_in[8];
  const float* Asg_v = (const float*)d_in[9];
  const int*   Lcg_r = (const int*)d_in[10];
  const int*   Lcg_c = (const int*)d_in[11];
  const float* Lcg_v = (const float*)d_in[12];
  const int*   Lhy_r = (const int*)d_in[13];
  const int*   Lhy_c = (const int*)d_in[14];
  const float* Lhy_v = (const float*)d_in[15];
  const int*   Lsg_r = (const int*)d_in[16];
  const int*   Lsg_c = (const int*)d_in[17];
  const float* Lsg_v = (const float*)d_in[18];
  const float* cg_W  = (const float*)d_in[19];
  const float* cg_b  = (const float*)d_in[20];
  const float* hg_W  = (const float*)d_in[21];
  const float* hg_b  = (const float*)d_in[22];
  const float* sg_W  = (const float*)d_in[23];
  const float* sg_b  = (const float*)d_in[24];
  const float* snh_W = (const float*)d_in[25];
  const float* snh_b = (const float*)d_in[26];
  const float* snc_W = (const float*)d_in[27];
  const float* snc_b = (const float*)d_in[28];
  const float* sns_W = (const float*)d_in[29];
  const float* sns_b = (const float*)d_in[30];
  const float* spa_hyp_W  = (const float*)d_in[31];
  const float* spa_hyp_b  = (const float*)d_in[32];
  const float* spa_star_W = (const float*)d_in[33];
  const float* spa_star_b = (const float*)d_in[34];
  const float* spa_clq_W  = (const float*)d_in[35];
  const float* spa_clq_b  = (const float*)d_in[36];
  const float* spa_in_w   = (const float*)d_in[37];
  const float* spa_in_b   = (const float*)d_in[38];
  const float* spa_out_w  = (const float*)d_in[39];
  const float* spa_out_b  = (const float*)d_in[40];
  const float* spe_hyp_W  = (const float*)d_in[41];
  const float* spe_hyp_b  = (const float*)d_in[42];
  const float* spe_star_W = (const float*)d_in[43];
  const float* spe_star_b = (const float*)d_in[44];
  const float* spe_clq_W  = (const float*)d_in[45];
  const float* spe_clq_b  = (const float*)d_in[46];
  const float* spe_in_w   = (const float*)d_in[47];
  const float* spe_in_b   = (const float*)d_in[48];
  const float* spe_out_w  = (const float*)d_in[49];
  const float* spe_out_b  = (const float*)d_in[50];

  float* out = (float*)d_out;

  const size_t NF = (size_t)NN * DD;
  const size_t MF = (size_t)MM * DD;
  const size_t WELEMS  = 14u * 65536u;
  const size_t need = (3 * MF + 9 * NF) * 2
                    + ((size_t)3 * NN + 65536 + 256 + 4096) * 4
                    + ((size_t)ROWS_TOT + 1 + 2 * (size_t)ETOT + ROWS_TOT + 2048) * 4
                    + WELEMS * 2;

  auto fill = [&](float v) {
    long tot = (long)out_size;
    fill_kernel<<<dim3((unsigned)((tot + 255) / 256)), 256, 0, stream>>>(out, tot, v);
  };
  if (ws_size < need)                        { fill(12.0f); return; }
  if (n_in != 51)                            { fill(16.0f); return; }
  if (in_sizes[0] != NN * FD)                { fill(20.0f); return; }
  if (in_sizes[3] != NEN)                    { fill(24.0f); return; }
  if (in_sizes[9] != NEM)                    { fill(28.0f); return; }
  if (in_sizes[19] != 2 * FD * DD)           { fill(32.0f); return; }
  if (in_sizes[37] != 3 * DD * DD)           { fill(36.0f); return; }
  if (out_size != NN * 512 + NN * DD + EHN * DD) { fill(40.0f); return; }

  // ---- bf16 buffers ----
  unsigned short* T  = (unsigned short*)d_ws;
  unsigned short* H  = T + MF;
  unsigned short* SG = H + MF;
  unsigned short* CG = SG + MF;
  unsigned short* HG = CG + NF;
  unsigned short* LH = HG + NF;
  unsigned short* LC = LH + NF;
  unsigned short* LS = LC + NF;
  unsigned short* QH = LS + NF;
  unsigned short* KH = QH + NF;
  unsigned short* VH = KH + NF;
  unsigned short* AO = VH + NF;

  // ---- fp32 small ----
  float* fp = (float*)(AO + NF);
  float* rsAll = fp;           fp += 3 * NN;   // [rs_Lcg | rs_Lhy | rs_Lsg]
  float* tmp256 = fp;          fp += 65536;
  float* tmpv = fp;            fp += 256;
  float* CB = fp;              fp += 4096;

  // ---- int / weight region (global CSR over all 6 graphs) ----
  int* ip = (int*)fp;
  int* P    = ip;              ip += ROWS_TOT + 1;
  int* ecol = ip;              ip += ETOT;
  float* eval = (float*)ip;    ip += ETOT;
  int* cnt  = ip;              ip += ROWS_TOT;
  int* bsum = ip;              ip += 2048;
  unsigned short* WB = (unsigned short*)ip;

  // per-graph rowptr views into global P (values are global edge indices)
  int* rp_cg  = P;
  int* rp_hy  = P + NN;
  int* rp_sg  = P + 2 * NN;
  int* rp_Lcg = P + 2 * NN + MM;
  int* rp_Lhy = P + 3 * NN + MM;
  int* rp_Lsg = P + 4 * NN + MM;
  float* rs_c = rsAll;
  float* rs_h = rsAll + NN;
  float* rs_s = rsAll + 2 * NN;

  auto wslot = [&](int s) { return WB + (size_t)s * 65536; };
  auto cb    = [&](int s) { return CB + (size_t)s * 256; };

  auto combine = [&](const float* Bw, const float* Aw, const float* ab,
                     const float* bb, unsigned short* Wc, float* bcp, float fs) {
    combine_w_kernel<<<dim3(256), 256, 0, stream>>>(Bw, Aw, ab, bb, Wc, bcp, fs);
  };
  auto combine3 = [&](const float* w3, const float* b3, const float* pW,
                      const float* pb, const float* sW, const float* sb,
                      unsigned short* Wc, float* cvecp, float* c0p, float fs) {
    mm256f_kernel<<<dim3(256), 256, 0, stream>>>(pW, sW, tmp256);
    mm256b_kernel<<<dim3(256), 256, 0, stream>>>(w3, tmp256, Wc, fs);
    mv256_kernel<<<dim3(1), 256, 0, stream>>>(pW, sb, nullptr, tmpv, 1.0f);
    mv256_kernel<<<dim3(1), 256, 0, stream>>>(w3, tmpv, nullptr, cvecp, fs);
    mv256_kernel<<<dim3(1), 256, 0, stream>>>(w3, pb, b3, c0p, fs);
  };
  auto gemm32in = [&](const float* A, const unsigned short* Wt,
                      unsigned short* C, int Mrows) {
    gemm2_kernel<0, 1><<<dim3(Mrows / 64), 256, 0, stream>>>(
        A, Wt, nullptr, nullptr, nullptr, C, 256, 0, 0);
  };
  auto gemmbb = [&](const unsigned short* A, const unsigned short* Wt,
                    const float* c0, unsigned short* C, int Mrows) {
    gemm2_kernel<1, 1><<<dim3(Mrows / 64), 256, 0, stream>>>(
        A, Wt, c0, nullptr, nullptr, C, 256, 0, 0);
  };
  auto gemmrs = [&](const unsigned short* A, const unsigned short* Wt,
                    const float* c0, const float* rs, const float* cvec,
                    unsigned short* C, int Mrows) {
    gemm2_kernel<1, 1><<<dim3(Mrows / 64), 256, 0, stream>>>(
        A, Wt, c0, rs, cvec, C, 256, 0, 0);
  };
  auto gemmout = [&](const unsigned short* A, const unsigned short* Wt,
                     const float* c0, float* C, int coff) {
    gemm2_kernel<1, 0><<<dim3(NN / 64), 256, 0, stream>>>(
        A, Wt, c0, nullptr, nullptr, C, 512, coff, 0);
  };
  auto spmm = [&](const int* rowptr, const unsigned short* X, unsigned short* Y,
                  int srcR, int dstR, const float* bias, bool relu,
                  float* Y2 = nullptr) {
    csr_spmm_kernel<<<dim3(dstR / 4), 256, 0, stream>>>(
        rowptr, ecol, eval, X, Y, srcR, bias, relu ? 1 : 0, Y2);
  };
  auto attn = [&](const unsigned short* Qp, const unsigned short* Kp,
                  const unsigned short* Vp, unsigned short* Op) {
    attn_mfma_kernel<<<dim3(6144), 256, 0, stream>>>(Qp, Kp, Vp, Op);
  };

  const float fsQ = 0.17677669529663687f * 1.4426950408889634f;

  // ================= weight prep =================
  {
    CastJobs jobs;
    jobs.src[0] = cg_W;           jobs.dst[0] = wslot(0);  jobs.trans[0] = 1;
    jobs.src[1] = cg_W + FD * DD; jobs.dst[1] = wslot(1);  jobs.trans[1] = 1;
    jobs.src[2] = hg_W;           jobs.dst[2] = wslot(2);  jobs.trans[2] = 1;
    jobs.src[3] = hg_W + FD * DD; jobs.dst[3] = wslot(3);  jobs.trans[3] = 1;
    jobs.src[4] = sg_W;           jobs.dst[4] = wslot(4);  jobs.trans[4] = 1;
    jobs.src[5] = sg_W + FD * DD; jobs.dst[5] = wslot(5);  jobs.trans[5] = 1;
    jobs.src[6] = spa_out_w;      jobs.dst[6] = wslot(12); jobs.trans[6] = 0;
    jobs.src[7] = spe_out_w;      jobs.dst[7] = wslot(13); jobs.trans[7] = 0;
    cast_w8_kernel<<<dim3(8 * 256), 256, 0, stream>>>(jobs);
  }
  combine(spa_in_w,                spa_hyp_W,  spa_hyp_b,  spa_in_b,          wslot(6), cb(0), fsQ);
  combine(spa_in_w + DD * DD,      spa_star_W, spa_star_b, spa_in_b + DD,     wslot(7), cb(1), 1.0f);
  combine(spa_in_w + 2 * DD * DD,  spa_clq_W,  spa_clq_b,  spa_in_b + 2 * DD, wslot(8), cb(2), 1.0f);
  combine3(spe_in_w,               spe_in_b,            spe_hyp_W,  spe_hyp_b,  snh_W, snh_b, wslot(9),  cb(3), cb(4), fsQ);
  combine3(spe_in_w + DD * DD,     spe_in_b + DD,       spe_star_W, spe_star_b, snc_W, snc_b, wslot(10), cb(5), cb(6), 1.0f);
  combine3(spe_in_w + 2 * DD * DD, spe_in_b + 2 * DD,   spe_clq_W,  spe_clq_b,  sns_W, sns_b, wslot(11), cb(7), cb(8), 1.0f);

  // ================= batched CSR build (7 dispatches) =================
  {
    CooPtrs coo;
    coo.rw[0] = Acg_r; coo.cl[0] = Acg_c; coo.vl[0] = Acg_v;
    coo.rw[1] = Ahy_r; coo.cl[1] = Ahy_c; coo.vl[1] = Ahy_v;
    coo.rw[2] = Asg_r; coo.cl[2] = Asg_c; coo.vl[2] = Asg_v;
    coo.rw[3] = Lcg_r; coo.cl[3] = Lcg_c; coo.vl[3] = Lcg_v;
    coo.rw[4] = Lhy_r; coo.cl[4] = Lhy_c; coo.vl[4] = Lhy_v;
    coo.rw[5] = Lsg_r; coo.cl[5] = Lsg_c; coo.vl[5] = Lsg_v;
    hipMemsetAsync(cnt, 0, (size_t)ROWS_TOT * 4, stream);
    count_all_kernel<<<dim3(ETOT / 256), 256, 0, stream>>>(coo, cnt);
    scan1_kernel<<<dim3(ROWS_TOT / 256), 256, 0, stream>>>(cnt, bsum, ROWS_TOT);
    scan2_kernel<<<dim3(1), 256, 0, stream>>>(bsum, ROWS_TOT / 256);
    scan3_kernel<<<dim3(ROWS_TOT / 256), 256, 0, stream>>>(cnt, bsum, P, cnt, ROWS_TOT);
    fill_all_kernel<<<dim3(ETOT / 256), 256, 0, stream>>>(coo, P, cnt, ecol, eval);
    rowsum_all_kernel<<<dim3(3 * NN / 256), 256, 0, stream>>>(P, eval, rsAll);
  }

  // ================= expansion nets =================
  gemm32in(x, wslot(0), T, NN);
  spmm(rp_cg, T, H, NN, NN, cg_b, true);
  gemmbb(H, wslot(1), nullptr, T, NN);
  spmm(rp_cg, T, CG, NN, NN, cg_b + DD, false);

  gemm32in(x, wslot(2), T, NN);
  spmm(rp_hy, T, H, NN, NN, hg_b, true);
  gemmbb(H, wslot(3), nullptr, T, NN);
  spmm(rp_hy, T, HG, NN, NN, hg_b + DD, false);

  // sg: x_star rows >= NN are zero -> src_rows=NN on first spmm
  gemm32in(x, wslot(4), T, NN);
  spmm(rp_sg, T, H, NN, MM, sg_b, true);
  gemmbb(H, wslot(5), nullptr, T, MM);
  spmm(rp_sg, T, SG, MM, MM, sg_b + DD, false, out + (size_t)NN * 512);

  // ================= Laplacian spmms =================
  spmm(rp_Lhy, HG, LH, NN, NN, nullptr, false);
  spmm(rp_Lcg, CG, LC, NN, NN, nullptr, false);
  spmm(rp_Lsg, SG, LS, MM, NN, nullptr, false);  // rows < N only

  // ================= spectral MHA =================
  gemmrs(LH, wslot(9),  cb(4), rs_h, cb(3), QH, NN);
  gemmrs(LC, wslot(10), cb(6), rs_c, cb(5), KH, NN);
  gemmrs(LS, wslot(11), cb(8), rs_s, cb(7), VH, NN);
  attn(QH, KH, VH, AO);
  gemmout(AO, wslot(13), spe_out_b, out, 256);   // taa cols 256..511

  // ================= spatial MHA =================
  gemmbb(HG, wslot(6), cb(0), QH, NN);
  gemmbb(CG, wslot(7), cb(1), KH, NN);
  gemmbb(SG, wslot(8), cb(2), VH, NN);
  attn(QH, KH, VH, AO);
  gemmout(AO, wslot(12), spa_out_b, out, 0);     // taa cols 0..255
}

// Round 10
// 1603.106 us; speedup vs baseline: 5.3854x; 1.0459x over previous
//
#include <hip/hip_runtime.h>

// Problem dims (fixed by reference)
#define NN 49152
#define EHN 8192
#define MM (NN + EHN)       // 57344
#define FD 256
#define DD 256
#define NHEADS 8
#define DHEAD 32
#define CHK 1024
#define NEN (10 * NN)       // 491520
#define NEM (10 * MM)       // 573440
#define ROWS_TOT (4 * NN + 2 * MM)   // 311296
#define ETOT (4 * NEN + 2 * NEM)     // 3,112,960

typedef __bf16 bf16x8 __attribute__((ext_vector_type(8)));
typedef unsigned short u16x8 __attribute__((ext_vector_type(8)));
typedef float f32x4 __attribute__((ext_vector_type(4)));

static __device__ __forceinline__ unsigned short f2bf(float f) {
  unsigned int u = __float_as_uint(f);
  unsigned int r = (u + 0x7FFFu + ((u >> 16) & 1u)) >> 16;
  return (unsigned short)r;
}
static __device__ __forceinline__ float bf2f(unsigned short u) {
  return __uint_as_float((unsigned int)u << 16);
}
static __device__ __forceinline__ unsigned int cvtpk(float a, float b) {
  unsigned int r;
  asm("v_cvt_pk_bf16_f32 %0, %1, %2" : "=v"(r) : "v"(a), "v"(b));
  return r;
}

// ---------------- weight prep ----------------
struct CastJobs {
  const float* src[8];
  unsigned short* dst[8];
  int trans[8];
};
__global__ __launch_bounds__(256) void cast_w8_kernel(CastJobs jobs)
{
  int job = blockIdx.x >> 8;
  int i = (blockIdx.x & 255) * 256 + threadIdx.x;
  int n = i >> 8, k = i & 255;
  const float* src = jobs.src[job];
  float f = jobs.trans[job] ? src[(size_t)k * 256 + n] : src[i];
  jobs.dst[job][i] = f2bf(f);
}

__global__ __launch_bounds__(256) void combine_w_kernel(
    const float* __restrict__ Bw, const float* __restrict__ Aw,
    const float* __restrict__ ab, const float* __restrict__ bb,
    unsigned short* __restrict__ Wc, float* __restrict__ bc, float fscale)
{
  int n = blockIdx.x, t = threadIdx.x;
  __shared__ float shB[256];
  __shared__ float red[256];
  shB[t] = Bw[n * 256 + t];
  __syncthreads();
  float acc = 0.0f;
  #pragma unroll 8
  for (int j = 0; j < 256; ++j) acc += shB[j] * Aw[j * 256 + t];
  Wc[n * 256 + t] = f2bf(acc * fscale);
  red[t] = shB[t] * ab[t];
  __syncthreads();
  for (int off = 128; off; off >>= 1) {
    if (t < off) red[t] += red[t + off];
    __syncthreads();
  }
  if (t == 0) bc[n] = (red[0] + bb[n]) * fscale;
}

__global__ __launch_bounds__(256) void mm256f_kernel(
    const float* __restrict__ A, const float* __restrict__ B,
    float* __restrict__ C)
{
  int n = blockIdx.x, t = threadIdx.x;
  __shared__ float sa[256];
  sa[t] = A[n * 256 + t];
  __syncthreads();
  float acc = 0.0f;
  #pragma unroll 8
  for (int j = 0; j < 256; ++j) acc += sa[j] * B[j * 256 + t];
  C[n * 256 + t] = acc;
}

__global__ __launch_bounds__(256) void mm256b_kernel(
    const float* __restrict__ A, const float* __restrict__ B,
    unsigned short* __restrict__ W, float fs)
{
  int n = blockIdx.x, t = threadIdx.x;
  __shared__ float sa[256];
  sa[t] = A[n * 256 + t];
  __syncthreads();
  float acc = 0.0f;
  #pragma unroll 8
  for (int j = 0; j < 256; ++j) acc += sa[j] * B[j * 256 + t];
  W[n * 256 + t] = f2bf(acc * fs);
}

__global__ __launch_bounds__(256) void mv256_kernel(
    const float* __restrict__ W, const float* __restrict__ v,
    const float* __restrict__ add, float* __restrict__ outv, float fs)
{
  int t = threadIdx.x;
  __shared__ float sv[256];
  sv[t] = v[t];
  __syncthreads();
  float acc = 0.0f;
  #pragma unroll 8
  for (int k = 0; k < 256; ++k) acc += W[t * 256 + k] * sv[k];
  if (add) acc += add[t];
  outv[t] = fs * acc;
}

// ---------------- batched bf16-MFMA GEMM (3 jobs, bf16 out) ----------------
// job g occupies blocks [bs[g-1], bs[g]); row block bm within job.
struct Gemm3 {
  const void* A[3];
  const unsigned short* W[3];
  const float* c0[3];     // nullable
  const float* rs[3];     // nullable
  const float* cvec[3];
  unsigned short* out[3];
  int bs1, bs2, btot;
};
template<int ABF>
__global__ __launch_bounds__(256) void gemm3_kernel(Gemm3 g)
{
  const int b = blockIdx.x;
  const int j = (b >= g.bs2) ? 2 : (b >= g.bs1 ? 1 : 0);
  const int bm = (b - (j == 2 ? g.bs2 : j == 1 ? g.bs1 : 0)) * 64;
  const void* Ain = g.A[j];
  const unsigned short* Wt = g.W[j];

  __shared__ __align__(16) char sA[2][4096];
  __shared__ __align__(16) char sB[2][16384];
  const int tid = threadIdx.x, lane = tid & 63, wid = tid >> 6;
  const int l15 = lane & 15, l4 = lane >> 4;

  f32x4 acc[16] = {};
  const int ar = tid >> 2, akq = (tid & 3) * 8;
  const int bn = tid;

  float4 fa0, fa1;
  u16x8 ua;
  u16x8 rb0, rb1, rb2, rb3;
  auto stage_load = [&](int k0) {
    if (ABF) {
      ua = *(const u16x8*)((const unsigned short*)Ain +
                           (size_t)(bm + ar) * 256 + k0 + akq);
    } else {
      const float* ap = (const float*)Ain + (size_t)(bm + ar) * 256 + k0 + akq;
      fa0 = *(const float4*)ap;
      fa1 = *(const float4*)(ap + 4);
    }
    const unsigned short* bp = Wt + (size_t)bn * 256 + k0;
    rb0 = *(const u16x8*)bp;        rb1 = *(const u16x8*)(bp + 8);
    rb2 = *(const u16x8*)(bp + 16); rb3 = *(const u16x8*)(bp + 24);
  };
  auto stage_write = [&](int buf) {
    u16x8 va;
    if (ABF) {
      va = ua;
    } else {
      va[0] = f2bf(fa0.x); va[1] = f2bf(fa0.y); va[2] = f2bf(fa0.z); va[3] = f2bf(fa0.w);
      va[4] = f2bf(fa1.x); va[5] = f2bf(fa1.y); va[6] = f2bf(fa1.z); va[7] = f2bf(fa1.w);
    }
    int aa = ((ar << 6) + (akq << 1)) ^ ((ar & 7) << 4);
    *(u16x8*)(sA[buf] + aa) = va;
    int bb = (bn << 6) ^ ((bn & 7) << 4);
    *(u16x8*)(sB[buf] + bb) = rb0;
    *(u16x8*)(sB[buf] + (bb ^ 16)) = rb1;
    *(u16x8*)(sB[buf] + (bb ^ 32)) = rb2;
    *(u16x8*)(sB[buf] + (bb ^ 48)) = rb3;
  };

  stage_load(0);
  stage_write(0);
  __syncthreads();
  int cur = 0;
  for (int it = 0; it < 8; ++it) {
    if (it < 7) stage_load((it + 1) * 32);
    int ra = wid * 16 + l15;
    bf16x8 af = *(const bf16x8*)(sA[cur] + ((ra << 6) + (l4 << 4) ^ ((ra & 7) << 4)));
    #pragma unroll
    for (int n4 = 0; n4 < 16; ++n4) {
      int rn = n4 * 16 + l15;
      bf16x8 bf = *(const bf16x8*)(sB[cur] + ((rn << 6) + (l4 << 4) ^ ((rn & 7) << 4)));
      acc[n4] = __builtin_amdgcn_mfma_f32_16x16x32_bf16(af, bf, acc[n4], 0, 0, 0);
    }
    __syncthreads();
    if (it < 7) {
      stage_write(cur ^ 1);
      __syncthreads();
      cur ^= 1;
    }
  }
  const int row = bm + wid * 16 + l4 * 4;
  const float* rs = g.rs[j];
  const float* c0 = g.c0[j];
  const float* cvec = g.cvec[j];
  unsigned short* Cout = g.out[j];
  float rsv[4];
  if (rs) {
    #pragma unroll
    for (int jj = 0; jj < 4; ++jj) rsv[jj] = rs[row + jj];
  }
  #pragma unroll
  for (int n4 = 0; n4 < 16; ++n4) {
    int col = n4 * 16 + l15;
    float base = c0 ? c0[col] : 0.0f;
    float cv = rs ? cvec[col] : 0.0f;
    #pragma unroll
    for (int jj = 0; jj < 4; ++jj) {
      float v = acc[n4][jj] + base;
      if (rs) v += rsv[jj] * cv;
      Cout[(size_t)(row + jj) * 256 + col] = f2bf(v);
    }
  }
}

// out-projection GEMM (fp32 strided out) — unchanged structure
__global__ __launch_bounds__(256) void gemmout_kernel(
    const unsigned short* __restrict__ Ain, const unsigned short* __restrict__ Wt,
    const float* __restrict__ c0, float* __restrict__ Cout, int coff)
{
  __shared__ __align__(16) char sA[2][4096];
  __shared__ __align__(16) char sB[2][16384];
  const int tid = threadIdx.x, lane = tid & 63, wid = tid >> 6;
  const int l15 = lane & 15, l4 = lane >> 4;
  const int bm = blockIdx.x * 64;

  f32x4 acc[16] = {};
  const int ar = tid >> 2, akq = (tid & 3) * 8;
  const int bn = tid;
  u16x8 ua, rb0, rb1, rb2, rb3;
  auto stage_load = [&](int k0) {
    ua = *(const u16x8*)(Ain + (size_t)(bm + ar) * 256 + k0 + akq);
    const unsigned short* bp = Wt + (size_t)bn * 256 + k0;
    rb0 = *(const u16x8*)bp;        rb1 = *(const u16x8*)(bp + 8);
    rb2 = *(const u16x8*)(bp + 16); rb3 = *(const u16x8*)(bp + 24);
  };
  auto stage_write = [&](int buf) {
    int aa = ((ar << 6) + (akq << 1)) ^ ((ar & 7) << 4);
    *(u16x8*)(sA[buf] + aa) = ua;
    int bb = (bn << 6) ^ ((bn & 7) << 4);
    *(u16x8*)(sB[buf] + bb) = rb0;
    *(u16x8*)(sB[buf] + (bb ^ 16)) = rb1;
    *(u16x8*)(sB[buf] + (bb ^ 32)) = rb2;
    *(u16x8*)(sB[buf] + (bb ^ 48)) = rb3;
  };
  stage_load(0);
  stage_write(0);
  __syncthreads();
  int cur = 0;
  for (int it = 0; it < 8; ++it) {
    if (it < 7) stage_load((it + 1) * 32);
    int ra = wid * 16 + l15;
    bf16x8 af = *(const bf16x8*)(sA[cur] + ((ra << 6) + (l4 << 4) ^ ((ra & 7) << 4)));
    #pragma unroll
    for (int n4 = 0; n4 < 16; ++n4) {
      int rn = n4 * 16 + l15;
      bf16x8 bf = *(const bf16x8*)(sB[cur] + ((rn << 6) + (l4 << 4) ^ ((rn & 7) << 4)));
      acc[n4] = __builtin_amdgcn_mfma_f32_16x16x32_bf16(af, bf, acc[n4], 0, 0, 0);
    }
    __syncthreads();
    if (it < 7) {
      stage_write(cur ^ 1);
      __syncthreads();
      cur ^= 1;
    }
  }
  const int row = bm + wid * 16 + l4 * 4;
  #pragma unroll
  for (int n4 = 0; n4 < 16; ++n4) {
    int col = n4 * 16 + l15;
    float base = c0[col];
    #pragma unroll
    for (int jj = 0; jj < 4; ++jj)
      Cout[(size_t)(row + jj) * 512 + coff + col] = acc[n4][jj] + base;
  }
}

// ================= batched CSR build =================
struct CooPtrs {
  const int* rw[6];
  const int* cl[6];
  const float* vl[6];
};
static __device__ __forceinline__ void coo_block_resolve(
    int b, int& g, int& eb, int& rb)
{
  if      (b < 1920) { g = 0; eb = 0;    rb = 0; }
  else if (b < 3840) { g = 1; eb = 1920; rb = NN; }
  else if (b < 6080) { g = 2; eb = 3840; rb = 2 * NN; }
  else if (b < 8000) { g = 3; eb = 6080; rb = 2 * NN + MM; }
  else if (b < 9920) { g = 4; eb = 8000; rb = 3 * NN + MM; }
  else               { g = 5; eb = 9920; rb = 4 * NN + MM; }
}

__global__ __launch_bounds__(256) void count_all_kernel(
    CooPtrs coo, int* __restrict__ cnt)
{
  int g, eb, rb;
  coo_block_resolve(blockIdx.x, g, eb, rb);
  int e = (blockIdx.x - eb) * 256 + threadIdx.x;
  atomicAdd(&cnt[rb + coo.rw[g][e]], 1);
}

__global__ __launch_bounds__(256) void scan1_kernel(
    const int* __restrict__ cnt, int* __restrict__ bsum, int n)
{
  __shared__ int sh[256];
  int i = blockIdx.x * 256 + threadIdx.x;
  sh[threadIdx.x] = (i < n) ? cnt[i] : 0;
  __syncthreads();
  for (int off = 128; off; off >>= 1) {
    if (threadIdx.x < off) sh[threadIdx.x] += sh[threadIdx.x + off];
    __syncthreads();
  }
  if (threadIdx.x == 0) bsum[blockIdx.x] = sh[0];
}

__global__ __launch_bounds__(256) void scan2_kernel(int* __restrict__ bsum, int nb)
{
  __shared__ int sh[256];
  int t = threadIdx.x;
  int carry = 0;
  for (int base = 0; base < nb; base += 256) {
    int i = base + t;
    int v = (i < nb) ? bsum[i] : 0;
    sh[t] = v;
    __syncthreads();
    for (int off = 1; off < 256; off <<= 1) {
      int add = (t >= off) ? sh[t - off] : 0;
      __syncthreads();
      sh[t] += add;
      __syncthreads();
    }
    int incl = sh[t];
    int tot = sh[255];
    if (i < nb) bsum[i] = carry + incl - v;
    carry += tot;
    __syncthreads();
  }
}

__global__ __launch_bounds__(256) void scan3_kernel(
    const int* __restrict__ cnt, const int* __restrict__ bsum,
    int* __restrict__ rowptr, int* __restrict__ cntz, int n)
{
  __shared__ int sh[256];
  int i = blockIdx.x * 256 + threadIdx.x;
  int v = (i < n) ? cnt[i] : 0;
  sh[threadIdx.x] = v;
  __syncthreads();
  for (int off = 1; off < 256; off <<= 1) {
    int add = (threadIdx.x >= off) ? sh[threadIdx.x - off] : 0;
    __syncthreads();
    sh[threadIdx.x] += add;
    __syncthreads();
  }
  int incl = sh[threadIdx.x];
  int base = bsum[blockIdx.x];
  if (i < n) { rowptr[i] = base + incl - v; cntz[i] = 0; }
  if (i == n - 1) rowptr[n] = base + incl;
}

// packed (col, val) single 8B scatter — halves dirty-line count vs 2 arrays
__global__ __launch_bounds__(256) void fill_all_kernel(
    CooPtrs coo, const int* __restrict__ P, int* __restrict__ cur,
    int2* __restrict__ epack)
{
  int g, eb, rb;
  coo_block_resolve(blockIdx.x, g, eb, rb);
  int e = (blockIdx.x - eb) * 256 + threadIdx.x;
  int grow = rb + coo.rw[g][e];
  int pos = P[grow] + atomicAdd(&cur[grow], 1);
  epack[pos] = make_int2(coo.cl[g][e], __float_as_int(coo.vl[g][e]));
}

__global__ __launch_bounds__(256) void rowsum_all_kernel(
    const int* __restrict__ P, const int2* __restrict__ epack,
    float* __restrict__ rsAll)
{
  int j = blockIdx.x * 256 + threadIdx.x;
  int g = j / NN;
  int r = j - g * NN;
  int grow = (g == 0 ? 2 * NN + MM : g == 1 ? 3 * NN + MM : 4 * NN + MM) + r;
  float s = 0.0f;
  int end = P[grow + 1];
  for (int e = P[grow]; e < end; ++e) s += __int_as_float(epack[e].y);
  rsAll[j] = s;
}

// ---------------- batched CSR SpMM (3 jobs), wave-per-row -------------------
struct Spmm3 {
  const int* rowptr[3];
  const unsigned short* X[3];
  unsigned short* Y[3];
  float* Y2[3];
  const float* bias[3];
  int src_rows[3];
  int bs1, bs2;    // block starts of jobs 1,2
};
__global__ __launch_bounds__(256) void spmm3_kernel(
    Spmm3 s, const int2* __restrict__ ep, int relu)
{
  const int b = blockIdx.x;
  const int j = (b >= s.bs2) ? 2 : (b >= s.bs1 ? 1 : 0);
  const int rblk = b - (j == 2 ? s.bs2 : j == 1 ? s.bs1 : 0);
  const int wave = threadIdx.x >> 6, lane = threadIdx.x & 63;
  const int r = rblk * 4 + wave;
  const int f0 = lane * 4;
  const int src_rows = s.src_rows[j];
  const unsigned short* X = s.X[j];
  const int* rowptr = s.rowptr[j];
  int e = rowptr[r], end = rowptr[r + 1];
  float a0 = 0.0f, a1 = 0.0f, a2 = 0.0f, a3 = 0.0f;
  for (; e + 3 < end; e += 4) {
    int2 cv0 = ep[e], cv1 = ep[e + 1], cv2 = ep[e + 2], cv3 = ep[e + 3];
    ushort4 x0 = {0,0,0,0}, x1 = {0,0,0,0}, x2 = {0,0,0,0}, x3 = {0,0,0,0};
    if (cv0.x < src_rows) x0 = *(const ushort4*)(X + (size_t)cv0.x * DD + f0);
    if (cv1.x < src_rows) x1 = *(const ushort4*)(X + (size_t)cv1.x * DD + f0);
    if (cv2.x < src_rows) x2 = *(const ushort4*)(X + (size_t)cv2.x * DD + f0);
    if (cv3.x < src_rows) x3 = *(const ushort4*)(X + (size_t)cv3.x * DD + f0);
    float v0 = __int_as_float(cv0.y), v1 = __int_as_float(cv1.y);
    float v2 = __int_as_float(cv2.y), v3 = __int_as_float(cv3.y);
    if (cv0.x < src_rows) { a0 += v0*bf2f(x0.x); a1 += v0*bf2f(x0.y); a2 += v0*bf2f(x0.z); a3 += v0*bf2f(x0.w); }
    if (cv1.x < src_rows) { a0 += v1*bf2f(x1.x); a1 += v1*bf2f(x1.y); a2 += v1*bf2f(x1.z); a3 += v1*bf2f(x1.w); }
    if (cv2.x < src_rows) { a0 += v2*bf2f(x2.x); a1 += v2*bf2f(x2.y); a2 += v2*bf2f(x2.z); a3 += v2*bf2f(x2.w); }
    if (cv3.x < src_rows) { a0 += v3*bf2f(x3.x); a1 += v3*bf2f(x3.y); a2 += v3*bf2f(x3.z); a3 += v3*bf2f(x3.w); }
  }
  for (; e < end; ++e) {
    int2 cv = ep[e];
    if (cv.x < src_rows) {
      float v = __int_as_float(cv.y);
      ushort4 xx = *(const ushort4*)(X + (size_t)cv.x * DD + f0);
      a0 += v * bf2f(xx.x); a1 += v * bf2f(xx.y);
      a2 += v * bf2f(xx.z); a3 += v * bf2f(xx.w);
    }
  }
  const float* bias = s.bias[j];
  if (bias) {
    a0 += bias[f0]; a1 += bias[f0 + 1]; a2 += bias[f0 + 2]; a3 += bias[f0 + 3];
  }
  if (relu) {
    a0 = fmaxf(a0, 0.0f); a1 = fmaxf(a1, 0.0f);
    a2 = fmaxf(a2, 0.0f); a3 = fmaxf(a3, 0.0f);
  }
  uint2 yb = { cvtpk(a0, a1), cvtpk(a2, a3) };
  *(uint2*)(s.Y[j] + (size_t)r * DD + f0) = yb;
  if (s.Y2[j]) {
    float4 yf = {a0, a1, a2, a3};
    *(float4*)(s.Y2[j] + (size_t)r * DD + f0) = yf;
  }
}

// ---------------- MFMA flash attention (r9-proven) ----------------
__global__ __launch_bounds__(256) void attn_mfma_kernel(
    const unsigned short* __restrict__ Q, const unsigned short* __restrict__ K,
    const unsigned short* __restrict__ V, unsigned short* __restrict__ O)
{
  __shared__ __align__(16) char sKb[4096];
  __shared__ __align__(16) char sVb[4096];
  __shared__ __align__(16) char sPb[8192];
  const int wgid = (blockIdx.x & 7) * 768 + (blockIdx.x >> 3);
  const int qb = wgid & 15, h = (wgid >> 4) & 7, c = wgid >> 7;
  const int tid = threadIdx.x, lane = tid & 63, wid = tid >> 6;
  const int l15 = lane & 15, l4 = lane >> 4;
  char* sPw = sPb + wid * 2048;
  const size_t base = (size_t)c * (CHK * DD) + (size_t)h * DHEAD;
  const int q0 = qb * 64 + wid * 16;

  bf16x8 qf = *(const bf16x8*)(Q + base + (size_t)(q0 + l15) * DD + l4 * 8);

  const int key_s = tid >> 2, dq = (tid & 3) * 8;
  const unsigned short* Kp = K + base + (size_t)key_s * DD + dq;
  const unsigned short* Vp = V + base + (size_t)key_s * DD + dq;
  const int kaddr = ((key_s << 6) + (dq << 1)) ^ ((key_s & 7) << 4);

  f32x4 oacc[2] = {};
  float m = -1e30f, l = 0.0f;
  const f32x4 zero = {};

  for (int kt = 0; kt < CHK; kt += 64) {
    __syncthreads();
    u16x8 kv = *(const u16x8*)Kp;  Kp += 64 * DD;
    u16x8 vv = *(const u16x8*)Vp;  Vp += 64 * DD;
    *(u16x8*)(sKb + kaddr) = kv;
    #pragma unroll
    for (int i = 0; i < 8; ++i) {
      int d = dq + i;
      int bb = ((d << 7) + (key_s << 1))
             ^ ((d & 7) << 4) ^ (((d >> 3) & 3) << 5);
      *(unsigned short*)(sVb + bb) = vv[i];
    }
    __syncthreads();

    f32x4 s[4];
    #pragma unroll
    for (int s4 = 0; s4 < 4; ++s4) {
      int key = s4 * 16 + l15;
      int ba = ((key << 6) + (l4 << 4)) ^ ((key & 7) << 4);
      bf16x8 kf = *(const bf16x8*)(sKb + ba);
      s[s4] = __builtin_amdgcn_mfma_f32_16x16x32_bf16(kf, qf, zero, 0, 0, 0);
    }
    float tmax = -1e30f;
    #pragma unroll
    for (int s4 = 0; s4 < 4; ++s4)
      #pragma unroll
      for (int j = 0; j < 4; ++j) tmax = fmaxf(tmax, s[s4][j]);
    tmax = fmaxf(tmax, __shfl_xor(tmax, 16));
    tmax = fmaxf(tmax, __shfl_xor(tmax, 32));
    bool skip = __all(tmax - m <= 8.0f);
    float mnew = skip ? m : fmaxf(m, tmax);
    if (!skip) {
      float corr = __builtin_amdgcn_exp2f(m - mnew);
      l *= corr;
      oacc[0] *= corr;
      oacc[1] *= corr;
    }
    float psum = 0.0f;
    float p[4][4];
    #pragma unroll
    for (int s4 = 0; s4 < 4; ++s4)
      #pragma unroll
      for (int j = 0; j < 4; ++j) {
        p[s4][j] = __builtin_amdgcn_exp2f(s[s4][j] - mnew);
        psum += p[s4][j];
      }
    psum += __shfl_xor(psum, 16);
    psum += __shfl_xor(psum, 32);
    l += psum;
    m = mnew;
    #pragma unroll
    for (int s4 = 0; s4 < 4; ++s4) {
      uint2 pk = { cvtpk(p[s4][0], p[s4][1]), cvtpk(p[s4][2], p[s4][3]) };
      int bp = ((l15 << 7) + (s4 << 5) + (l4 << 3)) ^ ((l15 & 7) << 4);
      *(uint2*)(sPw + bp) = pk;
    }
    __syncthreads();

    #pragma unroll
    for (int dh = 0; dh < 2; ++dh)
      #pragma unroll
      for (int kh = 0; kh < 2; ++kh) {
        int d = dh * 16 + l15;
        int ba = ((d << 7) + ((kh * 32 + l4 * 8) << 1))
               ^ ((d & 7) << 4) ^ (((d >> 3) & 3) << 5);
        bf16x8 vf = *(const bf16x8*)(sVb + ba);
        int bp = ((l15 << 7) + (kh << 6) + (l4 << 4)) ^ ((l15 & 7) << 4);
        bf16x8 pf = *(const bf16x8*)(sPw + bp);
        oacc[dh] = __builtin_amdgcn_mfma_f32_16x16x32_bf16(vf, pf, oacc[dh], 0, 0, 0);
      }
  }

  float inv = 1.0f / l;
  unsigned short* orow = O + base + (size_t)(q0 + l15) * DD;
  #pragma unroll
  for (int dh = 0; dh < 2; ++dh) {
    uint2 o2 = { cvtpk(oacc[dh][0] * inv, oacc[dh][1] * inv),
                 cvtpk(oacc[dh][2] * inv, oacc[dh][3] * inv) };
    *(uint2*)(orow + dh * 16 + l4 * 4) = o2;
  }
}

__global__ __launch_bounds__(256) void fill_kernel(float* p, long n, float v)
{
  long i = (long)blockIdx.x * 256 + threadIdx.x;
  if (i < n) p[i] = v;
}

extern "C" void kernel_launch(void* const* d_in, const int* in_sizes, int n_in,
                              void* d_out, int out_size, void* d_ws, size_t ws_size,
                              hipStream_t stream)
{
  const float* x     = (const float*)d_in[0];
  const int*   Acg_r = (const int*)d_in[1];
  const int*   Acg_c = (const int*)d_in[2];
  const float* Acg_v = (const float*)d_in[3];
  const int*   Ahy_r = (const int*)d_in[4];
  const int*   Ahy_c = (const int*)d_in[5];
  const float* Ahy_v = (const float*)d_in[6];
  const int*   Asg_r = (const int*)d_in[7];
  const int*   Asg_c = (const int*)d_in[8];
  const float* Asg_v = (const float*)d_in[9];
  const int*   Lcg_r = (const int*)d_in[10];
  const int*   Lcg_c = (const int*)d_in[11];
  const float* Lcg_v = (const float*)d_in[12];
  const int*   Lhy_r = (const int*)d_in[13];
  const int*   Lhy_c = (const int*)d_in[14];
  const float* Lhy_v = (const float*)d_in[15];
  const int*   Lsg_r = (const int*)d_in[16];
  const int*   Lsg_c = (const int*)d_in[17];
  const float* Lsg_v = (const float*)d_in[18];
  const float* cg_W  = (const float*)d_in[19];
  const float* cg_b  = (const float*)d_in[20];
  const float* hg_W  = (const float*)d_in[21];
  const float* hg_b  = (const float*)d_in[22];
  const float* sg_W  = (const float*)d_in[23];
  const float* sg_b  = (const float*)d_in[24];
  const float* snh_W = (const float*)d_in[25];
  const float* snh_b = (const float*)d_in[26];
  const float* snc_W = (const float*)d_in[27];
  const float* snc_b = (const float*)d_in[28];
  const float* sns_W = (const float*)d_in[29];
  const float* sns_b = (const float*)d_in[30];
  const float* spa_hyp_W  = (const float*)d_in[31];
  const float* spa_hyp_b  = (const float*)d_in[32];
  const float* spa_star_W = (const float*)d_in[33];
  const float* spa_star_b = (const float*)d_in[34];
  const float* spa_clq_W  = (const float*)d_in[35];
  const float* spa_clq_b  = (const float*)d_in[36];
  const float* spa_in_w   = (const float*)d_in[37];
  const float* spa_in_b   = (const float*)d_in[38];
  const float* spa_out_w  = (const float*)d_in[39];
  const float* spa_out_b  = (const float*)d_in[40];
  const float* spe_hyp_W  = (const float*)d_in[41];
  const float* spe_hyp_b  = (const float*)d_in[42];
  const float* spe_star_W = (const float*)d_in[43];
  const float* spe_star_b = (const float*)d_in[44];
  const float* spe_clq_W  = (const float*)d_in[45];
  const float* spe_clq_b  = (const float*)d_in[46];
  const float* spe_in_w   = (const float*)d_in[47];
  const float* spe_in_b   = (const float*)d_in[48];
  const float* spe_out_w  = (const float*)d_in[49];
  const float* spe_out_b  = (const float*)d_in[50];

  float* out = (float*)d_out;

  const size_t NF = (size_t)NN * DD;
  const size_t MF = (size_t)MM * DD;
  const size_t WELEMS  = 14u * 65536u;
  const size_t need = (14 * NF + 3 * MF) * 2                      // bf16 bufs
                    + (size_t)ETOT * 8                            // packed edges
                    + ((size_t)3 * NN + 65536 + 256 + 4096) * 4   // fp32 small
                    + ((size_t)ROWS_TOT + 1 + ROWS_TOT + 2048) * 4
                    + WELEMS * 2;

  auto fill = [&](float v) {
    long tot = (long)out_size;
    fill_kernel<<<dim3((unsigned)((tot + 255) / 256)), 256, 0, stream>>>(out, tot, v);
  };
  if (ws_size < need)                        { fill(12.0f); return; }
  if (n_in != 51)                            { fill(16.0f); return; }
  if (in_sizes[0] != NN * FD)                { fill(20.0f); return; }
  if (in_sizes[3] != NEN)                    { fill(24.0f); return; }
  if (in_sizes[9] != NEM)                    { fill(28.0f); return; }
  if (in_sizes[19] != 2 * FD * DD)           { fill(32.0f); return; }
  if (in_sizes[37] != 3 * DD * DD)           { fill(36.0f); return; }
  if (out_size != NN * 512 + NN * DD + EHN * DD) { fill(40.0f); return; }

  // ---- bf16 buffers ----
  unsigned short* Tcg = (unsigned short*)d_ws;   // layer1 out / layer2 out alias
  unsigned short* Thy = Tcg + NF;
  unsigned short* Tsg = Thy + NF;
  unsigned short* Hcg = Tsg + NF;
  unsigned short* Hhy = Hcg + NF;
  unsigned short* Hsg = Hhy + NF;                // M
  unsigned short* Usg = Hsg + MF;                // M (layer2 sg out)
  unsigned short* SG  = Usg + MF;                // M
  unsigned short* CG  = SG + MF;
  unsigned short* HG  = CG + NF;
  unsigned short* LH  = HG + NF;
  unsigned short* LC  = LH + NF;
  unsigned short* LS  = LC + NF;
  unsigned short* QH  = LS + NF;
  unsigned short* KH  = QH + NF;
  unsigned short* VH  = KH + NF;
  unsigned short* AO  = VH + NF;
  unsigned short* Ucg = Tcg;    // alias: T dead before layer2 gemm writes U
  unsigned short* Uhy = Thy;

  // ---- packed edges (8B aligned: bf16 region is even bytes) ----
  int2* epack = (int2*)(AO + NF);
  // ---- fp32 small ----
  float* fp = (float*)(epack + ETOT);
  float* rsAll = fp;           fp += 3 * NN;
  float* tmp256 = fp;          fp += 65536;
  float* tmpv = fp;            fp += 256;
  float* CB = fp;              fp += 4096;
  // ---- ints ----
  int* P    = (int*)fp;
  int* cnt  = P + ROWS_TOT + 1;
  int* bsum = cnt + ROWS_TOT;
  unsigned short* WB = (unsigned short*)(bsum + 2048);

  int* rp_cg  = P;
  int* rp_hy  = P + NN;
  int* rp_sg  = P + 2 * NN;
  int* rp_Lcg = P + 2 * NN + MM;
  int* rp_Lhy = P + 3 * NN + MM;
  int* rp_Lsg = P + 4 * NN + MM;
  float* rs_c = rsAll;
  float* rs_h = rsAll + NN;
  float* rs_s = rsAll + 2 * NN;

  auto wslot = [&](int s) { return WB + (size_t)s * 65536; };
  auto cb    = [&](int s) { return CB + (size_t)s * 256; };

  auto combine = [&](const float* Bw, const float* Aw, const float* ab,
                     const float* bb, unsigned short* Wc, float* bcp, float fs) {
    combine_w_kernel<<<dim3(256), 256, 0, stream>>>(Bw, Aw, ab, bb, Wc, bcp, fs);
  };
  auto combine3 = [&](const float* w3, const float* b3, const float* pW,
                      const float* pb, const float* sW, const float* sb,
                      unsigned short* Wc, float* cvecp, float* c0p, float fs) {
    mm256f_kernel<<<dim3(256), 256, 0, stream>>>(pW, sW, tmp256);
    mm256b_kernel<<<dim3(256), 256, 0, stream>>>(w3, tmp256, Wc, fs);
    mv256_kernel<<<dim3(1), 256, 0, stream>>>(pW, sb, nullptr, tmpv, 1.0f);
    mv256_kernel<<<dim3(1), 256, 0, stream>>>(w3, tmpv, nullptr, cvecp, fs);
    mv256_kernel<<<dim3(1), 256, 0, stream>>>(w3, pb, b3, c0p, fs);
  };

  const float fsQ = 0.17677669529663687f * 1.4426950408889634f;

  // ================= weight prep =================
  {
    CastJobs jobs;
    jobs.src[0] = cg_W;           jobs.dst[0] = wslot(0);  jobs.trans[0] = 1;
    jobs.src[1] = cg_W + FD * DD; jobs.dst[1] = wslot(1);  jobs.trans[1] = 1;
    jobs.src[2] = hg_W;           jobs.dst[2] = wslot(2);  jobs.trans[2] = 1;
    jobs.src[3] = hg_W + FD * DD; jobs.dst[3] = wslot(3);  jobs.trans[3] = 1;
    jobs.src[4] = sg_W;           jobs.dst[4] = wslot(4);  jobs.trans[4] = 1;
    jobs.src[5] = sg_W + FD * DD; jobs.dst[5] = wslot(5);  jobs.trans[5] = 1;
    jobs.src[6] = spa_out_w;      jobs.dst[6] = wslot(12); jobs.trans[6] = 0;
    jobs.src[7] = spe_out_w;      jobs.dst[7] = wslot(13); jobs.trans[7] = 0;
    cast_w8_kernel<<<dim3(8 * 256), 256, 0, stream>>>(jobs);
  }
  combine(spa_in_w,                spa_hyp_W,  spa_hyp_b,  spa_in_b,          wslot(6), cb(0), fsQ);
  combine(spa_in_w + DD * DD,      spa_star_W, spa_star_b, spa_in_b + DD,     wslot(7), cb(1), 1.0f);
  combine(spa_in_w + 2 * DD * DD,  spa_clq_W,  spa_clq_b,  spa_in_b + 2 * DD, wslot(8), cb(2), 1.0f);
  combine3(spe_in_w,               spe_in_b,            spe_hyp_W,  spe_hyp_b,  snh_W, snh_b, wslot(9),  cb(3), cb(4), fsQ);
  combine3(spe_in_w + DD * DD,     spe_in_b + DD,       spe_star_W, spe_star_b, snc_W, snc_b, wslot(10), cb(5), cb(6), 1.0f);
  combine3(spe_in_w + 2 * DD * DD, spe_in_b + 2 * DD,   spe_clq_W,  spe_clq_b,  sns_W, sns_b, wslot(11), cb(7), cb(8), 1.0f);

  // ================= batched CSR build =================
  {
    CooPtrs coo;
    coo.rw[0] = Acg_r; coo.cl[0] = Acg_c; coo.vl[0] = Acg_v;
    coo.rw[1] = Ahy_r; coo.cl[1] = Ahy_c; coo.vl[1] = Ahy_v;
    coo.rw[2] = Asg_r; coo.cl[2] = Asg_c; coo.vl[2] = Asg_v;
    coo.rw[3] = Lcg_r; coo.cl[3] = Lcg_c; coo.vl[3] = Lcg_v;
    coo.rw[4] = Lhy_r; coo.cl[4] = Lhy_c; coo.vl[4] = Lhy_v;
    coo.rw[5] = Lsg_r; coo.cl[5] = Lsg_c; coo.vl[5] = Lsg_v;
    hipMemsetAsync(cnt, 0, (size_t)ROWS_TOT * 4, stream);
    count_all_kernel<<<dim3(ETOT / 256), 256, 0, stream>>>(coo, cnt);
    scan1_kernel<<<dim3(ROWS_TOT / 256), 256, 0, stream>>>(cnt, bsum, ROWS_TOT);
    scan2_kernel<<<dim3(1), 256, 0, stream>>>(bsum, ROWS_TOT / 256);
    scan3_kernel<<<dim3(ROWS_TOT / 256), 256, 0, stream>>>(cnt, bsum, P, cnt, ROWS_TOT);
    fill_all_kernel<<<dim3(ETOT / 256), 256, 0, stream>>>(coo, P, cnt, epack);
    rowsum_all_kernel<<<dim3(3 * NN / 256), 256, 0, stream>>>(P, epack, rsAll);
  }

  // ================= expansion nets (batched ×3) =================
  {  // layer-1 GEMM: T_g = x @ W_g0  (shared A = x)
    Gemm3 g = {};
    for (int j = 0; j < 3; ++j) { g.A[j] = x; g.c0[j] = nullptr; g.rs[j] = nullptr; }
    g.W[0] = wslot(0); g.out[0] = Tcg;
    g.W[1] = wslot(2); g.out[1] = Thy;
    g.W[2] = wslot(4); g.out[2] = Tsg;
    g.bs1 = 768; g.bs2 = 1536; g.btot = 2304;
    gemm3_kernel<0><<<dim3(2304), 256, 0, stream>>>(g);
  }
  {  // layer-1 SpMM: H_g = relu(A_g @ T_g + b_g0)
    Spmm3 s = {};
    s.rowptr[0] = rp_cg; s.X[0] = Tcg; s.Y[0] = Hcg; s.Y2[0] = nullptr; s.bias[0] = cg_b; s.src_rows[0] = NN;
    s.rowptr[1] = rp_hy; s.X[1] = Thy; s.Y[1] = Hhy; s.Y2[1] = nullptr; s.bias[1] = hg_b; s.src_rows[1] = NN;
    s.rowptr[2] = rp_sg; s.X[2] = Tsg; s.Y[2] = Hsg; s.Y2[2] = nullptr; s.bias[2] = sg_b; s.src_rows[2] = NN;
    s.bs1 = NN / 4; s.bs2 = 2 * (NN / 4);
    spmm3_kernel<<<dim3(2 * (NN / 4) + MM / 4), 256, 0, stream>>>(s, epack, 1);
  }
  {  // layer-2 GEMM: U_g = H_g @ W_g1
    Gemm3 g = {};
    g.A[0] = Hcg; g.W[0] = wslot(1); g.out[0] = Ucg;
    g.A[1] = Hhy; g.W[1] = wslot(3); g.out[1] = Uhy;
    g.A[2] = Hsg; g.W[2] = wslot(5); g.out[2] = Usg;
    for (int j = 0; j < 3; ++j) { g.c0[j] = nullptr; g.rs[j] = nullptr; }
    g.bs1 = NN / 64; g.bs2 = 2 * (NN / 64); g.btot = 2 * (NN / 64) + MM / 64;
    gemm3_kernel<1><<<dim3(2 * (NN / 64) + MM / 64), 256, 0, stream>>>(g);
  }
  {  // layer-2 SpMM: feat_g = A_g @ U_g + b_g1  (+dual write X_star/S_star)
    Spmm3 s = {};
    s.rowptr[0] = rp_cg; s.X[0] = Ucg; s.Y[0] = CG; s.Y2[0] = nullptr; s.bias[0] = cg_b + DD; s.src_rows[0] = NN;
    s.rowptr[1] = rp_hy; s.X[1] = Uhy; s.Y[1] = HG; s.Y2[1] = nullptr; s.bias[1] = hg_b + DD; s.src_rows[1] = NN;
    s.rowptr[2] = rp_sg; s.X[2] = Usg; s.Y[2] = SG; s.Y2[2] = out + (size_t)NN * 512; s.bias[2] = sg_b + DD; s.src_rows[2] = MM;
    s.bs1 = NN / 4; s.bs2 = 2 * (NN / 4);
    spmm3_kernel<<<dim3(2 * (NN / 4) + MM / 4), 256, 0, stream>>>(s, epack, 0);
  }
  {  // Laplacian SpMMs (first NN rows each)
    Spmm3 s = {};
    s.rowptr[0] = rp_Lhy; s.X[0] = HG; s.Y[0] = LH; s.Y2[0] = nullptr; s.bias[0] = nullptr; s.src_rows[0] = NN;
    s.rowptr[1] = rp_Lcg; s.X[1] = CG; s.Y[1] = LC; s.Y2[1] = nullptr; s.bias[1] = nullptr; s.src_rows[1] = NN;
    s.rowptr[2] = rp_Lsg; s.X[2] = SG; s.Y[2] = LS; s.Y2[2] = nullptr; s.bias[2] = nullptr; s.src_rows[2] = MM;
    s.bs1 = NN / 4; s.bs2 = 2 * (NN / 4);
    spmm3_kernel<<<dim3(3 * (NN / 4)), 256, 0, stream>>>(s, epack, 0);
  }

  // ================= spectral MHA =================
  {
    Gemm3 g = {};
    g.A[0] = LH; g.W[0] = wslot(9);  g.c0[0] = cb(4); g.rs[0] = rs_h; g.cvec[0] = cb(3); g.out[0] = QH;
    g.A[1] = LC; g.W[1] = wslot(10); g.c0[1] = cb(6); g.rs[1] = rs_c; g.cvec[1] = cb(5); g.out[1] = KH;
    g.A[2] = LS; g.W[2] = wslot(11); g.c0[2] = cb(8); g.rs[2] = rs_s; g.cvec[2] = cb(7); g.out[2] = VH;
    g.bs1 = 768; g.bs2 = 1536; g.btot = 2304;
    gemm3_kernel<1><<<dim3(2304), 256, 0, stream>>>(g);
  }
  attn_mfma_kernel<<<dim3(6144), 256, 0, stream>>>(QH, KH, VH, AO);
  gemmout_kernel<<<dim3(NN / 64), 256, 0, stream>>>(AO, wslot(13), spe_out_b, out, 256);

  // ================= spatial MHA =================
  {
    Gemm3 g = {};
    g.A[0] = HG; g.W[0] = wslot(6); g.c0[0] = cb(0); g.rs[0] = nullptr; g.out[0] = QH;
    g.A[1] = CG; g.W[1] = wslot(7); g.c0[1] = cb(1); g.rs[1] = nullptr; g.out[1] = KH;
    g.A[2] = SG; g.W[2] = wslot(8); g.c0[2] = cb(2); g.rs[2] = nullptr; g.out[2] = VH;
    g.bs1 = 768; g.bs2 = 1536; g.btot = 2304;
    gemm3_kernel<1><<<dim3(2304), 256, 0, stream>>>(g);
  }
  attn_mfma_kernel<<<dim3(6144), 256, 0, stream>>>(QH, KH, VH, AO);
  gemmout_kernel<<<dim3(NN / 64), 256, 0, stream>>>(AO, wslot(12), spa_out_b, out, 0);
}